// Round 2
// baseline (52414.368 us; speedup 1.0000x reference)
//
#include <hip/hip_runtime.h>
#include <cstdint>
#include <cstddef>

#define EPSF 1e-5f

// ---------------- patch embed: h[b,e,l] = sum_p x[b,0,p,l]*pw[e,p] + pb[e]
__global__ __launch_bounds__(256) void k_patch(const float* __restrict__ x, const float* __restrict__ pw,
                                               const float* __restrict__ pb, float* __restrict__ out) {
  int l = blockIdx.x * 256 + threadIdx.x;
  int e = blockIdx.y;
  int b = blockIdx.z;
  const float* xb = x + (size_t)b * 8 * 12288;
  float acc = pb[e];
#pragma unroll
  for (int p = 0; p < 8; ++p)
    acc += xb[(size_t)p * 12288 + l] * pw[e * 8 + p];
  out[((size_t)b * 256 + e) * 12288 + l] = acc;
}

// ---------------- full conv1d (256->256, K=5 causal) + BN(eval) + ReLU
__global__ __launch_bounds__(256) void k_conv(const float* __restrict__ in, const float* __restrict__ w,
                                              const float* __restrict__ cbias, const float* __restrict__ bng,
                                              const float* __restrict__ bnb, float* __restrict__ out, int L) {
  __shared__ float Xs[16][68];
  __shared__ float Ws[16][320];
  const int l0 = blockIdx.x * 64;
  const int co0 = blockIdx.y * 64;
  const int b = blockIdx.z;
  const int tid = threadIdx.x;
  const int tl = tid & 15;
  const int tc = tid >> 4;
  const float* inb = in + (size_t)b * 256 * L;
  float acc[4][4];
#pragma unroll
  for (int r = 0; r < 4; ++r)
#pragma unroll
    for (int j = 0; j < 4; ++j) acc[r][j] = 0.f;

  for (int ci0 = 0; ci0 < 256; ci0 += 16) {
    for (int i = tid; i < 16 * 68; i += 256) {
      int ci = i / 68, pos = i - ci * 68;
      int gl = l0 - 4 + pos;
      Xs[ci][pos] = (gl >= 0) ? inb[(size_t)(ci0 + ci) * L + gl] : 0.f;
    }
    for (int i = tid; i < 5120; i += 256) {
      int co = i / 80, r = i - co * 80;
      int ci = r / 5, k = r - ci * 5;
      Ws[ci][co * 5 + k] = w[(size_t)(co0 + co) * 1280 + (ci0 + ci) * 5 + k];
    }
    __syncthreads();
#pragma unroll 4
    for (int ci = 0; ci < 16; ++ci) {
      float xv[8];
#pragma unroll
      for (int j = 0; j < 8; ++j) xv[j] = Xs[ci][4 * tl + j];
#pragma unroll
      for (int r = 0; r < 4; ++r) {
        const float* wp = &Ws[ci][(4 * tc + r) * 5];
        float w0 = wp[0], w1 = wp[1], w2 = wp[2], w3 = wp[3], w4 = wp[4];
#pragma unroll
        for (int j = 0; j < 4; ++j)
          acc[r][j] += w0 * xv[j] + w1 * xv[j + 1] + w2 * xv[j + 2] + w3 * xv[j + 3] + w4 * xv[j + 4];
      }
    }
    __syncthreads();
  }
  const float sc = rsqrtf(1.f + EPSF);
#pragma unroll
  for (int r = 0; r < 4; ++r) {
    int co = co0 + 4 * tc + r;
    float alpha = bng[co] * sc;
    float beta = cbias[co] * alpha + bnb[co];
#pragma unroll
    for (int j = 0; j < 4; ++j) {
      int l = l0 + 4 * tl + j;
      float v = acc[r][j] * alpha + beta;
      out[((size_t)b * 256 + co) * L + l] = fmaxf(v, 0.f);
    }
  }
}

// ---------------- maxpool over last dim
__global__ void k_mp(const float* __restrict__ in, float* __restrict__ out, int Lout, int Lin, int kp,
                     size_t total) {
  size_t i = (size_t)blockIdx.x * 256 + threadIdx.x;
  if (i >= total) return;
  int lo = (int)(i % Lout);
  size_t bc = i / Lout;
  const float* p = in + bc * Lin + (size_t)lo * kp;
  float m = p[0];
  for (int j = 1; j < kp; ++j) m = fmaxf(m, p[j]);
  out[i] = m;
}

// ---------------- transpose (b,256,2048)->(b,2048,256 at rows 1..2048) + pos add
__global__ __launch_bounds__(256) void k_asm(const float* __restrict__ hin, const float* __restrict__ pos,
                                             float* __restrict__ u) {
  __shared__ float tile[64][65];
  int t0 = blockIdx.x * 64, e0 = blockIdx.y * 64, b = blockIdx.z;
  int tid = threadIdx.x;
  for (int i = tid; i < 4096; i += 256) {
    int e = i >> 6, t = i & 63;
    tile[e][t] = hin[((size_t)b * 256 + e0 + e) * 2048 + t0 + t];
  }
  __syncthreads();
  for (int i = tid; i < 4096; i += 256) {
    int t = i >> 6, e = i & 63;
    int gt = 1 + t0 + t, ge = e0 + e;
    u[((size_t)b * 2049 + gt) * 256 + ge] = tile[e][t] + pos[(size_t)gt * 256 + ge];
  }
}

__global__ void k_cls(const float* __restrict__ cls, const float* __restrict__ pos, float* __restrict__ u) {
  int e = threadIdx.x;
  float v = cls[e] + pos[e];
  for (int b = 0; b < 16; ++b) u[(size_t)b * 2049 * 256 + e] = v;
}

// ---------------- generic f32 GEMM: C[M,N] (=/+=) A[M,K] @ B[K,N]; K % 16 == 0
template <int ACC>
__global__ __launch_bounds__(256) void k_gemm(const float* __restrict__ A, const float* __restrict__ B,
                                              float* __restrict__ C, int M, int N, int K) {
  __shared__ float As[16][64];
  __shared__ float Bs[16][64];
  const int n0 = blockIdx.x * 64;
  const int m0 = blockIdx.y * 64;
  const int tid = threadIdx.x;
  const int tr = tid & 15;
  const int tc = tid >> 4;
  const int am = tid >> 2;
  const int ak = (tid & 3) * 4;
  const int bk = tid >> 4;
  const int bn = (tid & 15) * 4;
  float acc[4][4];
#pragma unroll
  for (int i = 0; i < 4; ++i)
#pragma unroll
    for (int j = 0; j < 4; ++j) acc[i][j] = 0.f;

  for (int k0 = 0; k0 < K; k0 += 16) {
    float a0 = 0.f, a1 = 0.f, a2 = 0.f, a3 = 0.f;
    if (m0 + am < M) {
      const float* ap = A + (size_t)(m0 + am) * K + k0 + ak;
      a0 = ap[0]; a1 = ap[1]; a2 = ap[2]; a3 = ap[3];
    }
    As[ak + 0][am] = a0; As[ak + 1][am] = a1; As[ak + 2][am] = a2; As[ak + 3][am] = a3;
    const float* bp = B + (size_t)(k0 + bk) * N + n0 + bn;
    Bs[bk][bn + 0] = (n0 + bn + 0 < N) ? bp[0] : 0.f;
    Bs[bk][bn + 1] = (n0 + bn + 1 < N) ? bp[1] : 0.f;
    Bs[bk][bn + 2] = (n0 + bn + 2 < N) ? bp[2] : 0.f;
    Bs[bk][bn + 3] = (n0 + bn + 3 < N) ? bp[3] : 0.f;
    __syncthreads();
#pragma unroll
    for (int k = 0; k < 16; ++k) {
      float av[4], bv[4];
#pragma unroll
      for (int i = 0; i < 4; ++i) av[i] = As[k][4 * tr + i];
#pragma unroll
      for (int j = 0; j < 4; ++j) bv[j] = Bs[k][4 * tc + j];
#pragma unroll
      for (int i = 0; i < 4; ++i)
#pragma unroll
        for (int j = 0; j < 4; ++j) acc[i][j] += av[i] * bv[j];
    }
    __syncthreads();
  }
#pragma unroll
  for (int i = 0; i < 4; ++i) {
    int m = m0 + 4 * tr + i;
    if (m >= M) continue;
    float* cp = C + (size_t)m * N + n0 + 4 * tc;
#pragma unroll
    for (int j = 0; j < 4; ++j) {
      int n = n0 + 4 * tc + j;
      if (n < N) {
        if (ACC) cp[j] += acc[i][j];
        else cp[j] = acc[i][j];
      }
    }
  }
}

// ---------------- dt = softplus(dtraw + bias); dA = exp(-exp(A_log)*dt)
__global__ void k_dtda(const float* __restrict__ zx, const float* __restrict__ dtb,
                       const float* __restrict__ al, float* __restrict__ dt, float* __restrict__ dA,
                       int total) {
  int i = blockIdx.x * 256 + threadIdx.x;
  if (i >= total) return;
  int hh = i & 7;
  size_t row = (size_t)(i >> 3);
  float v = zx[row * 1288 + 1280 + hh] + dtb[hh];
  float d = (v > 20.f) ? v : log1pf(expf(v));
  dt[i] = d;
  dA[i] = expf(-expf(al[hh]) * d);
}

// ---------------- depthwise causal conv K=4 + silu on xBC slice of zxbcdt
__global__ __launch_bounds__(256) void k_dw(const float* __restrict__ zx, const float* __restrict__ cw,
                                            const float* __restrict__ cb, float* __restrict__ xBC) {
  int c = blockIdx.x * 256 + threadIdx.x;  // 0..767
  int t = blockIdx.y;
  int b = blockIdx.z;
  const float* col = zx + ((size_t)b * 2049) * 1288 + 512 + c;
  float acc = cb[c];
#pragma unroll
  for (int k = 0; k < 4; ++k) {
    int ts = t - 3 + k;
    if (ts >= 0) acc += col[(size_t)ts * 1288] * cw[c * 4 + k];
  }
  float sig = 1.f / (1.f + expf(-acc));
  xBC[((size_t)b * 2049 + t) * 768 + c] = acc * sig;
}

// ---------------- sequential SSM scan. block=(b,h): 16 waves x 8 n's, lane=p.
__global__ __launch_bounds__(1024) void k_scan(const float* __restrict__ xBC, const float* __restrict__ dt,
                                               const float* __restrict__ dA, const float* __restrict__ Dh,
                                               float* __restrict__ y) {
  const int L = 2049;
  const int h = blockIdx.x;
  const int b = blockIdx.y;
  const int tid = threadIdx.x;
  const int w = tid >> 6;
  const int p = tid & 63;
  __shared__ float part[2][16][64];
  const float* xb = xBC + (size_t)b * L * 768;
  const float* dtb = dt + ((size_t)b * L) * 8 + h;
  const float* dab = dA + ((size_t)b * L) * 8 + h;
  float* yb = y + (size_t)b * L * 512 + h * 64 + p;
  const float Dhh = Dh[h];
  float s[8];
#pragma unroll
  for (int j = 0; j < 8; ++j) s[j] = 0.f;

  float xsA, dtA, daA, BvA[8], CvA[8];
  float xsB, dtB, daB, BvB[8], CvB[8];

#define PREF(xs_, dt_, da_, Bv_, Cv_, T)                         \
  {                                                              \
    int tt = (T) < L ? (T) : (L - 1);                            \
    const float* row = xb + (size_t)tt * 768;                    \
    xs_ = row[h * 64 + p];                                       \
    float4 b0 = *(const float4*)(row + 512 + 8 * w);             \
    float4 b1 = *(const float4*)(row + 512 + 8 * w + 4);         \
    float4 c0 = *(const float4*)(row + 640 + 8 * w);             \
    float4 c1 = *(const float4*)(row + 640 + 8 * w + 4);         \
    Bv_[0] = b0.x; Bv_[1] = b0.y; Bv_[2] = b0.z; Bv_[3] = b0.w;  \
    Bv_[4] = b1.x; Bv_[5] = b1.y; Bv_[6] = b1.z; Bv_[7] = b1.w;  \
    Cv_[0] = c0.x; Cv_[1] = c0.y; Cv_[2] = c0.z; Cv_[3] = c0.w;  \
    Cv_[4] = c1.x; Cv_[5] = c1.y; Cv_[6] = c1.z; Cv_[7] = c1.w;  \
    dt_ = dtb[(size_t)tt * 8];                                   \
    da_ = dab[(size_t)tt * 8];                                   \
  }

#define STEP(xs_, dt_, da_, Bv_, Cv_, T)                          \
  {                                                               \
    float dtx = dt_ * xs_;                                        \
    float partial = 0.f;                                          \
    _Pragma("unroll") for (int j = 0; j < 8; ++j) {               \
      s[j] = s[j] * da_ + dtx * Bv_[j];                           \
      partial += s[j] * Cv_[j];                                   \
    }                                                             \
    part[(T) & 1][w][p] = partial;                                \
    __syncthreads();                                              \
    if (w == 0) {                                                 \
      float sum = Dhh * xs_;                                      \
      _Pragma("unroll") for (int ww = 0; ww < 16; ++ww)           \
          sum += part[(T) & 1][ww][p];                            \
      yb[(size_t)(T) * 512] = sum;                                \
    }                                                             \
  }

  PREF(xsA, dtA, daA, BvA, CvA, 0);
  PREF(xsB, dtB, daB, BvB, CvB, 1);
  for (int t = 0; t < L - 1; t += 2) {
    STEP(xsA, dtA, daA, BvA, CvA, t);
    PREF(xsA, dtA, daA, BvA, CvA, t + 2);
    STEP(xsB, dtB, daB, BvB, CvB, t + 1);
    PREF(xsB, dtB, daB, BvB, CvB, t + 3);
  }
  STEP(xsA, dtA, daA, BvA, CvA, L - 1);
#undef PREF
#undef STEP
}

// ---------------- y = y*silu(z); RMS-norm over 512; *norm_w  (wave per row)
__global__ __launch_bounds__(256) void k_gaterms(const float* __restrict__ y, const float* __restrict__ zx,
                                                 const float* __restrict__ nw, float* __restrict__ y2) {
  int row = blockIdx.x * 4 + (threadIdx.x >> 6);
  int lane = threadIdx.x & 63;
  const float* yr = y + (size_t)row * 512 + lane * 8;
  const float* zr = zx + (size_t)row * 1288 + lane * 8;
  float g[8];
  float ss = 0.f;
#pragma unroll
  for (int j = 0; j < 8; ++j) {
    float yv = yr[j], zv = zr[j];
    float sig = 1.f / (1.f + expf(-zv));
    float gg = yv * zv * sig;
    g[j] = gg;
    ss += gg * gg;
  }
#pragma unroll
  for (int off = 32; off > 0; off >>= 1) ss += __shfl_xor(ss, off);
  float r = rsqrtf(ss * (1.f / 512.f) + EPSF);
#pragma unroll
  for (int j = 0; j < 8; ++j) y2[(size_t)row * 512 + lane * 8 + j] = g[j] * r * nw[lane * 8 + j];
}

// ---------------- final LayerNorm over E=256 for rows t=1..2048 (wave per row)
__global__ __launch_bounds__(256) void k_ln(const float* __restrict__ u, const float* __restrict__ g,
                                            const float* __restrict__ bb, float* __restrict__ out) {
  int rid = blockIdx.x * 4 + (threadIdx.x >> 6);
  int lane = threadIdx.x & 63;
  int b = rid >> 11;
  int t = (rid & 2047) + 1;
  const float* ur = u + ((size_t)b * 2049 + t) * 256 + lane * 4;
  float v[4];
  float s1 = 0.f, s2 = 0.f;
#pragma unroll
  for (int j = 0; j < 4; ++j) {
    v[j] = ur[j];
    s1 += v[j];
    s2 += v[j] * v[j];
  }
#pragma unroll
  for (int off = 32; off > 0; off >>= 1) {
    s1 += __shfl_xor(s1, off);
    s2 += __shfl_xor(s2, off);
  }
  float mu = s1 * (1.f / 256.f);
  float var = s2 * (1.f / 256.f) - mu * mu;
  float rs = rsqrtf(var + EPSF);
  float* orow = out + ((size_t)b * 2048 + (t - 1)) * 256 + lane * 4;
#pragma unroll
  for (int j = 0; j < 4; ++j) orow[j] = (v[j] - mu) * rs * g[lane * 4 + j] + bb[lane * 4 + j];
}

// ---------------- masked pool partials (deterministic, no atomics)
__global__ __launch_bounds__(256) void k_pp(const float* __restrict__ hln, const int* __restrict__ idx,
                                            float* __restrict__ part) {
  int ch = blockIdx.x;
  int b = blockIdx.y;
  int e = threadIdx.x;
  int agg = idx[b] / 6;
  int t0 = ch * 256;
  int tend = agg + 1 - t0;
  if (tend > 256) tend = 256;
  float s = 0.f;
  for (int i = 0; i < tend; ++i) s += hln[((size_t)b * 2048 + t0 + i) * 256 + e];
  part[((size_t)b * 8 + ch) * 256 + e] = s;
}

// ---------------- pooled @ fc_w + fc_b
__global__ __launch_bounds__(256) void k_fc(const float* __restrict__ part, const int* __restrict__ idx,
                                            const float* __restrict__ fw, const float* __restrict__ fb,
                                            float* __restrict__ out) {
  __shared__ float pooled[256];
  int b = blockIdx.x;
  int tid = threadIdx.x;
  float s = 0.f;
#pragma unroll
  for (int ch = 0; ch < 8; ++ch) s += part[((size_t)b * 8 + ch) * 256 + tid];
  pooled[tid] = s;
  __syncthreads();
  if (tid < 100) {
    int agg = idx[b] / 6;
    float inv = 1.f / (float)(agg + 1);
    float acc = 0.f;
    for (int e = 0; e < 256; ++e) acc += pooled[e] * fw[e * 100 + tid];
    out[b * 100 + tid] = acc * inv + fb[tid];
  }
}

extern "C" void kernel_launch(void* const* d_in, const int* in_sizes, int n_in,
                              void* d_out, int out_size, void* d_ws, size_t ws_size,
                              hipStream_t stream) {
  (void)in_sizes; (void)n_in; (void)out_size;
  const float* x        = (const float*)d_in[0];
  const int*   idx      = (const int*)d_in[1];
  const float* patch_w  = (const float*)d_in[2];
  const float* patch_b  = (const float*)d_in[3];
  const float* conv_w   = (const float*)d_in[4];
  const float* conv_b   = (const float*)d_in[5];
  const float* bn_g     = (const float*)d_in[6];
  const float* bn_b     = (const float*)d_in[7];
  const float* cls_tok  = (const float*)d_in[8];
  const float* pos_emb  = (const float*)d_in[9];
  const float* Wi       = (const float*)d_in[10];
  const float* cw       = (const float*)d_in[11];
  const float* cb       = (const float*)d_in[12];
  const float* dt_bias  = (const float*)d_in[13];
  const float* A_log    = (const float*)d_in[14];
  const float* Dh       = (const float*)d_in[15];
  const float* norm_w   = (const float*)d_in[16];
  const float* Wo       = (const float*)d_in[17];
  const float* ln_g     = (const float*)d_in[18];
  const float* ln_b     = (const float*)d_in[19];
  const float* fc_w     = (const float*)d_in[20];
  const float* fc_b     = (const float*)d_in[21];
  float* out = (float*)d_out;
  float* ws = (float*)d_ws;

  // batch-chunked workspace layout (all element counts in floats)
  // per-batch sizes: frontend buf 256*12288 = 3145728; zx row block 2049*1288 = 2639112
  size_t CB = 4;  // batches per chunk
  {
    size_t need4 = (8392704ull + 2ull * 4 * 3145728ull + 2ull * 4 * 16392ull + 32768ull) * 4;
    if (ws_size < need4) CB = 2;  // 84 MB fallback (hln spans bufA+bufB which are contiguous)
  }
  const int NCHUNK = (int)(16 / CB);
  const int Mc = (int)(CB * 2049);  // rows per chunk in mamba stage

  float* u    = ws;                          // 16*2049*256 = 8392704
  float* bufA = u + 8392704;                 // CB*3145728
  float* bufB = bufA + CB * 3145728;         // CB*3145728
  float* dtb  = bufB + CB * 3145728;         // CB*16392
  float* dab  = dtb + CB * 16392;            // CB*16392
  float* ppar = dab + CB * 16392;            // 32768
  float* hln  = bufA;                        // 16*2048*256 = 8388608 (spans into bufB if CB==2; safe)

  // ---- conv frontend, batch-chunked
  for (int bc = 0; bc < NCHUNK; ++bc) {
    const float* xc = x + (size_t)bc * CB * 8 * 12288;
    float* uc = u + (size_t)bc * CB * 2049 * 256;
    k_patch<<<dim3(48, 256, (unsigned)CB), 256, 0, stream>>>(xc, patch_w, patch_b, bufA);
    k_conv<<<dim3(192, 4, (unsigned)CB), 256, 0, stream>>>(bufA, conv_w + 0 * 327680, conv_b + 0, bn_g + 0, bn_b + 0, bufB, 12288);
    k_conv<<<dim3(192, 4, (unsigned)CB), 256, 0, stream>>>(bufB, conv_w + 1 * 327680, conv_b + 256, bn_g + 256, bn_b + 256, bufA, 12288);
    {
      size_t tot = CB * 256 * 4096;
      k_mp<<<dim3((unsigned)((tot + 255) / 256)), 256, 0, stream>>>(bufA, bufB, 4096, 12288, 3, tot);
    }
    k_conv<<<dim3(64, 4, (unsigned)CB), 256, 0, stream>>>(bufB, conv_w + 2 * 327680, conv_b + 512, bn_g + 512, bn_b + 512, bufA, 4096);
    k_conv<<<dim3(64, 4, (unsigned)CB), 256, 0, stream>>>(bufA, conv_w + 3 * 327680, conv_b + 768, bn_g + 768, bn_b + 768, bufB, 4096);
    {
      size_t tot = CB * 256 * 2048;
      k_mp<<<dim3((unsigned)((tot + 255) / 256)), 256, 0, stream>>>(bufB, bufA, 2048, 4096, 2, tot);
    }
    k_asm<<<dim3(32, 4, (unsigned)CB), 256, 0, stream>>>(bufA, pos_emb, uc);
  }
  k_cls<<<dim3(1), 256, 0, stream>>>(cls_tok, pos_emb, u);

  // ---- mamba layers, batch-chunked per layer
  float* zx   = bufA;                         // (CB,2049,1288) = CB*2639112 <= CB*3145728
  float* xBC  = bufB;                         // (CB,2049,768)
  float* ybuf = bufB + CB * 2049 * 768;       // (CB,2049,512); total CB*2622720 <= CB*3145728
  float* y2   = bufB;                         // overwrites xBC (safe: scan done)

  for (int l = 0; l < 8; ++l) {
    const float* Wil  = Wi + (size_t)l * 256 * 1288;
    const float* cwl  = cw + (size_t)l * 768 * 4;
    const float* cbl  = cb + (size_t)l * 768;
    const float* dtbl = dt_bias + l * 8;
    const float* all  = A_log + l * 8;
    const float* dhl  = Dh + l * 8;
    const float* nwl  = norm_w + (size_t)l * 512;
    const float* wol  = Wo + (size_t)l * 512 * 256;
    for (int bc = 0; bc < NCHUNK; ++bc) {
      float* uc = u + (size_t)bc * CB * 2049 * 256;
      k_gemm<0><<<dim3(21, (unsigned)((Mc + 63) / 64)), 256, 0, stream>>>(uc, Wil, zx, Mc, 1288, 256);
      k_dtda<<<dim3((unsigned)((Mc * 8 + 255) / 256)), 256, 0, stream>>>(zx, dtbl, all, dtb, dab, Mc * 8);
      k_dw<<<dim3(3, 2049, (unsigned)CB), 256, 0, stream>>>(zx, cwl, cbl, xBC);
      k_scan<<<dim3(8, (unsigned)CB), 1024, 0, stream>>>(xBC, dtb, dab, dhl, ybuf);
      k_gaterms<<<dim3((unsigned)(Mc / 4)), 256, 0, stream>>>(ybuf, zx, nwl, y2);
      k_gemm<1><<<dim3(4, (unsigned)((Mc + 63) / 64)), 256, 0, stream>>>(y2, wol, uc, Mc, 256, 512);
    }
  }

  // ---- final LN + masked pool + fc
  k_ln<<<dim3(8192), 256, 0, stream>>>(u, ln_g, ln_b, hln);
  k_pp<<<dim3(8, 16), 256, 0, stream>>>(hln, idx, ppar);
  k_fc<<<dim3(16), 256, 0, stream>>>(ppar, idx, fc_w, fc_b, out);
}

// Round 3
// 24397.845 us; speedup vs baseline: 2.1483x; 2.1483x over previous
//
#include <hip/hip_runtime.h>
#include <cstdint>
#include <cstddef>

#define EPSF 1e-5f

// ---------------- patch embed: h[b,e,l] = sum_p x[b,0,p,l]*pw[e,p] + pb[e]
__global__ __launch_bounds__(256) void k_patch(const float* __restrict__ x, const float* __restrict__ pw,
                                               const float* __restrict__ pb, float* __restrict__ out) {
  int l = blockIdx.x * 256 + threadIdx.x;
  int e = blockIdx.y;
  int b = blockIdx.z;
  const float* xb = x + (size_t)b * 8 * 12288;
  float acc = pb[e];
#pragma unroll
  for (int p = 0; p < 8; ++p)
    acc += xb[(size_t)p * 12288 + l] * pw[e * 8 + p];
  out[((size_t)b * 256 + e) * 12288 + l] = acc;
}

// ---------------- full conv1d (256->256, K=5 causal) + BN(eval) + ReLU
__global__ __launch_bounds__(256) void k_conv(const float* __restrict__ in, const float* __restrict__ w,
                                              const float* __restrict__ cbias, const float* __restrict__ bng,
                                              const float* __restrict__ bnb, float* __restrict__ out, int L) {
  __shared__ float Xs[16][68];
  __shared__ float Ws[16][320];
  const int l0 = blockIdx.x * 64;
  const int co0 = blockIdx.y * 64;
  const int b = blockIdx.z;
  const int tid = threadIdx.x;
  const int tl = tid & 15;
  const int tc = tid >> 4;
  const float* inb = in + (size_t)b * 256 * L;
  float acc[4][4];
#pragma unroll
  for (int r = 0; r < 4; ++r)
#pragma unroll
    for (int j = 0; j < 4; ++j) acc[r][j] = 0.f;

  for (int ci0 = 0; ci0 < 256; ci0 += 16) {
    for (int i = tid; i < 16 * 68; i += 256) {
      int ci = i / 68, pos = i - ci * 68;
      int gl = l0 - 4 + pos;
      Xs[ci][pos] = (gl >= 0) ? inb[(size_t)(ci0 + ci) * L + gl] : 0.f;
    }
    for (int i = tid; i < 5120; i += 256) {
      int co = i / 80, r = i - co * 80;
      int ci = r / 5, k = r - ci * 5;
      Ws[ci][co * 5 + k] = w[(size_t)(co0 + co) * 1280 + (ci0 + ci) * 5 + k];
    }
    __syncthreads();
#pragma unroll 4
    for (int ci = 0; ci < 16; ++ci) {
      float xv[8];
#pragma unroll
      for (int j = 0; j < 8; ++j) xv[j] = Xs[ci][4 * tl + j];
#pragma unroll
      for (int r = 0; r < 4; ++r) {
        const float* wp = &Ws[ci][(4 * tc + r) * 5];
        float w0 = wp[0], w1 = wp[1], w2 = wp[2], w3 = wp[3], w4 = wp[4];
#pragma unroll
        for (int j = 0; j < 4; ++j)
          acc[r][j] += w0 * xv[j] + w1 * xv[j + 1] + w2 * xv[j + 2] + w3 * xv[j + 3] + w4 * xv[j + 4];
      }
    }
    __syncthreads();
  }
  const float sc = rsqrtf(1.f + EPSF);
#pragma unroll
  for (int r = 0; r < 4; ++r) {
    int co = co0 + 4 * tc + r;
    float alpha = bng[co] * sc;
    float beta = cbias[co] * alpha + bnb[co];
#pragma unroll
    for (int j = 0; j < 4; ++j) {
      int l = l0 + 4 * tl + j;
      float v = acc[r][j] * alpha + beta;
      out[((size_t)b * 256 + co) * L + l] = fmaxf(v, 0.f);
    }
  }
}

// ---------------- maxpool over last dim
__global__ void k_mp(const float* __restrict__ in, float* __restrict__ out, int Lout, int Lin, int kp,
                     size_t total) {
  size_t i = (size_t)blockIdx.x * 256 + threadIdx.x;
  if (i >= total) return;
  int lo = (int)(i % Lout);
  size_t bc = i / Lout;
  const float* p = in + bc * Lin + (size_t)lo * kp;
  float m = p[0];
  for (int j = 1; j < kp; ++j) m = fmaxf(m, p[j]);
  out[i] = m;
}

// ---------------- transpose (b,256,2048)->(b,2048,256 at rows 1..2048) + pos add
__global__ __launch_bounds__(256) void k_asm(const float* __restrict__ hin, const float* __restrict__ pos,
                                             float* __restrict__ u) {
  __shared__ float tile[64][65];
  int t0 = blockIdx.x * 64, e0 = blockIdx.y * 64, b = blockIdx.z;
  int tid = threadIdx.x;
  for (int i = tid; i < 4096; i += 256) {
    int e = i >> 6, t = i & 63;
    tile[e][t] = hin[((size_t)b * 256 + e0 + e) * 2048 + t0 + t];
  }
  __syncthreads();
  for (int i = tid; i < 4096; i += 256) {
    int t = i >> 6, e = i & 63;
    int gt = 1 + t0 + t, ge = e0 + e;
    u[((size_t)b * 2049 + gt) * 256 + ge] = tile[e][t] + pos[(size_t)gt * 256 + ge];
  }
}

__global__ void k_cls(const float* __restrict__ cls, const float* __restrict__ pos, float* __restrict__ u) {
  int e = threadIdx.x;
  float v = cls[e] + pos[e];
  for (int b = 0; b < 16; ++b) u[(size_t)b * 2049 * 256 + e] = v;
}

// ---------------- generic f32 GEMM: C[M,N] (=/+=) A[M,K] @ B[K,N]; K % 16 == 0
template <int ACC>
__global__ __launch_bounds__(256) void k_gemm(const float* __restrict__ A, const float* __restrict__ B,
                                              float* __restrict__ C, int M, int N, int K) {
  __shared__ float As[16][64];
  __shared__ float Bs[16][64];
  const int n0 = blockIdx.x * 64;
  const int m0 = blockIdx.y * 64;
  const int tid = threadIdx.x;
  const int tr = tid & 15;
  const int tc = tid >> 4;
  const int am = tid >> 2;
  const int ak = (tid & 3) * 4;
  const int bk = tid >> 4;
  const int bn = (tid & 15) * 4;
  float acc[4][4];
#pragma unroll
  for (int i = 0; i < 4; ++i)
#pragma unroll
    for (int j = 0; j < 4; ++j) acc[i][j] = 0.f;

  for (int k0 = 0; k0 < K; k0 += 16) {
    float a0 = 0.f, a1 = 0.f, a2 = 0.f, a3 = 0.f;
    if (m0 + am < M) {
      const float* ap = A + (size_t)(m0 + am) * K + k0 + ak;
      a0 = ap[0]; a1 = ap[1]; a2 = ap[2]; a3 = ap[3];
    }
    As[ak + 0][am] = a0; As[ak + 1][am] = a1; As[ak + 2][am] = a2; As[ak + 3][am] = a3;
    const float* bp = B + (size_t)(k0 + bk) * N + n0 + bn;
    Bs[bk][bn + 0] = (n0 + bn + 0 < N) ? bp[0] : 0.f;
    Bs[bk][bn + 1] = (n0 + bn + 1 < N) ? bp[1] : 0.f;
    Bs[bk][bn + 2] = (n0 + bn + 2 < N) ? bp[2] : 0.f;
    Bs[bk][bn + 3] = (n0 + bn + 3 < N) ? bp[3] : 0.f;
    __syncthreads();
#pragma unroll
    for (int k = 0; k < 16; ++k) {
      float av[4], bv[4];
#pragma unroll
      for (int i = 0; i < 4; ++i) av[i] = As[k][4 * tr + i];
#pragma unroll
      for (int j = 0; j < 4; ++j) bv[j] = Bs[k][4 * tc + j];
#pragma unroll
      for (int i = 0; i < 4; ++i)
#pragma unroll
        for (int j = 0; j < 4; ++j) acc[i][j] += av[i] * bv[j];
    }
    __syncthreads();
  }
#pragma unroll
  for (int i = 0; i < 4; ++i) {
    int m = m0 + 4 * tr + i;
    if (m >= M) continue;
    float* cp = C + (size_t)m * N + n0 + 4 * tc;
#pragma unroll
    for (int j = 0; j < 4; ++j) {
      int n = n0 + 4 * tc + j;
      if (n < N) {
        if (ACC) cp[j] += acc[i][j];
        else cp[j] = acc[i][j];
      }
    }
  }
}

// ---------------- dt = softplus(dtraw + bias); ld = -exp(A_log)*dt  (log of dA)
__global__ void k_dtda(const float* __restrict__ zx, const float* __restrict__ dtb,
                       const float* __restrict__ al, float* __restrict__ dt, float* __restrict__ ld,
                       int total) {
  int i = blockIdx.x * 256 + threadIdx.x;
  if (i >= total) return;
  int hh = i & 7;
  size_t row = (size_t)(i >> 3);
  float v = zx[row * 1288 + 1280 + hh] + dtb[hh];
  float d = (v > 20.f) ? v : log1pf(expf(v));
  dt[i] = d;
  ld[i] = -expf(al[hh]) * d;
}

// ---------------- depthwise causal conv K=4 + silu on xBC slice of zxbcdt
__global__ __launch_bounds__(256) void k_dw(const float* __restrict__ zx, const float* __restrict__ cw,
                                            const float* __restrict__ cb, float* __restrict__ xBC) {
  int c = blockIdx.x * 256 + threadIdx.x;  // 0..767
  int t = blockIdx.y;
  int b = blockIdx.z;
  const float* col = zx + ((size_t)b * 2049) * 1288 + 512 + c;
  float acc = cb[c];
#pragma unroll
  for (int k = 0; k < 4; ++k) {
    int ts = t - 3 + k;
    if (ts >= 0) acc += col[(size_t)ts * 1288] * cw[c * 4 + k];
  }
  float sig = 1.f / (1.f + expf(-acc));
  xBC[((size_t)b * 2049 + t) * 768 + c] = acc * sig;
}

// ================= chunked SSD scan (Q=128, 17 chunks over L=2049) =================
// Phase A: per (chunk,h,b): Y_intra = (mask∘decay∘(C Bᵀ) dt) @ X  ;  Sc = (w2∘X)ᵀ @ B ; Dtot
__global__ __launch_bounds__(256) void k_ssd_intra(const float* __restrict__ xBC,
                                                   const float* __restrict__ dtg,
                                                   const float* __restrict__ ldg,
                                                   float* __restrict__ ybuf,
                                                   float* __restrict__ sc,
                                                   float* __restrict__ dtot) {
  const int L = 2049;
  const int c = blockIdx.x, h = blockIdx.y, b = blockIdx.z;
  const int tid = threadIdx.x;
  const int t0 = c * 128;
  int qc = L - t0; if (qc > 128) qc = 128;

  __shared__ float Ms[64][130];          // 33.3 KB
  __shared__ float Sb[3264];             // 13.1 KB staging union
  __shared__ float dt_s[128], ld_s[128], Lc_s[128];

  if (tid < 128) {
    float d = 0.f, l = 0.f;
    if (tid < qc) {
      size_t rowi = ((size_t)b * L + t0 + tid) * 8 + h;
      d = dtg[rowi]; l = ldg[rowi];
    }
    dt_s[tid] = d; ld_s[tid] = l;
  }
  __syncthreads();
  if (tid == 0) {
    float a = 0.f;
    for (int i = 0; i < 128; ++i) { a += ld_s[i]; Lc_s[i] = a; }
    dtot[((size_t)b * 8 + h) * 17 + c] = __expf(Lc_s[qc - 1]);
  }
  __syncthreads();

  const float* xb = xBC + ((size_t)b * L) * 768;
  const int tt = tid >> 4, ts = tid & 15;

  float* Ct = Sb;          // [64][17]
  float* Bt = Sb + 1088;   // [128][17]
  float* Xt = Sb;          // [16][65]
  float* Xw = Sb;          // [16][65]
  float* Bt2 = Sb + 1040;  // [16][130]

  for (int half = 0; half < 2; ++half) {
    // ---- G = C(half rows) @ Bᵀ over n=128
    float acc[4][8];
#pragma unroll
    for (int i = 0; i < 4; ++i)
#pragma unroll
      for (int j = 0; j < 8; ++j) acc[i][j] = 0.f;
    for (int n0 = 0; n0 < 128; n0 += 16) {
      __syncthreads();
      for (int q = tid; q < 1024; q += 256) {
        int r = q >> 4, k = q & 15;
        int t = half * 64 + r;
        Ct[r * 17 + k] = (t < qc) ? xb[((size_t)(t0 + t)) * 768 + 640 + n0 + k] : 0.f;
      }
      for (int q = tid; q < 2048; q += 256) {
        int r = q >> 4, k = q & 15;
        Bt[r * 17 + k] = (r < qc) ? xb[((size_t)(t0 + r)) * 768 + 512 + n0 + k] : 0.f;
      }
      __syncthreads();
#pragma unroll
      for (int k = 0; k < 16; ++k) {
        float a[4], bb[8];
#pragma unroll
        for (int i = 0; i < 4; ++i) a[i] = Ct[(tt * 4 + i) * 17 + k];
#pragma unroll
        for (int j = 0; j < 8; ++j) bb[j] = Bt[(ts * 8 + j) * 17 + k];
#pragma unroll
        for (int i = 0; i < 4; ++i)
#pragma unroll
          for (int j = 0; j < 8; ++j) acc[i][j] += a[i] * bb[j];
      }
    }
    // ---- mask + decay + dt  -> Ms
#pragma unroll
    for (int i = 0; i < 4; ++i) {
      int tl = tt * 4 + i;
      int t = half * 64 + tl;
#pragma unroll
      for (int j = 0; j < 8; ++j) {
        int s = ts * 8 + j;
        float v = 0.f;
        if (s <= t) v = __expf(Lc_s[t] - Lc_s[s]) * dt_s[s] * acc[i][j];
        Ms[tl][s] = v;
      }
    }
    // ---- Y_half = Ms @ X
    float ya[4][4];
#pragma unroll
    for (int i = 0; i < 4; ++i)
#pragma unroll
      for (int j = 0; j < 4; ++j) ya[i][j] = 0.f;
    const int smax = half ? 128 : 64;
    for (int s0 = 0; s0 < smax; s0 += 16) {
      __syncthreads();
      for (int q = tid; q < 1024; q += 256) {
        int r = q >> 6, p = q & 63;
        int s = s0 + r;
        Xt[r * 65 + p] = (s < qc) ? xb[((size_t)(t0 + s)) * 768 + h * 64 + p] : 0.f;
      }
      __syncthreads();
#pragma unroll
      for (int k = 0; k < 16; ++k) {
        float a[4], xx[4];
#pragma unroll
        for (int i = 0; i < 4; ++i) a[i] = Ms[tt * 4 + i][s0 + k];
#pragma unroll
        for (int j = 0; j < 4; ++j) xx[j] = Xt[k * 65 + ts * 4 + j];
#pragma unroll
        for (int i = 0; i < 4; ++i)
#pragma unroll
          for (int j = 0; j < 4; ++j) ya[i][j] += a[i] * xx[j];
      }
    }
#pragma unroll
    for (int i = 0; i < 4; ++i) {
      int t = half * 64 + tt * 4 + i;
      if (t < qc) {
        float* yp = ybuf + ((size_t)b * L + t0 + t) * 512 + h * 64 + ts * 4;
#pragma unroll
        for (int j = 0; j < 4; ++j) yp[j] = ya[i][j];
      }
    }
    __syncthreads();
  }

  // ---- Sc[p][n] = sum_s w2[s] X[s,p] B[s,n],  w2[s]=exp(Lend-Lc[s])*dt[s]
  float sa[4][8];
#pragma unroll
  for (int i = 0; i < 4; ++i)
#pragma unroll
    for (int j = 0; j < 8; ++j) sa[i][j] = 0.f;
  const float Lend = Lc_s[qc - 1];
  for (int s0 = 0; s0 < 128; s0 += 16) {
    __syncthreads();
    for (int q = tid; q < 1024; q += 256) {
      int r = q >> 6, p = q & 63;
      int s = s0 + r;
      float w2 = __expf(Lend - Lc_s[s]) * dt_s[s];
      Xw[r * 65 + p] = (s < qc) ? w2 * xb[((size_t)(t0 + s)) * 768 + h * 64 + p] : 0.f;
    }
    for (int q = tid; q < 2048; q += 256) {
      int r = q >> 7, n = q & 127;
      int s = s0 + r;
      Bt2[r * 130 + n] = (s < qc) ? xb[((size_t)(t0 + s)) * 768 + 512 + n] : 0.f;
    }
    __syncthreads();
#pragma unroll
    for (int k = 0; k < 16; ++k) {
      float a[4], bb[8];
#pragma unroll
      for (int i = 0; i < 4; ++i) a[i] = Xw[k * 65 + tt * 4 + i];
#pragma unroll
      for (int j = 0; j < 8; ++j) bb[j] = Bt2[k * 130 + ts * 8 + j];
#pragma unroll
      for (int i = 0; i < 4; ++i)
#pragma unroll
        for (int j = 0; j < 8; ++j) sa[i][j] += a[i] * bb[j];
    }
  }
  float* scp = sc + (((size_t)b * 8 + h) * 17 + c) * 8192;
#pragma unroll
  for (int i = 0; i < 4; ++i) {
    int p = tt * 4 + i;
#pragma unroll
    for (int j = 0; j < 8; ++j) scp[p * 128 + ts * 8 + j] = sa[i][j];
  }
}

// Phase B: sequential over 17 chunks per (b,h); Sc[c] becomes h0[c] (state BEFORE chunk c)
__global__ __launch_bounds__(256) void k_ssd_scan(float* __restrict__ sc, const float* __restrict__ dtot) {
  const int h = blockIdx.x, b = blockIdx.y;
  const int tid = threadIdx.x;
  float* base = sc + ((size_t)b * 8 + h) * 17 * 8192;
  const float* dtp = dtot + ((size_t)b * 8 + h) * 17;
  float hc[32];
#pragma unroll
  for (int k = 0; k < 32; ++k) hc[k] = 0.f;
  for (int cc = 0; cc < 17; ++cc) {
    float D = dtp[cc];
    float* p = base + (size_t)cc * 8192;
#pragma unroll
    for (int k = 0; k < 32; ++k) {
      float t = p[tid + k * 256];
      p[tid + k * 256] = hc[k];
      hc[k] = hc[k] * D + t;
    }
  }
}

// Phase C: y[t,p] += exp(Lc[t]) * (C[t] · h0) + Dh*xs
__global__ __launch_bounds__(256) void k_ssd_inter(const float* __restrict__ xBC,
                                                   const float* __restrict__ ldg,
                                                   const float* __restrict__ sc,
                                                   const float* __restrict__ Dh,
                                                   float* __restrict__ ybuf) {
  const int L = 2049;
  const int c = blockIdx.x, h = blockIdx.y, b = blockIdx.z;
  const int tid = threadIdx.x;
  const int t0 = c * 128;
  int qc = L - t0; if (qc > 128) qc = 128;
  __shared__ float Ct[128][17];
  __shared__ float H0[64][17];
  __shared__ float ld_s[128], Lc_s[128];
  if (tid < 128)
    ld_s[tid] = (tid < qc) ? ldg[((size_t)b * L + t0 + tid) * 8 + h] : 0.f;
  __syncthreads();
  if (tid == 0) { float a = 0.f; for (int i = 0; i < 128; ++i) { a += ld_s[i]; Lc_s[i] = a; } }
  __syncthreads();
  const float* xb = xBC + ((size_t)b * L) * 768;
  const float* hp = sc + (((size_t)b * 8 + h) * 17 + c) * 8192;
  const int tt = tid >> 4, ts = tid & 15;
  float acc[8][4];
#pragma unroll
  for (int i = 0; i < 8; ++i)
#pragma unroll
    for (int j = 0; j < 4; ++j) acc[i][j] = 0.f;
  for (int n0 = 0; n0 < 128; n0 += 16) {
    __syncthreads();
    for (int q = tid; q < 2048; q += 256) {
      int r = q >> 4, k = q & 15;
      Ct[r][k] = (r < qc) ? xb[((size_t)(t0 + r)) * 768 + 640 + n0 + k] : 0.f;
    }
    for (int q = tid; q < 1024; q += 256) {
      int r = q >> 4, k = q & 15;
      H0[r][k] = hp[r * 128 + n0 + k];
    }
    __syncthreads();
#pragma unroll
    for (int k = 0; k < 16; ++k) {
      float a[8], bb[4];
#pragma unroll
      for (int i = 0; i < 8; ++i) a[i] = Ct[tt * 8 + i][k];
#pragma unroll
      for (int j = 0; j < 4; ++j) bb[j] = H0[ts * 4 + j][k];
#pragma unroll
      for (int i = 0; i < 8; ++i)
#pragma unroll
        for (int j = 0; j < 4; ++j) acc[i][j] += a[i] * bb[j];
    }
  }
  const float DD = Dh[h];
#pragma unroll
  for (int i = 0; i < 8; ++i) {
    int t = tt * 8 + i;
    if (t >= qc) continue;
    float e = __expf(Lc_s[t]);
    size_t lt = (size_t)(t0 + t);
    float* yp = ybuf + ((size_t)b * L + lt) * 512 + h * 64 + ts * 4;
    const float* xp = xb + lt * 768 + h * 64 + ts * 4;
#pragma unroll
    for (int j = 0; j < 4; ++j) yp[j] += e * acc[i][j] + DD * xp[j];
  }
}

// ---------------- y = y*silu(z); RMS-norm over 512; *norm_w  (wave per row)
__global__ __launch_bounds__(256) void k_gaterms(const float* __restrict__ y, const float* __restrict__ zx,
                                                 const float* __restrict__ nw, float* __restrict__ y2) {
  int row = blockIdx.x * 4 + (threadIdx.x >> 6);
  int lane = threadIdx.x & 63;
  const float* yr = y + (size_t)row * 512 + lane * 8;
  const float* zr = zx + (size_t)row * 1288 + lane * 8;
  float g[8];
  float ss = 0.f;
#pragma unroll
  for (int j = 0; j < 8; ++j) {
    float yv = yr[j], zv = zr[j];
    float sig = 1.f / (1.f + expf(-zv));
    float gg = yv * zv * sig;
    g[j] = gg;
    ss += gg * gg;
  }
#pragma unroll
  for (int off = 32; off > 0; off >>= 1) ss += __shfl_xor(ss, off);
  float r = rsqrtf(ss * (1.f / 512.f) + EPSF);
#pragma unroll
  for (int j = 0; j < 8; ++j) y2[(size_t)row * 512 + lane * 8 + j] = g[j] * r * nw[lane * 8 + j];
}

// ---------------- final LayerNorm over E=256 for rows t=1..2048 (wave per row)
__global__ __launch_bounds__(256) void k_ln(const float* __restrict__ u, const float* __restrict__ g,
                                            const float* __restrict__ bb, float* __restrict__ out) {
  int rid = blockIdx.x * 4 + (threadIdx.x >> 6);
  int lane = threadIdx.x & 63;
  int b = rid >> 11;
  int t = (rid & 2047) + 1;
  const float* ur = u + ((size_t)b * 2049 + t) * 256 + lane * 4;
  float v[4];
  float s1 = 0.f, s2 = 0.f;
#pragma unroll
  for (int j = 0; j < 4; ++j) {
    v[j] = ur[j];
    s1 += v[j];
    s2 += v[j] * v[j];
  }
#pragma unroll
  for (int off = 32; off > 0; off >>= 1) {
    s1 += __shfl_xor(s1, off);
    s2 += __shfl_xor(s2, off);
  }
  float mu = s1 * (1.f / 256.f);
  float var = s2 * (1.f / 256.f) - mu * mu;
  float rs = rsqrtf(var + EPSF);
  float* orow = out + ((size_t)b * 2048 + (t - 1)) * 256 + lane * 4;
#pragma unroll
  for (int j = 0; j < 4; ++j) orow[j] = (v[j] - mu) * rs * g[lane * 4 + j] + bb[lane * 4 + j];
}

// ---------------- masked pool partials (deterministic, no atomics)
__global__ __launch_bounds__(256) void k_pp(const float* __restrict__ hln, const int* __restrict__ idx,
                                            float* __restrict__ part) {
  int ch = blockIdx.x;
  int b = blockIdx.y;
  int e = threadIdx.x;
  int agg = idx[b] / 6;
  int t0 = ch * 256;
  int tend = agg + 1 - t0;
  if (tend > 256) tend = 256;
  float s = 0.f;
  for (int i = 0; i < tend; ++i) s += hln[((size_t)b * 2048 + t0 + i) * 256 + e];
  part[((size_t)b * 8 + ch) * 256 + e] = s;
}

// ---------------- pooled @ fc_w + fc_b
__global__ __launch_bounds__(256) void k_fc(const float* __restrict__ part, const int* __restrict__ idx,
                                            const float* __restrict__ fw, const float* __restrict__ fb,
                                            float* __restrict__ out) {
  __shared__ float pooled[256];
  int b = blockIdx.x;
  int tid = threadIdx.x;
  float s = 0.f;
#pragma unroll
  for (int ch = 0; ch < 8; ++ch) s += part[((size_t)b * 8 + ch) * 256 + tid];
  pooled[tid] = s;
  __syncthreads();
  if (tid < 100) {
    int agg = idx[b] / 6;
    float inv = 1.f / (float)(agg + 1);
    float acc = 0.f;
    for (int e = 0; e < 256; ++e) acc += pooled[e] * fw[e * 100 + tid];
    out[b * 100 + tid] = acc * inv + fb[tid];
  }
}

extern "C" void kernel_launch(void* const* d_in, const int* in_sizes, int n_in,
                              void* d_out, int out_size, void* d_ws, size_t ws_size,
                              hipStream_t stream) {
  (void)in_sizes; (void)n_in; (void)out_size;
  const float* x        = (const float*)d_in[0];
  const int*   idx      = (const int*)d_in[1];
  const float* patch_w  = (const float*)d_in[2];
  const float* patch_b  = (const float*)d_in[3];
  const float* conv_w   = (const float*)d_in[4];
  const float* conv_b   = (const float*)d_in[5];
  const float* bn_g     = (const float*)d_in[6];
  const float* bn_b     = (const float*)d_in[7];
  const float* cls_tok  = (const float*)d_in[8];
  const float* pos_emb  = (const float*)d_in[9];
  const float* Wi       = (const float*)d_in[10];
  const float* cw       = (const float*)d_in[11];
  const float* cb       = (const float*)d_in[12];
  const float* dt_bias  = (const float*)d_in[13];
  const float* A_log    = (const float*)d_in[14];
  const float* Dh       = (const float*)d_in[15];
  const float* norm_w   = (const float*)d_in[16];
  const float* Wo       = (const float*)d_in[17];
  const float* ln_g     = (const float*)d_in[18];
  const float* ln_b     = (const float*)d_in[19];
  const float* fc_w     = (const float*)d_in[20];
  const float* fc_b     = (const float*)d_in[21];
  float* out = (float*)d_out;
  float* ws = (float*)d_ws;

  // workspace accounting (floats): u + 2 ping-pong + dt + ld + ppar + sc + dtot
  size_t CB = 4;
  {
    size_t need4 = (8392704ull + 2ull * 4 * 3145728ull + 2ull * 4 * 16392ull + 32768ull +
                    4ull * 8 * 17 * 8192ull + 1024ull) * 4;
    if (ws_size < need4) CB = 2;
  }
  const int NCHUNK = (int)(16 / CB);
  const int Mc = (int)(CB * 2049);

  float* u    = ws;                              // 8392704
  float* bufA = u + 8392704;                     // CB*3145728
  float* bufB = bufA + CB * 3145728;             // CB*3145728
  float* dtb  = bufB + CB * 3145728;             // CB*16392
  float* ldb  = dtb + CB * 16392;                // CB*16392
  float* ppar = ldb + CB * 16392;                // 32768
  float* scb  = ppar + 32768;                    // CB*8*17*8192
  float* dtot = scb + CB * 8 * 17 * 8192;        // CB*136 (pad 1024)
  float* hln  = bufA;                            // 16*2048*256 (spans bufA+bufB when CB==2)

  // ---- conv frontend, batch-chunked
  for (int bc = 0; bc < NCHUNK; ++bc) {
    const float* xc = x + (size_t)bc * CB * 8 * 12288;
    float* uc = u + (size_t)bc * CB * 2049 * 256;
    k_patch<<<dim3(48, 256, (unsigned)CB), 256, 0, stream>>>(xc, patch_w, patch_b, bufA);
    k_conv<<<dim3(192, 4, (unsigned)CB), 256, 0, stream>>>(bufA, conv_w + 0 * 327680, conv_b + 0, bn_g + 0, bn_b + 0, bufB, 12288);
    k_conv<<<dim3(192, 4, (unsigned)CB), 256, 0, stream>>>(bufB, conv_w + 1 * 327680, conv_b + 256, bn_g + 256, bn_b + 256, bufA, 12288);
    {
      size_t tot = CB * 256 * 4096;
      k_mp<<<dim3((unsigned)((tot + 255) / 256)), 256, 0, stream>>>(bufA, bufB, 4096, 12288, 3, tot);
    }
    k_conv<<<dim3(64, 4, (unsigned)CB), 256, 0, stream>>>(bufB, conv_w + 2 * 327680, conv_b + 512, bn_g + 512, bn_b + 512, bufA, 4096);
    k_conv<<<dim3(64, 4, (unsigned)CB), 256, 0, stream>>>(bufA, conv_w + 3 * 327680, conv_b + 768, bn_g + 768, bn_b + 768, bufB, 4096);
    {
      size_t tot = CB * 256 * 2048;
      k_mp<<<dim3((unsigned)((tot + 255) / 256)), 256, 0, stream>>>(bufB, bufA, 2048, 4096, 2, tot);
    }
    k_asm<<<dim3(32, 4, (unsigned)CB), 256, 0, stream>>>(bufA, pos_emb, uc);
  }
  k_cls<<<dim3(1), 256, 0, stream>>>(cls_tok, pos_emb, u);

  // ---- mamba layers, batch-chunked per layer
  float* zx   = bufA;                         // (CB,2049,1288)
  float* xBC  = bufB;                         // (CB,2049,768)
  float* ybuf = bufB + CB * 2049 * 768;       // (CB,2049,512)
  float* y2   = bufB;                         // overwrites xBC (safe: ssd done)

  for (int l = 0; l < 8; ++l) {
    const float* Wil  = Wi + (size_t)l * 256 * 1288;
    const float* cwl  = cw + (size_t)l * 768 * 4;
    const float* cbl  = cb + (size_t)l * 768;
    const float* dtbl = dt_bias + l * 8;
    const float* all  = A_log + l * 8;
    const float* dhl  = Dh + l * 8;
    const float* nwl  = norm_w + (size_t)l * 512;
    const float* wol  = Wo + (size_t)l * 512 * 256;
    for (int bc = 0; bc < NCHUNK; ++bc) {
      float* uc = u + (size_t)bc * CB * 2049 * 256;
      k_gemm<0><<<dim3(21, (unsigned)((Mc + 63) / 64)), 256, 0, stream>>>(uc, Wil, zx, Mc, 1288, 256);
      k_dtda<<<dim3((unsigned)((Mc * 8 + 255) / 256)), 256, 0, stream>>>(zx, dtbl, all, dtb, ldb, Mc * 8);
      k_dw<<<dim3(3, 2049, (unsigned)CB), 256, 0, stream>>>(zx, cwl, cbl, xBC);
      k_ssd_intra<<<dim3(17, 8, (unsigned)CB), 256, 0, stream>>>(xBC, dtb, ldb, ybuf, scb, dtot);
      k_ssd_scan<<<dim3(8, (unsigned)CB), 256, 0, stream>>>(scb, dtot);
      k_ssd_inter<<<dim3(17, 8, (unsigned)CB), 256, 0, stream>>>(xBC, ldb, scb, dhl, ybuf);
      k_gaterms<<<dim3((unsigned)(Mc / 4)), 256, 0, stream>>>(ybuf, zx, nwl, y2);
      k_gemm<1><<<dim3(4, (unsigned)((Mc + 63) / 64)), 256, 0, stream>>>(y2, wol, uc, Mc, 256, 512);
    }
  }

  // ---- final LN + masked pool + fc
  k_ln<<<dim3(8192), 256, 0, stream>>>(u, ln_g, ln_b, hln);
  k_pp<<<dim3(8, 16), 256, 0, stream>>>(hln, idx, ppar);
  k_fc<<<dim3(16), 256, 0, stream>>>(ppar, idx, fc_w, fc_b, out);
}

// Round 4
// 14721.800 us; speedup vs baseline: 3.5603x; 1.6573x over previous
//
#include <hip/hip_runtime.h>
#include <cstdint>
#include <cstddef>

#define EPSF 1e-5f

typedef unsigned short u16;
typedef __attribute__((ext_vector_type(8))) short short8v;
typedef __attribute__((ext_vector_type(4))) float f32x4;

static __device__ __forceinline__ u16 f2bf(float f) {
  union { float f; unsigned u; } v; v.f = f;
  unsigned r = v.u + 0x7fffu + ((v.u >> 16) & 1u);
  return (u16)(r >> 16);
}
static __device__ __forceinline__ float bf2f(u16 h) {
  union { unsigned u; float f; } v; v.u = ((unsigned)h) << 16;
  return v.f;
}

// ---------------- weight prep ----------------
// conv_w [4][256][256][5] f32 -> wbf [4][256][5][256] bf16
__global__ void k_wconv(const float* __restrict__ src, u16* __restrict__ dst) {
  int i = blockIdx.x * 256 + threadIdx.x;
  if (i >= 4 * 256 * 256 * 5) return;
  int k = i % 5, r = i / 5;
  int ci = r & 255; r >>= 8;
  int co = r & 255; int l = r >> 8;
  dst[(((size_t)l * 256 + co) * 5 + k) * 256 + ci] = f2bf(src[i]);
}
// Wi [8][256][1288] -> WiT [8][1288][256] bf16
__global__ void k_wti(const float* __restrict__ src, u16* __restrict__ dst) {
  int i = blockIdx.x * 256 + threadIdx.x;
  if (i >= 8 * 1288 * 256) return;
  int k = i & 255; int r = i >> 8;
  int n = r % 1288; int l = r / 1288;
  dst[i] = f2bf(src[((size_t)l * 256 + k) * 1288 + n]);
}
// Wo [8][512][256] -> WoT [8][256][512] bf16
__global__ void k_wto(const float* __restrict__ src, u16* __restrict__ dst) {
  int i = blockIdx.x * 256 + threadIdx.x;
  if (i >= 8 * 256 * 512) return;
  int k = i & 511; int r = i >> 9;
  int n = r & 255; int l = r >> 8;
  dst[i] = f2bf(src[((size_t)l * 512 + k) * 256 + n]);
}

// ---------------- patch embed -> [b][L][256] bf16
__global__ __launch_bounds__(256) void k_patchm(const float* __restrict__ x, const float* __restrict__ pw,
                                                const float* __restrict__ pb, u16* __restrict__ outb) {
  __shared__ float xs[8][64];
  const int l0 = blockIdx.x * 64;
  const int b = blockIdx.y;
  const int tid = threadIdx.x;
  const float* xb = x + (size_t)b * 8 * 12288;
  for (int q = tid; q < 512; q += 256) {
    int p = q >> 6, ll = q & 63;
    xs[p][ll] = xb[(size_t)p * 12288 + l0 + ll];
  }
  __syncthreads();
  float pwr[8];
#pragma unroll
  for (int p = 0; p < 8; ++p) pwr[p] = pw[tid * 8 + p];
  const float bias = pb[tid];
  u16* ob = outb + ((size_t)b * 12288 + l0) * 256 + tid;
  for (int ll = 0; ll < 64; ++ll) {
    float acc = bias;
#pragma unroll
    for (int p = 0; p < 8; ++p) acc += xs[p][ll] * pwr[p];
    ob[(size_t)ll * 256] = f2bf(acc);
  }
}

// ---------------- MFMA conv1d (256->256, K=5 causal) + BN + ReLU, [L][C] bf16
__global__ __launch_bounds__(256) void k_convm(const u16* __restrict__ in, const u16* __restrict__ wbf,
                                               const float* __restrict__ cbias, const float* __restrict__ bng,
                                               const float* __restrict__ bnb, u16* __restrict__ outb, int L) {
  __shared__ u16 Xs[132 * 40];
  __shared__ u16 Ws[64 * 168];
  const int l0 = blockIdx.x * 128;
  const int co0 = blockIdx.y * 64;
  const int b = blockIdx.z;
  const int tid = threadIdx.x;
  const int w = tid >> 6, l = tid & 63;
  const int mhalf = (w >> 1) * 64, nhalf = (w & 1) * 32;
  const u16* inb = in + (size_t)b * L * 256;
  u16* outbb = outb + (size_t)b * L * 256;
  f32x4 acc[4][2] = {};
  for (int ci0 = 0; ci0 < 256; ci0 += 32) {
    __syncthreads();
    for (int q = tid; q < 528; q += 256) {
      int row = q >> 2, coff = (q & 3) * 8;
      int gl = l0 - 4 + row;
      short8v v = {};
      if (gl >= 0) v = *(const short8v*)(inb + (size_t)gl * 256 + ci0 + coff);
      *(short8v*)(Xs + row * 40 + coff) = v;
    }
    for (int q = tid; q < 1280; q += 256) {
      int co = q / 20, rem = q % 20, k = rem >> 2, coff = (rem & 3) * 8;
      *(short8v*)(Ws + co * 168 + k * 32 + coff) =
          *(const short8v*)(wbf + ((size_t)(co0 + co) * 5 + k) * 256 + ci0 + coff);
    }
    __syncthreads();
    const int koff = (l >> 4) * 8;
    const int arow = mhalf + (l & 15);
    const int bro0 = (nhalf + (l & 15)) * 168;
    const int bro1 = (nhalf + 16 + (l & 15)) * 168;
#pragma unroll
    for (int k = 0; k < 5; ++k) {
      short8v b0 = *(const short8v*)(Ws + bro0 + k * 32 + koff);
      short8v b1 = *(const short8v*)(Ws + bro1 + k * 32 + koff);
#pragma unroll
      for (int mi = 0; mi < 4; ++mi) {
        short8v a = *(const short8v*)(Xs + (arow + mi * 16 + k) * 40 + koff);
        acc[mi][0] = __builtin_amdgcn_mfma_f32_16x16x32_bf16(a, b0, acc[mi][0], 0, 0, 0);
        acc[mi][1] = __builtin_amdgcn_mfma_f32_16x16x32_bf16(a, b1, acc[mi][1], 0, 0, 0);
      }
    }
  }
  const float scn = rsqrtf(1.f + EPSF);
#pragma unroll
  for (int ni = 0; ni < 2; ++ni) {
    int co = co0 + nhalf + ni * 16 + (l & 15);
    float alpha = bng[co] * scn;
    float beta = cbias[co] * alpha + bnb[co];
#pragma unroll
    for (int mi = 0; mi < 4; ++mi)
#pragma unroll
      for (int r = 0; r < 4; ++r) {
        int row = l0 + mhalf + mi * 16 + (l >> 4) * 4 + r;
        float v = acc[mi][ni][r] * alpha + beta;
        outbb[(size_t)row * 256 + co] = f2bf(fmaxf(v, 0.f));
      }
  }
}

// ---------------- maxpool over L dim, [L][C] bf16
__global__ void k_mpb(const u16* __restrict__ in, u16* __restrict__ out, int Lout, int kp, size_t total) {
  size_t i = (size_t)blockIdx.x * 256 + threadIdx.x;
  if (i >= total) return;
  size_t c = i & 255;
  size_t rest = i >> 8;
  size_t lo = rest % (size_t)Lout;
  size_t b = rest / (size_t)Lout;
  const u16* p = in + (b * (size_t)Lout * kp + lo * kp) * 256 + c;
  float m = bf2f(p[0]);
  for (int j = 1; j < kp; ++j) m = fmaxf(m, bf2f(p[(size_t)j * 256]));
  out[i] = f2bf(m);
}

// ---------------- assemble u rows 1..2048 (f32) from bf16 [b][2048][256] + pos
__global__ __launch_bounds__(256) void k_asmb(const u16* __restrict__ in, const float* __restrict__ pos,
                                              float* __restrict__ u) {
  int idx = blockIdx.x * 256 + threadIdx.x;  // over 2048*256
  int b = blockIdx.y;
  int t = idx >> 8, e = idx & 255;
  u[((size_t)b * 2049 + 1 + t) * 256 + e] = bf2f(in[((size_t)b * 2048 + t) * 256 + e]) + pos[(size_t)(1 + t) * 256 + e];
}

__global__ void k_cls(const float* __restrict__ cls, const float* __restrict__ pos, float* __restrict__ u) {
  int e = threadIdx.x;
  float v = cls[e] + pos[e];
  for (int b = 0; b < 16; ++b) u[(size_t)b * 2049 * 256 + e] = v;
}

// ---------------- cast u chunk -> bf16
__global__ void k_castu(const float* __restrict__ u, u16* __restrict__ ub, int total) {
  int i = blockIdx.x * 256 + threadIdx.x;
  if (i < total) ub[i] = f2bf(u[i]);
}

// ---------------- MFMA GEMM: C[M,N] (=/+=) A_bf[M,K] @ BT_bf[N,K]; K%32==0
template <int ACC>
__global__ __launch_bounds__(256) void k_gemmm(const u16* __restrict__ A, const u16* __restrict__ BT,
                                               float* __restrict__ C, int M, int N, int K) {
  __shared__ u16 As[128 * 40];
  __shared__ u16 Bs[64 * 40];
  const int n0 = blockIdx.x * 64;
  const int m0 = blockIdx.y * 128;
  const int tid = threadIdx.x;
  const int w = tid >> 6, l = tid & 63;
  const int mhalf = (w >> 1) * 64, nhalf = (w & 1) * 32;
  f32x4 acc[4][2] = {};
  for (int k0 = 0; k0 < K; k0 += 32) {
    __syncthreads();
    for (int q = tid; q < 512; q += 256) {
      int row = q >> 2, koff = (q & 3) * 8;
      short8v v = {};
      if (m0 + row < M) v = *(const short8v*)(A + (size_t)(m0 + row) * K + k0 + koff);
      *(short8v*)(As + row * 40 + koff) = v;
    }
    {
      int row = tid >> 2, koff = (tid & 3) * 8;
      short8v v = {};
      if (n0 + row < N) v = *(const short8v*)(BT + (size_t)(n0 + row) * K + k0 + koff);
      *(short8v*)(Bs + row * 40 + koff) = v;
    }
    __syncthreads();
    const int koff = (l >> 4) * 8;
    short8v b0 = *(const short8v*)(Bs + (nhalf + (l & 15)) * 40 + koff);
    short8v b1 = *(const short8v*)(Bs + (nhalf + 16 + (l & 15)) * 40 + koff);
#pragma unroll
    for (int mi = 0; mi < 4; ++mi) {
      short8v a = *(const short8v*)(As + (mhalf + mi * 16 + (l & 15)) * 40 + koff);
      acc[mi][0] = __builtin_amdgcn_mfma_f32_16x16x32_bf16(a, b0, acc[mi][0], 0, 0, 0);
      acc[mi][1] = __builtin_amdgcn_mfma_f32_16x16x32_bf16(a, b1, acc[mi][1], 0, 0, 0);
    }
  }
#pragma unroll
  for (int mi = 0; mi < 4; ++mi)
#pragma unroll
    for (int r = 0; r < 4; ++r) {
      int m = m0 + mhalf + mi * 16 + (l >> 4) * 4 + r;
      if (m >= M) continue;
#pragma unroll
      for (int ni = 0; ni < 2; ++ni) {
        int n = n0 + nhalf + ni * 16 + (l & 15);
        if (n >= N) continue;
        if (ACC) C[(size_t)m * N + n] += acc[mi][ni][r];
        else C[(size_t)m * N + n] = acc[mi][ni][r];
      }
    }
}

// ---------------- dt = softplus(dtraw + bias); ld = -exp(A_log)*dt
__global__ void k_dtda(const float* __restrict__ zx, const float* __restrict__ dtb,
                       const float* __restrict__ al, float* __restrict__ dt, float* __restrict__ ld,
                       int total) {
  int i = blockIdx.x * 256 + threadIdx.x;
  if (i >= total) return;
  int hh = i & 7;
  size_t row = (size_t)(i >> 3);
  float v = zx[row * 1288 + 1280 + hh] + dtb[hh];
  float d = (v > 20.f) ? v : log1pf(expf(v));
  dt[i] = d;
  ld[i] = -expf(al[hh]) * d;
}

// ---------------- depthwise causal conv K=4 + silu on xBC slice of zxbcdt
__global__ __launch_bounds__(256) void k_dw(const float* __restrict__ zx, const float* __restrict__ cw,
                                            const float* __restrict__ cb, float* __restrict__ xBC) {
  int c = blockIdx.x * 256 + threadIdx.x;  // 0..767
  int t = blockIdx.y;
  int b = blockIdx.z;
  const float* col = zx + ((size_t)b * 2049) * 1288 + 512 + c;
  float acc = cb[c];
#pragma unroll
  for (int k = 0; k < 4; ++k) {
    int ts = t - 3 + k;
    if (ts >= 0) acc += col[(size_t)ts * 1288] * cw[c * 4 + k];
  }
  float sig = 1.f / (1.f + expf(-acc));
  xBC[((size_t)b * 2049 + t) * 768 + c] = acc * sig;
}

// ================= chunked SSD scan (Q=128, 17 chunks over L=2049) =================
__global__ __launch_bounds__(256) void k_ssd_intra(const float* __restrict__ xBC,
                                                   const float* __restrict__ dtg,
                                                   const float* __restrict__ ldg,
                                                   float* __restrict__ ybuf,
                                                   float* __restrict__ sc,
                                                   float* __restrict__ dtot) {
  const int L = 2049;
  const int c = blockIdx.x, h = blockIdx.y, b = blockIdx.z;
  const int tid = threadIdx.x;
  const int t0 = c * 128;
  int qc = L - t0; if (qc > 128) qc = 128;

  __shared__ float Ms[64][130];
  __shared__ float Sb[3264];
  __shared__ float dt_s[128], ld_s[128], Lc_s[128];

  if (tid < 128) {
    float d = 0.f, lv = 0.f;
    if (tid < qc) {
      size_t rowi = ((size_t)b * L + t0 + tid) * 8 + h;
      d = dtg[rowi]; lv = ldg[rowi];
    }
    dt_s[tid] = d; ld_s[tid] = lv;
  }
  __syncthreads();
  if (tid == 0) {
    float a = 0.f;
    for (int i = 0; i < 128; ++i) { a += ld_s[i]; Lc_s[i] = a; }
    dtot[((size_t)b * 8 + h) * 17 + c] = __expf(Lc_s[qc - 1]);
  }
  __syncthreads();

  const float* xb = xBC + ((size_t)b * L) * 768;
  const int tt = tid >> 4, ts = tid & 15;

  float* Ct = Sb;
  float* Bt = Sb + 1088;
  float* Xt = Sb;
  float* Xw = Sb;
  float* Bt2 = Sb + 1040;

  for (int half = 0; half < 2; ++half) {
    float acc[4][8];
#pragma unroll
    for (int i = 0; i < 4; ++i)
#pragma unroll
      for (int j = 0; j < 8; ++j) acc[i][j] = 0.f;
    for (int n0 = 0; n0 < 128; n0 += 16) {
      __syncthreads();
      for (int q = tid; q < 1024; q += 256) {
        int r = q >> 4, k = q & 15;
        int t = half * 64 + r;
        Ct[r * 17 + k] = (t < qc) ? xb[((size_t)(t0 + t)) * 768 + 640 + n0 + k] : 0.f;
      }
      for (int q = tid; q < 2048; q += 256) {
        int r = q >> 4, k = q & 15;
        Bt[r * 17 + k] = (r < qc) ? xb[((size_t)(t0 + r)) * 768 + 512 + n0 + k] : 0.f;
      }
      __syncthreads();
#pragma unroll
      for (int k = 0; k < 16; ++k) {
        float a[4], bb[8];
#pragma unroll
        for (int i = 0; i < 4; ++i) a[i] = Ct[(tt * 4 + i) * 17 + k];
#pragma unroll
        for (int j = 0; j < 8; ++j) bb[j] = Bt[(ts * 8 + j) * 17 + k];
#pragma unroll
        for (int i = 0; i < 4; ++i)
#pragma unroll
          for (int j = 0; j < 8; ++j) acc[i][j] += a[i] * bb[j];
      }
    }
#pragma unroll
    for (int i = 0; i < 4; ++i) {
      int tl = tt * 4 + i;
      int t = half * 64 + tl;
#pragma unroll
      for (int j = 0; j < 8; ++j) {
        int s = ts * 8 + j;
        float v = 0.f;
        if (s <= t) v = __expf(Lc_s[t] - Lc_s[s]) * dt_s[s] * acc[i][j];
        Ms[tl][s] = v;
      }
    }
    float ya[4][4];
#pragma unroll
    for (int i = 0; i < 4; ++i)
#pragma unroll
      for (int j = 0; j < 4; ++j) ya[i][j] = 0.f;
    const int smax = half ? 128 : 64;
    for (int s0 = 0; s0 < smax; s0 += 16) {
      __syncthreads();
      for (int q = tid; q < 1024; q += 256) {
        int r = q >> 6, p = q & 63;
        int s = s0 + r;
        Xt[r * 65 + p] = (s < qc) ? xb[((size_t)(t0 + s)) * 768 + h * 64 + p] : 0.f;
      }
      __syncthreads();
#pragma unroll
      for (int k = 0; k < 16; ++k) {
        float a[4], xx[4];
#pragma unroll
        for (int i = 0; i < 4; ++i) a[i] = Ms[tt * 4 + i][s0 + k];
#pragma unroll
        for (int j = 0; j < 4; ++j) xx[j] = Xt[k * 65 + ts * 4 + j];
#pragma unroll
        for (int i = 0; i < 4; ++i)
#pragma unroll
          for (int j = 0; j < 4; ++j) ya[i][j] += a[i] * xx[j];
      }
    }
#pragma unroll
    for (int i = 0; i < 4; ++i) {
      int t = half * 64 + tt * 4 + i;
      if (t < qc) {
        float* yp = ybuf + ((size_t)b * L + t0 + t) * 512 + h * 64 + ts * 4;
#pragma unroll
        for (int j = 0; j < 4; ++j) yp[j] = ya[i][j];
      }
    }
    __syncthreads();
  }

  float sa[4][8];
#pragma unroll
  for (int i = 0; i < 4; ++i)
#pragma unroll
    for (int j = 0; j < 8; ++j) sa[i][j] = 0.f;
  const float Lend = Lc_s[qc - 1];
  for (int s0 = 0; s0 < 128; s0 += 16) {
    __syncthreads();
    for (int q = tid; q < 1024; q += 256) {
      int r = q >> 6, p = q & 63;
      int s = s0 + r;
      float w2 = __expf(Lend - Lc_s[s]) * dt_s[s];
      Xw[r * 65 + p] = (s < qc) ? w2 * xb[((size_t)(t0 + s)) * 768 + h * 64 + p] : 0.f;
    }
    for (int q = tid; q < 2048; q += 256) {
      int r = q >> 7, n = q & 127;
      int s = s0 + r;
      Bt2[r * 130 + n] = (s < qc) ? xb[((size_t)(t0 + s)) * 768 + 512 + n] : 0.f;
    }
    __syncthreads();
#pragma unroll
    for (int k = 0; k < 16; ++k) {
      float a[4], bb[8];
#pragma unroll
      for (int i = 0; i < 4; ++i) a[i] = Xw[k * 65 + tt * 4 + i];
#pragma unroll
      for (int j = 0; j < 8; ++j) bb[j] = Bt2[k * 130 + ts * 8 + j];
#pragma unroll
      for (int i = 0; i < 4; ++i)
#pragma unroll
        for (int j = 0; j < 8; ++j) sa[i][j] += a[i] * bb[j];
    }
  }
  float* scp = sc + (((size_t)b * 8 + h) * 17 + c) * 8192;
#pragma unroll
  for (int i = 0; i < 4; ++i) {
    int p = tt * 4 + i;
#pragma unroll
    for (int j = 0; j < 8; ++j) scp[p * 128 + ts * 8 + j] = sa[i][j];
  }
}

__global__ __launch_bounds__(256) void k_ssd_scan(float* __restrict__ sc, const float* __restrict__ dtot) {
  const int h = blockIdx.x, b = blockIdx.y;
  const int tid = threadIdx.x;
  float* base = sc + ((size_t)b * 8 + h) * 17 * 8192;
  const float* dtp = dtot + ((size_t)b * 8 + h) * 17;
  float hc[32];
#pragma unroll
  for (int k = 0; k < 32; ++k) hc[k] = 0.f;
  for (int cc = 0; cc < 17; ++cc) {
    float D = dtp[cc];
    float* p = base + (size_t)cc * 8192;
#pragma unroll
    for (int k = 0; k < 32; ++k) {
      float t = p[tid + k * 256];
      p[tid + k * 256] = hc[k];
      hc[k] = hc[k] * D + t;
    }
  }
}

__global__ __launch_bounds__(256) void k_ssd_inter(const float* __restrict__ xBC,
                                                   const float* __restrict__ ldg,
                                                   const float* __restrict__ sc,
                                                   const float* __restrict__ Dh,
                                                   float* __restrict__ ybuf) {
  const int L = 2049;
  const int c = blockIdx.x, h = blockIdx.y, b = blockIdx.z;
  const int tid = threadIdx.x;
  const int t0 = c * 128;
  int qc = L - t0; if (qc > 128) qc = 128;
  __shared__ float Ct[128][17];
  __shared__ float H0[64][17];
  __shared__ float ld_s[128], Lc_s[128];
  if (tid < 128)
    ld_s[tid] = (tid < qc) ? ldg[((size_t)b * L + t0 + tid) * 8 + h] : 0.f;
  __syncthreads();
  if (tid == 0) { float a = 0.f; for (int i = 0; i < 128; ++i) { a += ld_s[i]; Lc_s[i] = a; } }
  __syncthreads();
  const float* xb = xBC + ((size_t)b * L) * 768;
  const float* hp = sc + (((size_t)b * 8 + h) * 17 + c) * 8192;
  const int tt = tid >> 4, ts = tid & 15;
  float acc[8][4];
#pragma unroll
  for (int i = 0; i < 8; ++i)
#pragma unroll
    for (int j = 0; j < 4; ++j) acc[i][j] = 0.f;
  for (int n0 = 0; n0 < 128; n0 += 16) {
    __syncthreads();
    for (int q = tid; q < 2048; q += 256) {
      int r = q >> 4, k = q & 15;
      Ct[r][k] = (r < qc) ? xb[((size_t)(t0 + r)) * 768 + 640 + n0 + k] : 0.f;
    }
    for (int q = tid; q < 1024; q += 256) {
      int r = q >> 4, k = q & 15;
      H0[r][k] = hp[r * 128 + n0 + k];
    }
    __syncthreads();
#pragma unroll
    for (int k = 0; k < 16; ++k) {
      float a[8], bb[4];
#pragma unroll
      for (int i = 0; i < 8; ++i) a[i] = Ct[tt * 8 + i][k];
#pragma unroll
      for (int j = 0; j < 4; ++j) bb[j] = H0[ts * 4 + j][k];
#pragma unroll
      for (int i = 0; i < 8; ++i)
#pragma unroll
        for (int j = 0; j < 4; ++j) acc[i][j] += a[i] * bb[j];
    }
  }
  const float DD = Dh[h];
#pragma unroll
  for (int i = 0; i < 8; ++i) {
    int t = tt * 8 + i;
    if (t >= qc) continue;
    float e = __expf(Lc_s[t]);
    size_t lt = (size_t)(t0 + t);
    float* yp = ybuf + ((size_t)b * L + lt) * 512 + h * 64 + ts * 4;
    const float* xp = xb + lt * 768 + h * 64 + ts * 4;
#pragma unroll
    for (int j = 0; j < 4; ++j) yp[j] += e * acc[i][j] + DD * xp[j];
  }
}

// ---------------- y = y*silu(z); RMS-norm over 512; *norm_w ; write bf16
__global__ __launch_bounds__(256) void k_gaterms(const float* __restrict__ y, const float* __restrict__ zx,
                                                 const float* __restrict__ nw, u16* __restrict__ y2,
                                                 int Mc) {
  int row = blockIdx.x * 4 + (threadIdx.x >> 6);
  if (row >= Mc) return;
  int lane = threadIdx.x & 63;
  const float* yr = y + (size_t)row * 512 + lane * 8;
  const float* zr = zx + (size_t)row * 1288 + lane * 8;
  float g[8];
  float ss = 0.f;
#pragma unroll
  for (int j = 0; j < 8; ++j) {
    float yv = yr[j], zv = zr[j];
    float sig = 1.f / (1.f + expf(-zv));
    float gg = yv * zv * sig;
    g[j] = gg;
    ss += gg * gg;
  }
#pragma unroll
  for (int off = 32; off > 0; off >>= 1) ss += __shfl_xor(ss, off);
  float r = rsqrtf(ss * (1.f / 512.f) + EPSF);
#pragma unroll
  for (int j = 0; j < 8; ++j)
    y2[(size_t)row * 512 + lane * 8 + j] = f2bf(g[j] * r * nw[lane * 8 + j]);
}

// ---------------- final LayerNorm over E=256 for rows t=1..2048 (wave per row)
__global__ __launch_bounds__(256) void k_ln(const float* __restrict__ u, const float* __restrict__ g,
                                            const float* __restrict__ bb, float* __restrict__ out) {
  int rid = blockIdx.x * 4 + (threadIdx.x >> 6);
  int lane = threadIdx.x & 63;
  int b = rid >> 11;
  int t = (rid & 2047) + 1;
  const float* ur = u + ((size_t)b * 2049 + t) * 256 + lane * 4;
  float v[4];
  float s1 = 0.f, s2 = 0.f;
#pragma unroll
  for (int j = 0; j < 4; ++j) {
    v[j] = ur[j];
    s1 += v[j];
    s2 += v[j] * v[j];
  }
#pragma unroll
  for (int off = 32; off > 0; off >>= 1) {
    s1 += __shfl_xor(s1, off);
    s2 += __shfl_xor(s2, off);
  }
  float mu = s1 * (1.f / 256.f);
  float var = s2 * (1.f / 256.f) - mu * mu;
  float rs = rsqrtf(var + EPSF);
  float* orow = out + ((size_t)b * 2048 + (t - 1)) * 256 + lane * 4;
#pragma unroll
  for (int j = 0; j < 4; ++j) orow[j] = (v[j] - mu) * rs * g[lane * 4 + j] + bb[lane * 4 + j];
}

// ---------------- masked pool partials
__global__ __launch_bounds__(256) void k_pp(const float* __restrict__ hln, const int* __restrict__ idx,
                                            float* __restrict__ part) {
  int ch = blockIdx.x;
  int b = blockIdx.y;
  int e = threadIdx.x;
  int agg = idx[b] / 6;
  int t0 = ch * 256;
  int tend = agg + 1 - t0;
  if (tend > 256) tend = 256;
  float s = 0.f;
  for (int i = 0; i < tend; ++i) s += hln[((size_t)b * 2048 + t0 + i) * 256 + e];
  part[((size_t)b * 8 + ch) * 256 + e] = s;
}

// ---------------- pooled @ fc_w + fc_b
__global__ __launch_bounds__(256) void k_fc(const float* __restrict__ part, const int* __restrict__ idx,
                                            const float* __restrict__ fw, const float* __restrict__ fb,
                                            float* __restrict__ out) {
  __shared__ float pooled[256];
  int b = blockIdx.x;
  int tid = threadIdx.x;
  float s = 0.f;
#pragma unroll
  for (int ch = 0; ch < 8; ++ch) s += part[((size_t)b * 8 + ch) * 256 + tid];
  pooled[tid] = s;
  __syncthreads();
  if (tid < 100) {
    int agg = idx[b] / 6;
    float inv = 1.f / (float)(agg + 1);
    float acc = 0.f;
    for (int e = 0; e < 256; ++e) acc += pooled[e] * fw[e * 100 + tid];
    out[b * 100 + tid] = acc * inv + fb[tid];
  }
}

extern "C" void kernel_launch(void* const* d_in, const int* in_sizes, int n_in,
                              void* d_out, int out_size, void* d_ws, size_t ws_size,
                              hipStream_t stream) {
  (void)in_sizes; (void)n_in; (void)out_size;
  const float* x        = (const float*)d_in[0];
  const int*   idx      = (const int*)d_in[1];
  const float* patch_w  = (const float*)d_in[2];
  const float* patch_b  = (const float*)d_in[3];
  const float* conv_w   = (const float*)d_in[4];
  const float* conv_b   = (const float*)d_in[5];
  const float* bn_g     = (const float*)d_in[6];
  const float* bn_b     = (const float*)d_in[7];
  const float* cls_tok  = (const float*)d_in[8];
  const float* pos_emb  = (const float*)d_in[9];
  const float* Wi       = (const float*)d_in[10];
  const float* cw       = (const float*)d_in[11];
  const float* cb       = (const float*)d_in[12];
  const float* dt_bias  = (const float*)d_in[13];
  const float* A_log    = (const float*)d_in[14];
  const float* Dh       = (const float*)d_in[15];
  const float* norm_w   = (const float*)d_in[16];
  const float* Wo       = (const float*)d_in[17];
  const float* ln_g     = (const float*)d_in[18];
  const float* ln_b     = (const float*)d_in[19];
  const float* fc_w     = (const float*)d_in[20];
  const float* fc_b     = (const float*)d_in[21];
  float* out = (float*)d_out;
  float* ws = (float*)d_ws;

  // workspace accounting in floats
  size_t CB = 4;
  {
    size_t per = 2ull * 3145728 + 2ull * 16392 + 1114112 + 262272;   // bufs + dt/ld + scb + u_bf
    size_t need4 = (8392704ull + 4ull * per + 32768 + 1024 + 1318912 + 524288 + 655360) * 4ull;
    if (ws_size < need4) CB = 2;
  }
  const int NCHUNK = (int)(16 / CB);
  const int Mc = (int)(CB * 2049);

  float* u    = ws;                              // 8392704
  float* bufA = u + 8392704;                     // CB*3145728
  float* bufB = bufA + CB * 3145728;             // CB*3145728
  float* dtb  = bufB + CB * 3145728;             // CB*16392
  float* ldb  = dtb + CB * 16392;                // CB*16392
  float* ppar = ldb + CB * 16392;                // 32768
  float* scb  = ppar + 32768;                    // CB*8*17*8192 = CB*1114112
  float* dtot = scb + CB * 1114112;              // pad 1024
  u16*  u_bf  = (u16*)(dtot + 1024);             // Mc*256 u16 = CB*262272 floats
  u16*  WiT   = (u16*)((float*)u_bf + CB * 262272);   // 1318912 floats
  u16*  WoT   = (u16*)((float*)WiT + 1318912);        // 524288 floats
  u16*  wbf   = (u16*)((float*)WoT + 524288);         // 655360 floats
  float* hln  = bufA;

  u16* bufA16 = (u16*)bufA;
  u16* bufB16 = (u16*)bufB;

  // ---- weight prep
  k_wconv<<<dim3((4 * 256 * 256 * 5 + 255) / 256), 256, 0, stream>>>(conv_w, wbf);
  k_wti<<<dim3((8 * 1288 * 256 + 255) / 256), 256, 0, stream>>>(Wi, WiT);
  k_wto<<<dim3((8 * 256 * 512 + 255) / 256), 256, 0, stream>>>(Wo, WoT);

  // ---- conv frontend (bf16, [L][C] layout), batch-chunked
  for (int bc = 0; bc < NCHUNK; ++bc) {
    const float* xc = x + (size_t)bc * CB * 8 * 12288;
    float* uc = u + (size_t)bc * CB * 2049 * 256;
    k_patchm<<<dim3(192, (unsigned)CB), 256, 0, stream>>>(xc, patch_w, patch_b, bufA16);
    k_convm<<<dim3(96, 4, (unsigned)CB), 256, 0, stream>>>(bufA16, wbf + 0 * 327680, conv_b + 0, bn_g + 0, bn_b + 0, bufB16, 12288);
    k_convm<<<dim3(96, 4, (unsigned)CB), 256, 0, stream>>>(bufB16, wbf + 1 * 327680, conv_b + 256, bn_g + 256, bn_b + 256, bufA16, 12288);
    {
      size_t tot = CB * 4096 * 256;
      k_mpb<<<dim3((unsigned)((tot + 255) / 256)), 256, 0, stream>>>(bufA16, bufB16, 4096, 3, tot);
    }
    k_convm<<<dim3(32, 4, (unsigned)CB), 256, 0, stream>>>(bufB16, wbf + 2 * 327680, conv_b + 512, bn_g + 512, bn_b + 512, bufA16, 4096);
    k_convm<<<dim3(32, 4, (unsigned)CB), 256, 0, stream>>>(bufA16, wbf + 3 * 327680, conv_b + 768, bn_g + 768, bn_b + 768, bufB16, 4096);
    {
      size_t tot = CB * 2048 * 256;
      k_mpb<<<dim3((unsigned)((tot + 255) / 256)), 256, 0, stream>>>(bufB16, bufA16, 2048, 2, tot);
    }
    k_asmb<<<dim3(2048, (unsigned)CB), 256, 0, stream>>>(bufA16, pos_emb, uc);
  }
  k_cls<<<dim3(1), 256, 0, stream>>>(cls_tok, pos_emb, u);

  // ---- mamba layers
  float* zx   = bufA;                         // (CB,2049,1288) f32
  float* xBC  = bufB;                         // (CB,2049,768) f32
  float* ybuf = bufB + (size_t)CB * 2049 * 768;  // (CB,2049,512) f32
  u16*  y2bf  = (u16*)bufB;                   // overwrites xBC (safe: ssd done)

  const unsigned gy = (unsigned)((Mc + 127) / 128);
  for (int l = 0; l < 8; ++l) {
    const u16* WiTl = WiT + (size_t)l * 1288 * 256;
    const u16* WoTl = WoT + (size_t)l * 256 * 512;
    const float* cwl  = cw + (size_t)l * 768 * 4;
    const float* cbl  = cb + (size_t)l * 768;
    const float* dtbl = dt_bias + l * 8;
    const float* all  = A_log + l * 8;
    const float* dhl  = Dh + l * 8;
    const float* nwl  = norm_w + (size_t)l * 512;
    for (int bc = 0; bc < NCHUNK; ++bc) {
      float* uc = u + (size_t)bc * CB * 2049 * 256;
      k_castu<<<dim3((unsigned)Mc), 256, 0, stream>>>(uc, u_bf, Mc * 256);
      k_gemmm<0><<<dim3(21, gy), 256, 0, stream>>>(u_bf, WiTl, zx, Mc, 1288, 256);
      k_dtda<<<dim3((unsigned)((Mc * 8 + 255) / 256)), 256, 0, stream>>>(zx, dtbl, all, dtb, ldb, Mc * 8);
      k_dw<<<dim3(3, 2049, (unsigned)CB), 256, 0, stream>>>(zx, cwl, cbl, xBC);
      k_ssd_intra<<<dim3(17, 8, (unsigned)CB), 256, 0, stream>>>(xBC, dtb, ldb, ybuf, scb, dtot);
      k_ssd_scan<<<dim3(8, (unsigned)CB), 256, 0, stream>>>(scb, dtot);
      k_ssd_inter<<<dim3(17, 8, (unsigned)CB), 256, 0, stream>>>(xBC, ldb, scb, dhl, ybuf);
      k_gaterms<<<dim3((unsigned)((Mc + 3) / 4)), 256, 0, stream>>>(ybuf, zx, nwl, y2bf, Mc);
      k_gemmm<1><<<dim3(4, gy), 256, 0, stream>>>(y2bf, WoTl, uc, Mc, 256, 512);
    }
  }

  // ---- final LN + masked pool + fc
  k_ln<<<dim3(8192), 256, 0, stream>>>(u, ln_g, ln_b, hln);
  k_pp<<<dim3(8, 16), 256, 0, stream>>>(hln, idx, ppar);
  k_fc<<<dim3(16), 256, 0, stream>>>(ppar, idx, fc_w, fc_b, out);
}

// Round 5
// 13915.364 us; speedup vs baseline: 3.7667x; 1.0580x over previous
//
#include <hip/hip_runtime.h>
#include <cstdint>
#include <cstddef>

#define EPSF 1e-5f

typedef unsigned short u16;
typedef __attribute__((ext_vector_type(8))) short short8v;
typedef __attribute__((ext_vector_type(4))) float f32x4;

static __device__ __forceinline__ u16 f2bf(float f) {
  union { float f; unsigned u; } v; v.f = f;
  unsigned r = v.u + 0x7fffu + ((v.u >> 16) & 1u);
  return (u16)(r >> 16);
}
static __device__ __forceinline__ float bf2f(u16 h) {
  union { unsigned u; float f; } v; v.u = ((unsigned)h) << 16;
  return v.f;
}

// ---------------- weight prep ----------------
__global__ void k_wconv(const float* __restrict__ src, u16* __restrict__ dst) {
  int i = blockIdx.x * 256 + threadIdx.x;
  if (i >= 4 * 256 * 256 * 5) return;
  int k = i % 5, r = i / 5;
  int ci = r & 255; r >>= 8;
  int co = r & 255; int l = r >> 8;
  dst[(((size_t)l * 256 + co) * 5 + k) * 256 + ci] = f2bf(src[i]);
}
__global__ void k_wti(const float* __restrict__ src, u16* __restrict__ dst) {
  int i = blockIdx.x * 256 + threadIdx.x;
  if (i >= 8 * 1288 * 256) return;
  int k = i & 255; int r = i >> 8;
  int n = r % 1288; int l = r / 1288;
  dst[i] = f2bf(src[((size_t)l * 256 + k) * 1288 + n]);
}
__global__ void k_wto(const float* __restrict__ src, u16* __restrict__ dst) {
  int i = blockIdx.x * 256 + threadIdx.x;
  if (i >= 8 * 256 * 512) return;
  int k = i & 511; int r = i >> 9;
  int n = r & 255; int l = r >> 8;
  dst[i] = f2bf(src[((size_t)l * 512 + k) * 256 + n]);
}

// ---------------- patch embed -> [b][L][256] bf16
__global__ __launch_bounds__(256) void k_patchm(const float* __restrict__ x, const float* __restrict__ pw,
                                                const float* __restrict__ pb, u16* __restrict__ outb) {
  __shared__ float xs[8][64];
  const int l0 = blockIdx.x * 64;
  const int b = blockIdx.y;
  const int tid = threadIdx.x;
  const float* xb = x + (size_t)b * 8 * 12288;
  for (int q = tid; q < 512; q += 256) {
    int p = q >> 6, ll = q & 63;
    xs[p][ll] = xb[(size_t)p * 12288 + l0 + ll];
  }
  __syncthreads();
  float pwr[8];
#pragma unroll
  for (int p = 0; p < 8; ++p) pwr[p] = pw[tid * 8 + p];
  const float bias = pb[tid];
  u16* ob = outb + ((size_t)b * 12288 + l0) * 256 + tid;
  for (int ll = 0; ll < 64; ++ll) {
    float acc = bias;
#pragma unroll
    for (int p = 0; p < 8; ++p) acc += xs[p][ll] * pwr[p];
    ob[(size_t)ll * 256] = f2bf(acc);
  }
}

// ---------------- MFMA conv1d (256->256, K=5 causal) + BN + ReLU, [L][C] bf16
__global__ __launch_bounds__(256) void k_convm(const u16* __restrict__ in, const u16* __restrict__ wbf,
                                               const float* __restrict__ cbias, const float* __restrict__ bng,
                                               const float* __restrict__ bnb, u16* __restrict__ outb, int L) {
  __shared__ u16 Xs[132 * 40];
  __shared__ u16 Ws[64 * 168];
  const int l0 = blockIdx.x * 128;
  const int co0 = blockIdx.y * 64;
  const int b = blockIdx.z;
  const int tid = threadIdx.x;
  const int w = tid >> 6, l = tid & 63;
  const int mhalf = (w >> 1) * 64, nhalf = (w & 1) * 32;
  const u16* inb = in + (size_t)b * L * 256;
  u16* outbb = outb + (size_t)b * L * 256;
  f32x4 acc[4][2] = {};
  for (int ci0 = 0; ci0 < 256; ci0 += 32) {
    __syncthreads();
    for (int q = tid; q < 528; q += 256) {
      int row = q >> 2, coff = (q & 3) * 8;
      int gl = l0 - 4 + row;
      short8v v = {};
      if (gl >= 0) v = *(const short8v*)(inb + (size_t)gl * 256 + ci0 + coff);
      *(short8v*)(Xs + row * 40 + coff) = v;
    }
    for (int q = tid; q < 1280; q += 256) {
      int co = q / 20, rem = q % 20, k = rem >> 2, coff = (rem & 3) * 8;
      *(short8v*)(Ws + co * 168 + k * 32 + coff) =
          *(const short8v*)(wbf + ((size_t)(co0 + co) * 5 + k) * 256 + ci0 + coff);
    }
    __syncthreads();
    const int koff = (l >> 4) * 8;
    const int arow = mhalf + (l & 15);
    const int bro0 = (nhalf + (l & 15)) * 168;
    const int bro1 = (nhalf + 16 + (l & 15)) * 168;
#pragma unroll
    for (int k = 0; k < 5; ++k) {
      short8v b0 = *(const short8v*)(Ws + bro0 + k * 32 + koff);
      short8v b1 = *(const short8v*)(Ws + bro1 + k * 32 + koff);
#pragma unroll
      for (int mi = 0; mi < 4; ++mi) {
        short8v a = *(const short8v*)(Xs + (arow + mi * 16 + k) * 40 + koff);
        acc[mi][0] = __builtin_amdgcn_mfma_f32_16x16x32_bf16(a, b0, acc[mi][0], 0, 0, 0);
        acc[mi][1] = __builtin_amdgcn_mfma_f32_16x16x32_bf16(a, b1, acc[mi][1], 0, 0, 0);
      }
    }
  }
  const float scn = rsqrtf(1.f + EPSF);
#pragma unroll
  for (int ni = 0; ni < 2; ++ni) {
    int co = co0 + nhalf + ni * 16 + (l & 15);
    float alpha = bng[co] * scn;
    float beta = cbias[co] * alpha + bnb[co];
#pragma unroll
    for (int mi = 0; mi < 4; ++mi)
#pragma unroll
      for (int r = 0; r < 4; ++r) {
        int row = l0 + mhalf + mi * 16 + (l >> 4) * 4 + r;
        float v = acc[mi][ni][r] * alpha + beta;
        outbb[(size_t)row * 256 + co] = f2bf(fmaxf(v, 0.f));
      }
  }
}

// ---------------- maxpool over L dim, [L][C] bf16
__global__ void k_mpb(const u16* __restrict__ in, u16* __restrict__ out, int Lout, int kp, size_t total) {
  size_t i = (size_t)blockIdx.x * 256 + threadIdx.x;
  if (i >= total) return;
  size_t c = i & 255;
  size_t rest = i >> 8;
  size_t lo = rest % (size_t)Lout;
  size_t b = rest / (size_t)Lout;
  const u16* p = in + (b * (size_t)Lout * kp + lo * kp) * 256 + c;
  float m = bf2f(p[0]);
  for (int j = 1; j < kp; ++j) m = fmaxf(m, bf2f(p[(size_t)j * 256]));
  out[i] = f2bf(m);
}

// ---------------- assemble u rows 0..2048 (f32 + bf16) ; row0 = cls+pos
__global__ __launch_bounds__(256) void k_asmb(const u16* __restrict__ in, const float* __restrict__ pos,
                                              const float* __restrict__ cls, float* __restrict__ uc,
                                              u16* __restrict__ ubc) {
  int t = blockIdx.x;           // 0..2048
  int b = blockIdx.y;
  int e = threadIdx.x;
  float v;
  if (t == 0)
    v = cls[e] + pos[e];
  else
    v = bf2f(in[((size_t)b * 2048 + (t - 1)) * 256 + e]) + pos[(size_t)t * 256 + e];
  size_t o = ((size_t)b * 2049 + t) * 256 + e;
  uc[o] = v;
  ubc[o] = f2bf(v);
}

// ---------------- MFMA GEMM: C[M,N] (=/+=) A_bf[M,K] @ BT_bf[N,K]; K%32==0
// ACC==1 additionally writes bf16 copy of updated C to ubf.
template <int ACC>
__global__ __launch_bounds__(256) void k_gemmm(const u16* __restrict__ A, const u16* __restrict__ BT,
                                               float* __restrict__ C, u16* __restrict__ ubf,
                                               int M, int N, int K) {
  __shared__ u16 As[128 * 40];
  __shared__ u16 Bs[64 * 40];
  const int n0 = blockIdx.x * 64;
  const int m0 = blockIdx.y * 128;
  const int tid = threadIdx.x;
  const int w = tid >> 6, l = tid & 63;
  const int mhalf = (w >> 1) * 64, nhalf = (w & 1) * 32;
  f32x4 acc[4][2] = {};
  for (int k0 = 0; k0 < K; k0 += 32) {
    __syncthreads();
    for (int q = tid; q < 512; q += 256) {
      int row = q >> 2, koff = (q & 3) * 8;
      short8v v = {};
      if (m0 + row < M) v = *(const short8v*)(A + (size_t)(m0 + row) * K + k0 + koff);
      *(short8v*)(As + row * 40 + koff) = v;
    }
    {
      int row = tid >> 2, koff = (tid & 3) * 8;
      short8v v = {};
      if (n0 + row < N) v = *(const short8v*)(BT + (size_t)(n0 + row) * K + k0 + koff);
      *(short8v*)(Bs + row * 40 + koff) = v;
    }
    __syncthreads();
    const int koff = (l >> 4) * 8;
    short8v b0 = *(const short8v*)(Bs + (nhalf + (l & 15)) * 40 + koff);
    short8v b1 = *(const short8v*)(Bs + (nhalf + 16 + (l & 15)) * 40 + koff);
#pragma unroll
    for (int mi = 0; mi < 4; ++mi) {
      short8v a = *(const short8v*)(As + (mhalf + mi * 16 + (l & 15)) * 40 + koff);
      acc[mi][0] = __builtin_amdgcn_mfma_f32_16x16x32_bf16(a, b0, acc[mi][0], 0, 0, 0);
      acc[mi][1] = __builtin_amdgcn_mfma_f32_16x16x32_bf16(a, b1, acc[mi][1], 0, 0, 0);
    }
  }
#pragma unroll
  for (int mi = 0; mi < 4; ++mi)
#pragma unroll
    for (int r = 0; r < 4; ++r) {
      int m = m0 + mhalf + mi * 16 + (l >> 4) * 4 + r;
      if (m >= M) continue;
#pragma unroll
      for (int ni = 0; ni < 2; ++ni) {
        int n = n0 + nhalf + ni * 16 + (l & 15);
        if (n >= N) continue;
        if constexpr (ACC) {
          float v = C[(size_t)m * N + n] + acc[mi][ni][r];
          C[(size_t)m * N + n] = v;
          ubf[(size_t)m * N + n] = f2bf(v);
        } else {
          C[(size_t)m * N + n] = acc[mi][ni][r];
        }
      }
    }
}

// ---------------- dt = softplus(dtraw + bias); ld = -exp(A_log)*dt
__global__ void k_dtda(const float* __restrict__ zx, const float* __restrict__ dtb,
                       const float* __restrict__ al, float* __restrict__ dt, float* __restrict__ ld,
                       int total) {
  int i = blockIdx.x * 256 + threadIdx.x;
  if (i >= total) return;
  int hh = i & 7;
  size_t row = (size_t)(i >> 3);
  float v = zx[row * 1288 + 1280 + hh] + dtb[hh];
  float d = (v > 20.f) ? v : log1pf(expf(v));
  dt[i] = d;
  ld[i] = -expf(al[hh]) * d;
}

// ---------------- depthwise causal conv K=4 + silu; sliding-window, t-tiled
__global__ __launch_bounds__(256) void k_dw(const float* __restrict__ zx, const float* __restrict__ cw,
                                            const float* __restrict__ cb, float* __restrict__ xBC) {
  int c = blockIdx.x * 256 + threadIdx.x;  // 0..767
  int t0 = blockIdx.y * 64;
  int b = blockIdx.z;
  const float* col = zx + ((size_t)b * 2049) * 1288 + 512 + c;
  float cw0 = cw[c * 4 + 0], cw1 = cw[c * 4 + 1], cw2 = cw[c * 4 + 2], cw3 = cw[c * 4 + 3];
  const float bias = cb[c];
  float w0 = 0.f, w1 = 0.f, w2 = 0.f;
  if (t0 - 3 >= 0) w0 = col[(size_t)(t0 - 3) * 1288];
  if (t0 - 2 >= 0) w1 = col[(size_t)(t0 - 2) * 1288];
  if (t0 - 1 >= 0) w2 = col[(size_t)(t0 - 1) * 1288];
  int tend = t0 + 64; if (tend > 2049) tend = 2049;
  float* ob = xBC + ((size_t)b * 2049) * 768 + c;
  for (int t = t0; t < tend; ++t) {
    float v = col[(size_t)t * 1288];
    float acc = bias + w0 * cw0 + w1 * cw1 + w2 * cw2 + v * cw3;
    float sig = 1.f / (1.f + expf(-acc));
    ob[(size_t)t * 768] = acc * sig;
    w0 = w1; w1 = w2; w2 = v;
  }
}

// ================= chunked SSD scan (Q=128, 17 chunks over L=2049) =================
__global__ __launch_bounds__(256) void k_ssd_intra(const float* __restrict__ xBC,
                                                   const float* __restrict__ dtg,
                                                   const float* __restrict__ ldg,
                                                   float* __restrict__ ybuf,
                                                   float* __restrict__ sc,
                                                   float* __restrict__ dtot) {
  const int L = 2049;
  const int c = blockIdx.x, h = blockIdx.y, b = blockIdx.z;
  const int tid = threadIdx.x;
  const int t0 = c * 128;
  int qc = L - t0; if (qc > 128) qc = 128;

  __shared__ float Ms[64][130];
  __shared__ float Sb[3264];
  __shared__ float dt_s[128], ld_s[128], Lc_s[128];

  if (tid < 128) {
    float d = 0.f, lv = 0.f;
    if (tid < qc) {
      size_t rowi = ((size_t)b * L + t0 + tid) * 8 + h;
      d = dtg[rowi]; lv = ldg[rowi];
    }
    dt_s[tid] = d; ld_s[tid] = lv;
  }
  __syncthreads();
  if (tid == 0) {
    float a = 0.f;
    for (int i = 0; i < 128; ++i) { a += ld_s[i]; Lc_s[i] = a; }
    dtot[((size_t)b * 8 + h) * 17 + c] = __expf(Lc_s[qc - 1]);
  }
  __syncthreads();

  const float* xb = xBC + ((size_t)b * L) * 768;
  const int tt = tid >> 4, ts = tid & 15;

  float* Ct = Sb;
  float* Bt = Sb + 1088;
  float* Xt = Sb;
  float* Xw = Sb;
  float* Bt2 = Sb + 1040;

  for (int half = 0; half < 2; ++half) {
    float acc[4][8];
#pragma unroll
    for (int i = 0; i < 4; ++i)
#pragma unroll
      for (int j = 0; j < 8; ++j) acc[i][j] = 0.f;
    for (int n0 = 0; n0 < 128; n0 += 16) {
      __syncthreads();
      for (int q = tid; q < 1024; q += 256) {
        int r = q >> 4, k = q & 15;
        int t = half * 64 + r;
        Ct[r * 17 + k] = (t < qc) ? xb[((size_t)(t0 + t)) * 768 + 640 + n0 + k] : 0.f;
      }
      for (int q = tid; q < 2048; q += 256) {
        int r = q >> 4, k = q & 15;
        Bt[r * 17 + k] = (r < qc) ? xb[((size_t)(t0 + r)) * 768 + 512 + n0 + k] : 0.f;
      }
      __syncthreads();
#pragma unroll
      for (int k = 0; k < 16; ++k) {
        float a[4], bb[8];
#pragma unroll
        for (int i = 0; i < 4; ++i) a[i] = Ct[(tt * 4 + i) * 17 + k];
#pragma unroll
        for (int j = 0; j < 8; ++j) bb[j] = Bt[(ts * 8 + j) * 17 + k];
#pragma unroll
        for (int i = 0; i < 4; ++i)
#pragma unroll
          for (int j = 0; j < 8; ++j) acc[i][j] += a[i] * bb[j];
      }
    }
#pragma unroll
    for (int i = 0; i < 4; ++i) {
      int tl = tt * 4 + i;
      int t = half * 64 + tl;
#pragma unroll
      for (int j = 0; j < 8; ++j) {
        int s = ts * 8 + j;
        float v = 0.f;
        if (s <= t) v = __expf(Lc_s[t] - Lc_s[s]) * dt_s[s] * acc[i][j];
        Ms[tl][s] = v;
      }
    }
    float ya[4][4];
#pragma unroll
    for (int i = 0; i < 4; ++i)
#pragma unroll
      for (int j = 0; j < 4; ++j) ya[i][j] = 0.f;
    const int smax = half ? 128 : 64;
    for (int s0 = 0; s0 < smax; s0 += 16) {
      __syncthreads();
      for (int q = tid; q < 1024; q += 256) {
        int r = q >> 6, p = q & 63;
        int s = s0 + r;
        Xt[r * 65 + p] = (s < qc) ? xb[((size_t)(t0 + s)) * 768 + h * 64 + p] : 0.f;
      }
      __syncthreads();
#pragma unroll
      for (int k = 0; k < 16; ++k) {
        float a[4], xx[4];
#pragma unroll
        for (int i = 0; i < 4; ++i) a[i] = Ms[tt * 4 + i][s0 + k];
#pragma unroll
        for (int j = 0; j < 4; ++j) xx[j] = Xt[k * 65 + ts * 4 + j];
#pragma unroll
        for (int i = 0; i < 4; ++i)
#pragma unroll
          for (int j = 0; j < 4; ++j) ya[i][j] += a[i] * xx[j];
      }
    }
#pragma unroll
    for (int i = 0; i < 4; ++i) {
      int t = half * 64 + tt * 4 + i;
      if (t < qc) {
        float* yp = ybuf + ((size_t)b * L + t0 + t) * 512 + h * 64 + ts * 4;
#pragma unroll
        for (int j = 0; j < 4; ++j) yp[j] = ya[i][j];
      }
    }
    __syncthreads();
  }

  float sa[4][8];
#pragma unroll
  for (int i = 0; i < 4; ++i)
#pragma unroll
    for (int j = 0; j < 8; ++j) sa[i][j] = 0.f;
  const float Lend = Lc_s[qc - 1];
  for (int s0 = 0; s0 < 128; s0 += 16) {
    __syncthreads();
    for (int q = tid; q < 1024; q += 256) {
      int r = q >> 6, p = q & 63;
      int s = s0 + r;
      float w2 = __expf(Lend - Lc_s[s]) * dt_s[s];
      Xw[r * 65 + p] = (s < qc) ? w2 * xb[((size_t)(t0 + s)) * 768 + h * 64 + p] : 0.f;
    }
    for (int q = tid; q < 2048; q += 256) {
      int r = q >> 7, n = q & 127;
      int s = s0 + r;
      Bt2[r * 130 + n] = (s < qc) ? xb[((size_t)(t0 + s)) * 768 + 512 + n] : 0.f;
    }
    __syncthreads();
#pragma unroll
    for (int k = 0; k < 16; ++k) {
      float a[4], bb[8];
#pragma unroll
      for (int i = 0; i < 4; ++i) a[i] = Xw[k * 65 + tt * 4 + i];
#pragma unroll
      for (int j = 0; j < 8; ++j) bb[j] = Bt2[k * 130 + ts * 8 + j];
#pragma unroll
      for (int i = 0; i < 4; ++i)
#pragma unroll
        for (int j = 0; j < 8; ++j) sa[i][j] += a[i] * bb[j];
    }
  }
  float* scp = sc + (((size_t)b * 8 + h) * 17 + c) * 8192;
#pragma unroll
  for (int i = 0; i < 4; ++i) {
    int p = tt * 4 + i;
#pragma unroll
    for (int j = 0; j < 8; ++j) scp[p * 128 + ts * 8 + j] = sa[i][j];
  }
}

// Phase B: parallel element-wise 17-chunk recurrence; sc[c] becomes h0 (state BEFORE chunk c)
__global__ __launch_bounds__(256) void k_ssd_scan(float* __restrict__ sc, const float* __restrict__ dtot,
                                                  int nbh) {
  int gid = blockIdx.x * 256 + threadIdx.x;
  int bh = gid >> 13;
  if (bh >= nbh) return;
  int elem = gid & 8191;
  float* base = sc + (size_t)bh * 17 * 8192 + elem;
  const float* dtp = dtot + (size_t)bh * 17;
  float hc = 0.f;
#pragma unroll
  for (int cc = 0; cc < 17; ++cc) {
    float D = dtp[cc];
    float v = base[(size_t)cc * 8192];
    base[(size_t)cc * 8192] = hc;
    hc = hc * D + v;
  }
}

__global__ __launch_bounds__(256) void k_ssd_inter(const float* __restrict__ xBC,
                                                   const float* __restrict__ ldg,
                                                   const float* __restrict__ sc,
                                                   const float* __restrict__ Dh,
                                                   float* __restrict__ ybuf) {
  const int L = 2049;
  const int c = blockIdx.x, h = blockIdx.y, b = blockIdx.z;
  const int tid = threadIdx.x;
  const int t0 = c * 128;
  int qc = L - t0; if (qc > 128) qc = 128;
  __shared__ float Ct[128][17];
  __shared__ float H0[64][17];
  __shared__ float ld_s[128], Lc_s[128];
  if (tid < 128)
    ld_s[tid] = (tid < qc) ? ldg[((size_t)b * L + t0 + tid) * 8 + h] : 0.f;
  __syncthreads();
  if (tid == 0) { float a = 0.f; for (int i = 0; i < 128; ++i) { a += ld_s[i]; Lc_s[i] = a; } }
  __syncthreads();
  const float* xb = xBC + ((size_t)b * L) * 768;
  const float* hp = sc + (((size_t)b * 8 + h) * 17 + c) * 8192;
  const int tt = tid >> 4, ts = tid & 15;
  float acc[8][4];
#pragma unroll
  for (int i = 0; i < 8; ++i)
#pragma unroll
    for (int j = 0; j < 4; ++j) acc[i][j] = 0.f;
  for (int n0 = 0; n0 < 128; n0 += 16) {
    __syncthreads();
    for (int q = tid; q < 2048; q += 256) {
      int r = q >> 4, k = q & 15;
      Ct[r][k] = (r < qc) ? xb[((size_t)(t0 + r)) * 768 + 640 + n0 + k] : 0.f;
    }
    for (int q = tid; q < 1024; q += 256) {
      int r = q >> 4, k = q & 15;
      H0[r][k] = hp[r * 128 + n0 + k];
    }
    __syncthreads();
#pragma unroll
    for (int k = 0; k < 16; ++k) {
      float a[8], bb[4];
#pragma unroll
      for (int i = 0; i < 8; ++i) a[i] = Ct[tt * 8 + i][k];
#pragma unroll
      for (int j = 0; j < 4; ++j) bb[j] = H0[ts * 4 + j][k];
#pragma unroll
      for (int i = 0; i < 8; ++i)
#pragma unroll
        for (int j = 0; j < 4; ++j) acc[i][j] += a[i] * bb[j];
    }
  }
  const float DD = Dh[h];
#pragma unroll
  for (int i = 0; i < 8; ++i) {
    int t = tt * 8 + i;
    if (t >= qc) continue;
    float e = __expf(Lc_s[t]);
    size_t lt = (size_t)(t0 + t);
    float* yp = ybuf + ((size_t)b * L + lt) * 512 + h * 64 + ts * 4;
    const float* xp = xb + lt * 768 + h * 64 + ts * 4;
#pragma unroll
    for (int j = 0; j < 4; ++j) yp[j] += e * acc[i][j] + DD * xp[j];
  }
}

// ---------------- y = y*silu(z); RMS-norm over 512; *norm_w ; write bf16
__global__ __launch_bounds__(256) void k_gaterms(const float* __restrict__ y, const float* __restrict__ zx,
                                                 const float* __restrict__ nw, u16* __restrict__ y2,
                                                 int Mc) {
  int row = blockIdx.x * 4 + (threadIdx.x >> 6);
  if (row >= Mc) return;
  int lane = threadIdx.x & 63;
  const float* yr = y + (size_t)row * 512 + lane * 8;
  const float* zr = zx + (size_t)row * 1288 + lane * 8;
  float g[8];
  float ss = 0.f;
#pragma unroll
  for (int j = 0; j < 8; ++j) {
    float yv = yr[j], zv = zr[j];
    float sig = 1.f / (1.f + expf(-zv));
    float gg = yv * zv * sig;
    g[j] = gg;
    ss += gg * gg;
  }
#pragma unroll
  for (int off = 32; off > 0; off >>= 1) ss += __shfl_xor(ss, off);
  float r = rsqrtf(ss * (1.f / 512.f) + EPSF);
#pragma unroll
  for (int j = 0; j < 8; ++j)
    y2[(size_t)row * 512 + lane * 8 + j] = f2bf(g[j] * r * nw[lane * 8 + j]);
}

// ---------------- final LayerNorm over E=256 for rows t=1..2048 (wave per row)
__global__ __launch_bounds__(256) void k_ln(const float* __restrict__ u, const float* __restrict__ g,
                                            const float* __restrict__ bb, float* __restrict__ out) {
  int rid = blockIdx.x * 4 + (threadIdx.x >> 6);
  int lane = threadIdx.x & 63;
  int b = rid >> 11;
  int t = (rid & 2047) + 1;
  const float* ur = u + ((size_t)b * 2049 + t) * 256 + lane * 4;
  float v[4];
  float s1 = 0.f, s2 = 0.f;
#pragma unroll
  for (int j = 0; j < 4; ++j) {
    v[j] = ur[j];
    s1 += v[j];
    s2 += v[j] * v[j];
  }
#pragma unroll
  for (int off = 32; off > 0; off >>= 1) {
    s1 += __shfl_xor(s1, off);
    s2 += __shfl_xor(s2, off);
  }
  float mu = s1 * (1.f / 256.f);
  float var = s2 * (1.f / 256.f) - mu * mu;
  float rs = rsqrtf(var + EPSF);
  float* orow = out + ((size_t)b * 2048 + (t - 1)) * 256 + lane * 4;
#pragma unroll
  for (int j = 0; j < 4; ++j) orow[j] = (v[j] - mu) * rs * g[lane * 4 + j] + bb[lane * 4 + j];
}

// ---------------- masked pool partials
__global__ __launch_bounds__(256) void k_pp(const float* __restrict__ hln, const int* __restrict__ idx,
                                            float* __restrict__ part) {
  int ch = blockIdx.x;
  int b = blockIdx.y;
  int e = threadIdx.x;
  int agg = idx[b] / 6;
  int t0 = ch * 256;
  int tend = agg + 1 - t0;
  if (tend > 256) tend = 256;
  float s = 0.f;
  for (int i = 0; i < tend; ++i) s += hln[((size_t)b * 2048 + t0 + i) * 256 + e];
  part[((size_t)b * 8 + ch) * 256 + e] = s;
}

// ---------------- pooled @ fc_w + fc_b
__global__ __launch_bounds__(256) void k_fc(const float* __restrict__ part, const int* __restrict__ idx,
                                            const float* __restrict__ fw, const float* __restrict__ fb,
                                            float* __restrict__ out) {
  __shared__ float pooled[256];
  int b = blockIdx.x;
  int tid = threadIdx.x;
  float s = 0.f;
#pragma unroll
  for (int ch = 0; ch < 8; ++ch) s += part[((size_t)b * 8 + ch) * 256 + tid];
  pooled[tid] = s;
  __syncthreads();
  if (tid < 100) {
    int agg = idx[b] / 6;
    float inv = 1.f / (float)(agg + 1);
    float acc = 0.f;
    for (int e = 0; e < 256; ++e) acc += pooled[e] * fw[e * 100 + tid];
    out[b * 100 + tid] = acc * inv + fb[tid];
  }
}

extern "C" void kernel_launch(void* const* d_in, const int* in_sizes, int n_in,
                              void* d_out, int out_size, void* d_ws, size_t ws_size,
                              hipStream_t stream) {
  (void)in_sizes; (void)n_in; (void)out_size;
  const float* x        = (const float*)d_in[0];
  const int*   idx      = (const int*)d_in[1];
  const float* patch_w  = (const float*)d_in[2];
  const float* patch_b  = (const float*)d_in[3];
  const float* conv_w   = (const float*)d_in[4];
  const float* conv_b   = (const float*)d_in[5];
  const float* bn_g     = (const float*)d_in[6];
  const float* bn_b     = (const float*)d_in[7];
  const float* cls_tok  = (const float*)d_in[8];
  const float* pos_emb  = (const float*)d_in[9];
  const float* Wi       = (const float*)d_in[10];
  const float* cw       = (const float*)d_in[11];
  const float* cb       = (const float*)d_in[12];
  const float* dt_bias  = (const float*)d_in[13];
  const float* A_log    = (const float*)d_in[14];
  const float* Dh       = (const float*)d_in[15];
  const float* norm_w   = (const float*)d_in[16];
  const float* Wo       = (const float*)d_in[17];
  const float* ln_g     = (const float*)d_in[18];
  const float* ln_b     = (const float*)d_in[19];
  const float* fc_w     = (const float*)d_in[20];
  const float* fc_b     = (const float*)d_in[21];
  float* out = (float*)d_out;
  float* ws = (float*)d_ws;

  // workspace accounting (floats)
  size_t CB = 4;
  {
    auto need = [](size_t cb) {
      size_t per = 2ull * 3145728 + 2ull * 16392 + 1114112 + 262272;  // bufs + dt/ld + scb + u_bf
      return (8392704ull + cb * per + 1024 + 1318912 + 524288 + 655360 + 32768) * 4ull;
    };
    if (ws_size < need(4)) CB = 2;
    if (ws_size < need(2)) CB = 1;
  }
  const int NCHUNK = (int)(16 / CB);
  const int Mc = (int)(CB * 2049);

  float* u    = ws;                              // 8392704
  float* bufA = u + 8392704;                     // CB*3145728
  float* bufB = bufA + CB * 3145728;             // CB*3145728
  float* dtb  = bufB + CB * 3145728;             // CB*16392
  float* ldb  = dtb + CB * 16392;                // CB*16392
  float* scb  = ldb + CB * 16392;                // CB*1114112
  float* dtot = scb + CB * 1114112;              // pad 1024
  u16*  u_bf  = (u16*)(dtot + 1024);             // CB*262272 floats
  u16*  WiT   = (u16*)((float*)u_bf + CB * 262272);   // 1318912 floats
  u16*  WoT   = (u16*)((float*)WiT + 1318912);        // 524288 floats
  u16*  wbf   = (u16*)((float*)WoT + 524288);         // 655360 floats
  float* ppar = (float*)wbf + 655360;                 // 32768 (at end: survives hln overlay)
  float* hln  = bufA;                                 // 16*2048*256 (dead buffers beyond bufA ok)

  u16* bufA16 = (u16*)bufA;
  u16* bufB16 = (u16*)bufB;

  // ---- weight prep
  k_wconv<<<dim3((4 * 256 * 256 * 5 + 255) / 256), 256, 0, stream>>>(conv_w, wbf);
  k_wti<<<dim3((8 * 1288 * 256 + 255) / 256), 256, 0, stream>>>(Wi, WiT);
  k_wto<<<dim3((8 * 256 * 512 + 255) / 256), 256, 0, stream>>>(Wo, WoT);

  float* zx   = bufA;                             // (CB,2049,1288) f32
  float* xBC  = bufB;                             // (CB,2049,768) f32
  float* ybuf = bufB + (size_t)CB * 2049 * 768;   // (CB,2049,512) f32
  u16*  y2bf  = (u16*)bufB;                       // overwrites xBC (safe: ssd done)

  const unsigned gy = (unsigned)((Mc + 127) / 128);

  // ---- per-chunk: frontend then all 8 layers (u_bf stays valid per chunk)
  for (int bc = 0; bc < NCHUNK; ++bc) {
    const float* xc = x + (size_t)bc * CB * 8 * 12288;
    float* uc = u + (size_t)bc * CB * 2049 * 256;

    k_patchm<<<dim3(192, (unsigned)CB), 256, 0, stream>>>(xc, patch_w, patch_b, bufA16);
    k_convm<<<dim3(96, 4, (unsigned)CB), 256, 0, stream>>>(bufA16, wbf + 0 * 327680, conv_b + 0, bn_g + 0, bn_b + 0, bufB16, 12288);
    k_convm<<<dim3(96, 4, (unsigned)CB), 256, 0, stream>>>(bufB16, wbf + 1 * 327680, conv_b + 256, bn_g + 256, bn_b + 256, bufA16, 12288);
    {
      size_t tot = CB * 4096 * 256;
      k_mpb<<<dim3((unsigned)((tot + 255) / 256)), 256, 0, stream>>>(bufA16, bufB16, 4096, 3, tot);
    }
    k_convm<<<dim3(32, 4, (unsigned)CB), 256, 0, stream>>>(bufB16, wbf + 2 * 327680, conv_b + 512, bn_g + 512, bn_b + 512, bufA16, 4096);
    k_convm<<<dim3(32, 4, (unsigned)CB), 256, 0, stream>>>(bufA16, wbf + 3 * 327680, conv_b + 768, bn_g + 768, bn_b + 768, bufB16, 4096);
    {
      size_t tot = CB * 2048 * 256;
      k_mpb<<<dim3((unsigned)((tot + 255) / 256)), 256, 0, stream>>>(bufB16, bufA16, 2048, 2, tot);
    }
    k_asmb<<<dim3(2049, (unsigned)CB), 256, 0, stream>>>(bufA16, pos_emb, cls_tok, uc, u_bf);

    for (int l = 0; l < 8; ++l) {
      const u16* WiTl = WiT + (size_t)l * 1288 * 256;
      const u16* WoTl = WoT + (size_t)l * 256 * 512;
      const float* cwl  = cw + (size_t)l * 768 * 4;
      const float* cbl  = cb + (size_t)l * 768;
      const float* dtbl = dt_bias + l * 8;
      const float* all  = A_log + l * 8;
      const float* dhl  = Dh + l * 8;
      const float* nwl  = norm_w + (size_t)l * 512;

      k_gemmm<0><<<dim3(21, gy), 256, 0, stream>>>(u_bf, WiTl, zx, nullptr, Mc, 1288, 256);
      k_dtda<<<dim3((unsigned)((Mc * 8 + 255) / 256)), 256, 0, stream>>>(zx, dtbl, all, dtb, ldb, Mc * 8);
      k_dw<<<dim3(3, 33, (unsigned)CB), 256, 0, stream>>>(zx, cwl, cbl, xBC);
      k_ssd_intra<<<dim3(17, 8, (unsigned)CB), 256, 0, stream>>>(xBC, dtb, ldb, ybuf, scb, dtot);
      k_ssd_scan<<<dim3((unsigned)(CB * 8 * 32)), 256, 0, stream>>>(scb, dtot, (int)(CB * 8));
      k_ssd_inter<<<dim3(17, 8, (unsigned)CB), 256, 0, stream>>>(xBC, ldb, scb, dhl, ybuf);
      k_gaterms<<<dim3((unsigned)((Mc + 3) / 4)), 256, 0, stream>>>(ybuf, zx, nwl, y2bf, Mc);
      k_gemmm<1><<<dim3(4, gy), 256, 0, stream>>>(y2bf, WoTl, uc, u_bf, Mc, 256, 512);
    }
  }

  // ---- final LN + masked pool + fc
  k_ln<<<dim3(8192), 256, 0, stream>>>(u, ln_g, ln_b, hln);
  k_pp<<<dim3(8, 16), 256, 0, stream>>>(hln, idx, ppar);
  k_fc<<<dim3(16), 256, 0, stream>>>(ppar, idx, fc_w, fc_b, out);
}

// Round 7
// 6710.946 us; speedup vs baseline: 7.8103x; 2.0735x over previous
//
#include <hip/hip_runtime.h>
#include <cstdint>
#include <cstddef>

#define EPSF 1e-5f

typedef unsigned short u16;
typedef __attribute__((ext_vector_type(8))) short short8v;
typedef __attribute__((ext_vector_type(4))) float f32x4;

static __device__ __forceinline__ u16 f2bf(float f) {
  union { float f; unsigned u; } v; v.f = f;
  unsigned r = v.u + 0x7fffu + ((v.u >> 16) & 1u);
  return (u16)(r >> 16);
}
static __device__ __forceinline__ float bf2f(u16 h) {
  union { unsigned u; float f; } v; v.u = ((unsigned)h) << 16;
  return v.f;
}

// ---------------- weight prep ----------------
__global__ void k_wconv(const float* __restrict__ src, u16* __restrict__ dst) {
  int i = blockIdx.x * 256 + threadIdx.x;
  if (i >= 4 * 256 * 256 * 5) return;
  int k = i % 5, r = i / 5;
  int ci = r & 255; r >>= 8;
  int co = r & 255; int l = r >> 8;
  dst[(((size_t)l * 256 + co) * 5 + k) * 256 + ci] = f2bf(src[i]);
}
__global__ void k_wti(const float* __restrict__ src, u16* __restrict__ dst) {
  int i = blockIdx.x * 256 + threadIdx.x;
  if (i >= 8 * 1288 * 256) return;
  int k = i & 255; int r = i >> 8;
  int n = r % 1288; int l = r / 1288;
  dst[i] = f2bf(src[((size_t)l * 256 + k) * 1288 + n]);
}
__global__ void k_wto(const float* __restrict__ src, u16* __restrict__ dst) {
  int i = blockIdx.x * 256 + threadIdx.x;
  if (i >= 8 * 256 * 512) return;
  int k = i & 511; int r = i >> 9;
  int n = r & 255; int l = r >> 8;
  dst[i] = f2bf(src[((size_t)l * 512 + k) * 256 + n]);
}

// ---------------- patch embed -> [b][L][256] bf16
__global__ __launch_bounds__(256) void k_patchm(const float* __restrict__ x, const float* __restrict__ pw,
                                                const float* __restrict__ pb, u16* __restrict__ outb) {
  __shared__ float xs[8][64];
  const int l0 = blockIdx.x * 64;
  const int b = blockIdx.y;
  const int tid = threadIdx.x;
  const float* xb = x + (size_t)b * 8 * 12288;
  for (int q = tid; q < 512; q += 256) {
    int p = q >> 6, ll = q & 63;
    xs[p][ll] = xb[(size_t)p * 12288 + l0 + ll];
  }
  __syncthreads();
  float pwr[8];
#pragma unroll
  for (int p = 0; p < 8; ++p) pwr[p] = pw[tid * 8 + p];
  const float bias = pb[tid];
  u16* ob = outb + ((size_t)b * 12288 + l0) * 256 + tid;
  for (int ll = 0; ll < 64; ++ll) {
    float acc = bias;
#pragma unroll
    for (int p = 0; p < 8; ++p) acc += xs[p][ll] * pwr[p];
    ob[(size_t)ll * 256] = f2bf(acc);
  }
}

// ---------------- MFMA conv1d (256->256, K=5 causal) + BN + ReLU, [L][C] bf16
__global__ __launch_bounds__(256) void k_convm(const u16* __restrict__ in, const u16* __restrict__ wbf,
                                               const float* __restrict__ cbias, const float* __restrict__ bng,
                                               const float* __restrict__ bnb, u16* __restrict__ outb, int L) {
  __shared__ u16 Xs[132 * 40];
  __shared__ u16 Ws[64 * 168];
  const int l0 = blockIdx.x * 128;
  const int co0 = blockIdx.y * 64;
  const int b = blockIdx.z;
  const int tid = threadIdx.x;
  const int w = tid >> 6, l = tid & 63;
  const int mhalf = (w >> 1) * 64, nhalf = (w & 1) * 32;
  const u16* inb = in + (size_t)b * L * 256;
  u16* outbb = outb + (size_t)b * L * 256;
  f32x4 acc[4][2] = {};
  for (int ci0 = 0; ci0 < 256; ci0 += 32) {
    __syncthreads();
    for (int q = tid; q < 528; q += 256) {
      int row = q >> 2, coff = (q & 3) * 8;
      int gl = l0 - 4 + row;
      short8v v = {};
      if (gl >= 0) v = *(const short8v*)(inb + (size_t)gl * 256 + ci0 + coff);
      *(short8v*)(Xs + row * 40 + coff) = v;
    }
    for (int q = tid; q < 1280; q += 256) {
      int co = q / 20, rem = q % 20, k = rem >> 2, coff = (rem & 3) * 8;
      *(short8v*)(Ws + co * 168 + k * 32 + coff) =
          *(const short8v*)(wbf + ((size_t)(co0 + co) * 5 + k) * 256 + ci0 + coff);
    }
    __syncthreads();
    const int koff = (l >> 4) * 8;
    const int arow = mhalf + (l & 15);
    const int bro0 = (nhalf + (l & 15)) * 168;
    const int bro1 = (nhalf + 16 + (l & 15)) * 168;
#pragma unroll
    for (int k = 0; k < 5; ++k) {
      short8v b0 = *(const short8v*)(Ws + bro0 + k * 32 + koff);
      short8v b1 = *(const short8v*)(Ws + bro1 + k * 32 + koff);
#pragma unroll
      for (int mi = 0; mi < 4; ++mi) {
        short8v a = *(const short8v*)(Xs + (arow + mi * 16 + k) * 40 + koff);
        acc[mi][0] = __builtin_amdgcn_mfma_f32_16x16x32_bf16(a, b0, acc[mi][0], 0, 0, 0);
        acc[mi][1] = __builtin_amdgcn_mfma_f32_16x16x32_bf16(a, b1, acc[mi][1], 0, 0, 0);
      }
    }
  }
  const float scn = rsqrtf(1.f + EPSF);
#pragma unroll
  for (int ni = 0; ni < 2; ++ni) {
    int co = co0 + nhalf + ni * 16 + (l & 15);
    float alpha = bng[co] * scn;
    float beta = cbias[co] * alpha + bnb[co];
#pragma unroll
    for (int mi = 0; mi < 4; ++mi)
#pragma unroll
      for (int r = 0; r < 4; ++r) {
        int row = l0 + mhalf + mi * 16 + (l >> 4) * 4 + r;
        float v = acc[mi][ni][r] * alpha + beta;
        outbb[(size_t)row * 256 + co] = f2bf(fmaxf(v, 0.f));
      }
  }
}

// ---------------- maxpool over L dim, [L][C] bf16
__global__ void k_mpb(const u16* __restrict__ in, u16* __restrict__ out, int Lout, int kp, size_t total) {
  size_t i = (size_t)blockIdx.x * 256 + threadIdx.x;
  if (i >= total) return;
  size_t c = i & 255;
  size_t rest = i >> 8;
  size_t lo = rest % (size_t)Lout;
  size_t b = rest / (size_t)Lout;
  const u16* p = in + (b * (size_t)Lout * kp + lo * kp) * 256 + c;
  float m = bf2f(p[0]);
  for (int j = 1; j < kp; ++j) m = fmaxf(m, bf2f(p[(size_t)j * 256]));
  out[i] = f2bf(m);
}

// ---------------- assemble u rows 0..2048 (f32 + bf16) ; row0 = cls+pos
__global__ __launch_bounds__(256) void k_asmb(const u16* __restrict__ in, const float* __restrict__ pos,
                                              const float* __restrict__ cls, float* __restrict__ uc,
                                              u16* __restrict__ ubc) {
  int t = blockIdx.x;
  int b = blockIdx.y;
  int e = threadIdx.x;
  float v;
  if (t == 0)
    v = cls[e] + pos[e];
  else
    v = bf2f(in[((size_t)b * 2048 + (t - 1)) * 256 + e]) + pos[(size_t)t * 256 + e];
  size_t o = ((size_t)b * 2049 + t) * 256 + e;
  uc[o] = v;
  ubc[o] = f2bf(v);
}

// ---------------- MFMA GEMM: C[M,N] (=/+=) A_bf[M,K] @ BT_bf[N,K]; K%32==0
template <int ACC>
__global__ __launch_bounds__(256) void k_gemmm(const u16* __restrict__ A, const u16* __restrict__ BT,
                                               float* __restrict__ C, u16* __restrict__ ubf,
                                               int M, int N, int K) {
  __shared__ u16 As[128 * 40];
  __shared__ u16 Bs[64 * 40];
  const int n0 = blockIdx.x * 64;
  const int m0 = blockIdx.y * 128;
  const int tid = threadIdx.x;
  const int w = tid >> 6, l = tid & 63;
  const int mhalf = (w >> 1) * 64, nhalf = (w & 1) * 32;
  f32x4 acc[4][2] = {};
  for (int k0 = 0; k0 < K; k0 += 32) {
    __syncthreads();
    for (int q = tid; q < 512; q += 256) {
      int row = q >> 2, koff = (q & 3) * 8;
      short8v v = {};
      if (m0 + row < M) v = *(const short8v*)(A + (size_t)(m0 + row) * K + k0 + koff);
      *(short8v*)(As + row * 40 + koff) = v;
    }
    {
      int row = tid >> 2, koff = (tid & 3) * 8;
      short8v v = {};
      if (n0 + row < N) v = *(const short8v*)(BT + (size_t)(n0 + row) * K + k0 + koff);
      *(short8v*)(Bs + row * 40 + koff) = v;
    }
    __syncthreads();
    const int koff = (l >> 4) * 8;
    short8v b0 = *(const short8v*)(Bs + (nhalf + (l & 15)) * 40 + koff);
    short8v b1 = *(const short8v*)(Bs + (nhalf + 16 + (l & 15)) * 40 + koff);
#pragma unroll
    for (int mi = 0; mi < 4; ++mi) {
      short8v a = *(const short8v*)(As + (mhalf + mi * 16 + (l & 15)) * 40 + koff);
      acc[mi][0] = __builtin_amdgcn_mfma_f32_16x16x32_bf16(a, b0, acc[mi][0], 0, 0, 0);
      acc[mi][1] = __builtin_amdgcn_mfma_f32_16x16x32_bf16(a, b1, acc[mi][1], 0, 0, 0);
    }
  }
#pragma unroll
  for (int mi = 0; mi < 4; ++mi)
#pragma unroll
    for (int r = 0; r < 4; ++r) {
      int m = m0 + mhalf + mi * 16 + (l >> 4) * 4 + r;
      if (m >= M) continue;
#pragma unroll
      for (int ni = 0; ni < 2; ++ni) {
        int n = n0 + nhalf + ni * 16 + (l & 15);
        if (n >= N) continue;
        if constexpr (ACC) {
          float v = C[(size_t)m * N + n] + acc[mi][ni][r];
          C[(size_t)m * N + n] = v;
          ubf[(size_t)m * N + n] = f2bf(v);
        } else {
          C[(size_t)m * N + n] = acc[mi][ni][r];
        }
      }
    }
}

// ---------------- depthwise causal conv K=4 + silu (bf16 out) ; bx==3: dt/ld
__global__ __launch_bounds__(256) void k_dw(const float* __restrict__ zx, const float* __restrict__ cw,
                                            const float* __restrict__ cb, const float* __restrict__ dtbias,
                                            const float* __restrict__ al, u16* __restrict__ xBCb,
                                            float* __restrict__ dtb, float* __restrict__ ldb) {
  const int bx = blockIdx.x;
  const int t0 = blockIdx.y * 64;
  const int b = blockIdx.z;
  if (bx == 3) {
    int h = threadIdx.x & 7, ro = threadIdx.x >> 3;
    float dbv = dtbias[h];
    float av = expf(al[h]);
#pragma unroll
    for (int it = 0; it < 2; ++it) {
      int r = t0 + it * 32 + ro;
      if (r < 2049) {
        float v = zx[((size_t)b * 2049 + r) * 1288 + 1280 + h] + dbv;
        float d = (v > 20.f) ? v : log1pf(expf(v));
        size_t o = ((size_t)b * 2049 + r) * 8 + h;
        dtb[o] = d;
        ldb[o] = -av * d;
      }
    }
    return;
  }
  int c = bx * 256 + threadIdx.x;
  const float* col = zx + ((size_t)b * 2049) * 1288 + 512 + c;
  float cw0 = cw[c * 4 + 0], cw1 = cw[c * 4 + 1], cw2 = cw[c * 4 + 2], cw3 = cw[c * 4 + 3];
  const float bias = cb[c];
  float w0 = 0.f, w1 = 0.f, w2 = 0.f;
  if (t0 - 3 >= 0) w0 = col[(size_t)(t0 - 3) * 1288];
  if (t0 - 2 >= 0) w1 = col[(size_t)(t0 - 2) * 1288];
  if (t0 - 1 >= 0) w2 = col[(size_t)(t0 - 1) * 1288];
  int tend = t0 + 64; if (tend > 2049) tend = 2049;
  u16* ob = xBCb + ((size_t)b * 2049) * 768 + c;
  for (int t = t0; t < tend; ++t) {
    float v = col[(size_t)t * 1288];
    float acc = bias + w0 * cw0 + w1 * cw1 + w2 * cw2 + v * cw3;
    float sig = 1.f / (1.f + expf(-acc));
    ob[(size_t)t * 768] = f2bf(acc * sig);
    w0 = w1; w1 = w2; w2 = v;
  }
}

// ================= MFMA chunked SSD (Q=128, 17 chunks over L=2049) =================
// intra per (c,h,b): G=C·Bᵀ (MFMA) -> Ms=mask·decay·dt·G (bf16) -> Y=Ms@X (MFMA) ;
// Sc=(w∘X)ᵀ@B (MFMA). All accum f32.
__global__ __launch_bounds__(256) void k_ssd_intra(const u16* __restrict__ xBCb,
                                                   const float* __restrict__ dtg,
                                                   const float* __restrict__ ldg,
                                                   float* __restrict__ ybuf,
                                                   float* __restrict__ sc,
                                                   float* __restrict__ dtot) {
  const int L = 2049;
  const int c = blockIdx.x, h = blockIdx.y, b = blockIdx.z;
  const int tid = threadIdx.x;
  const int w = tid >> 6, l = tid & 63;
  const int t0 = c * 128;
  int qc = L - t0; if (qc > 128) qc = 128;

  __shared__ u16 R1[128 * 136];  // Bs -> BsT
  __shared__ u16 R2[128 * 136];  // Cs -> Ms
  __shared__ u16 R3[128 * 136];  // XT (rows 0..63) | XWT (rows 64..127)
  __shared__ float dt_s[128], Lc_s[128];

  const u16* xb = xBCb + ((size_t)b * L) * 768;

  // wave0: load dt/ld + inclusive scan of ld -> Lc
  if (tid < 64) {
    int i2 = tid * 2;
    float a0 = 0.f, a1 = 0.f, d0 = 0.f, d1 = 0.f;
    if (i2 < qc) { size_t r = ((size_t)b * L + t0 + i2) * 8 + h; a0 = ldg[r]; d0 = dtg[r]; }
    if (i2 + 1 < qc) { size_t r = ((size_t)b * L + t0 + i2 + 1) * 8 + h; a1 = ldg[r]; d1 = dtg[r]; }
    dt_s[i2] = d0; dt_s[i2 + 1] = d1;
    float v = a0 + a1;
#pragma unroll
    for (int dlt = 1; dlt < 64; dlt <<= 1) {
      float t = __shfl_up(v, dlt, 64);
      if (tid >= dlt) v += t;
    }
    Lc_s[i2 + 1] = v;
    Lc_s[i2] = v - a1;
  }

  // stage Bs (R1), Cs (R2), XT (R3 rows 0..63)
  for (int q = tid; q < 2048; q += 256) {
    int row = q >> 4, off = (q & 15) * 8;
    short8v vb = {}, vc = {};
    if (row < qc) {
      const u16* src = xb + (size_t)(t0 + row) * 768;
      vb = *(const short8v*)(src + 512 + off);
      vc = *(const short8v*)(src + 640 + off);
    }
    *(short8v*)(R1 + row * 136 + off) = vb;
    *(short8v*)(R2 + row * 136 + off) = vc;
  }
  for (int q = tid; q < 8192; q += 256) {
    int s = q >> 6, p = q & 63;
    u16 v = 0;
    if (s < qc) v = xb[(size_t)(t0 + s) * 768 + h * 64 + p];
    R3[p * 136 + s] = v;
  }
  __syncthreads();  // B1

  // XWT staging (R3 rows 64..127) from XT
  {
    const float Lend = Lc_s[qc - 1];
    for (int q = tid; q < 8192; q += 256) {
      int p = q >> 7, s = q & 127;
      float w2 = __expf(Lend - Lc_s[s]) * dt_s[s];
      float xv = bf2f(R3[p * 136 + s]);
      R3[(64 + p) * 136 + s] = f2bf(xv * w2);
    }
  }

  // G = C·Bᵀ  (128×128, K=128)
  const int wm = (w >> 1) * 64, wn = (w & 1) * 64;
  f32x4 g[4][4] = {};
  const bool skipG = (wm < wn);  // strictly upper block: all masked out
  if (!skipG) {
#pragma unroll
    for (int ks = 0; ks < 4; ++ks) {
      const int koff = ks * 32 + (l >> 4) * 8;
      short8v bf[4];
#pragma unroll
      for (int ni = 0; ni < 4; ++ni)
        bf[ni] = *(const short8v*)(R1 + (wn + ni * 16 + (l & 15)) * 136 + koff);
#pragma unroll
      for (int mi = 0; mi < 4; ++mi) {
        short8v a = *(const short8v*)(R2 + (wm + mi * 16 + (l & 15)) * 136 + koff);
#pragma unroll
        for (int ni = 0; ni < 4; ++ni)
          g[mi][ni] = __builtin_amdgcn_mfma_f32_16x16x32_bf16(a, bf[ni], g[mi][ni], 0, 0, 0);
      }
    }
  }
  __syncthreads();  // B2 (G reads done)

  // Ms -> R2 ; BsT -> R1 ; dtot
#pragma unroll
  for (int mi = 0; mi < 4; ++mi)
#pragma unroll
    for (int r = 0; r < 4; ++r) {
      int t = wm + mi * 16 + (l >> 4) * 4 + r;
      float lct = Lc_s[t];
#pragma unroll
      for (int ni = 0; ni < 4; ++ni) {
        int s = wn + ni * 16 + (l & 15);
        float v = 0.f;
        if (s <= t) v = __expf(lct - Lc_s[s]) * dt_s[s] * g[mi][ni][r];
        R2[t * 136 + s] = f2bf(v);
      }
    }
  for (int q = tid; q < 16384; q += 256) {
    int s = q >> 7, n = q & 127;
    u16 v = 0;
    if (s < qc) v = xb[(size_t)(t0 + s) * 768 + 512 + n];
    R1[n * 136 + s] = v;
  }
  if (tid == 0) dtot[((size_t)b * 8 + h) * 17 + c] = __expf(Lc_s[qc - 1]);
  __syncthreads();  // B3

  // Y = Ms @ X  (128×64, K=128)
  {
    const int wmy = (w >> 1) * 64, wny = (w & 1) * 32;
    f32x4 ya[4][2] = {};
#pragma unroll
    for (int ks = 0; ks < 4; ++ks) {
      const int koff = ks * 32 + (l >> 4) * 8;
      short8v b0 = *(const short8v*)(R3 + (wny + (l & 15)) * 136 + koff);
      short8v b1 = *(const short8v*)(R3 + (wny + 16 + (l & 15)) * 136 + koff);
#pragma unroll
      for (int mi = 0; mi < 4; ++mi) {
        short8v a = *(const short8v*)(R2 + (wmy + mi * 16 + (l & 15)) * 136 + koff);
        ya[mi][0] = __builtin_amdgcn_mfma_f32_16x16x32_bf16(a, b0, ya[mi][0], 0, 0, 0);
        ya[mi][1] = __builtin_amdgcn_mfma_f32_16x16x32_bf16(a, b1, ya[mi][1], 0, 0, 0);
      }
    }
    float* yb = ybuf + ((size_t)b * L + t0) * 512 + h * 64;
#pragma unroll
    for (int mi = 0; mi < 4; ++mi)
#pragma unroll
      for (int r = 0; r < 4; ++r) {
        int t = wmy + mi * 16 + (l >> 4) * 4 + r;
        if (t >= qc) continue;
#pragma unroll
        for (int ni = 0; ni < 2; ++ni) {
          int p = wny + ni * 16 + (l & 15);
          yb[(size_t)t * 512 + p] = ya[mi][ni][r];
        }
      }
  }

  // Sc = XWTᵀ... : out[p][n] (64×128, K=128)
  {
    const int wms = (w & 1) * 32, wns = (w >> 1) * 64;
    f32x4 sa[2][4] = {};
#pragma unroll
    for (int ks = 0; ks < 4; ++ks) {
      const int koff = ks * 32 + (l >> 4) * 8;
      short8v a0 = *(const short8v*)(R3 + (64 + wms + (l & 15)) * 136 + koff);
      short8v a1 = *(const short8v*)(R3 + (64 + wms + 16 + (l & 15)) * 136 + koff);
#pragma unroll
      for (int ni = 0; ni < 4; ++ni) {
        short8v bb = *(const short8v*)(R1 + (wns + ni * 16 + (l & 15)) * 136 + koff);
        sa[0][ni] = __builtin_amdgcn_mfma_f32_16x16x32_bf16(a0, bb, sa[0][ni], 0, 0, 0);
        sa[1][ni] = __builtin_amdgcn_mfma_f32_16x16x32_bf16(a1, bb, sa[1][ni], 0, 0, 0);
      }
    }
    float* scp = sc + (((size_t)b * 8 + h) * 17 + c) * 8192;
#pragma unroll
    for (int mi = 0; mi < 2; ++mi)
#pragma unroll
      for (int r = 0; r < 4; ++r) {
        int p = wms + mi * 16 + (l >> 4) * 4 + r;
#pragma unroll
        for (int ni = 0; ni < 4; ++ni) {
          int n = wns + ni * 16 + (l & 15);
          scp[p * 128 + n] = sa[mi][ni][r];
        }
      }
  }
}

// Phase B: parallel element-wise 17-chunk recurrence; sc[c] becomes h0 (state BEFORE chunk c)
__global__ __launch_bounds__(256) void k_ssd_scan(float* __restrict__ sc, const float* __restrict__ dtot,
                                                  int nbh) {
  int gid = blockIdx.x * 256 + threadIdx.x;
  int bh = gid >> 13;
  if (bh >= nbh) return;
  int elem = gid & 8191;
  float* base = sc + (size_t)bh * 17 * 8192 + elem;
  const float* dtp = dtot + (size_t)bh * 17;
  float hc = 0.f;
#pragma unroll
  for (int cc = 0; cc < 17; ++cc) {
    float D = dtp[cc];
    float v = base[(size_t)cc * 8192];
    base[(size_t)cc * 8192] = hc;
    hc = hc * D + v;
  }
}

// inter per (c,h,b): y += exp(Lc[t])·(C[t]·h0) + Dh·xs   (MFMA 128×64, K=128)
__global__ __launch_bounds__(256) void k_ssd_inter(const u16* __restrict__ xBCb,
                                                   const float* __restrict__ ldg,
                                                   const float* __restrict__ sc,
                                                   const float* __restrict__ Dh,
                                                   float* __restrict__ ybuf) {
  const int L = 2049;
  const int c = blockIdx.x, h = blockIdx.y, b = blockIdx.z;
  const int tid = threadIdx.x;
  const int w = tid >> 6, l = tid & 63;
  const int t0 = c * 128;
  int qc = L - t0; if (qc > 128) qc = 128;

  __shared__ u16 Cs[128 * 136];
  __shared__ u16 H0[64 * 136];
  __shared__ float Lc_s[128];

  const u16* xb = xBCb + ((size_t)b * L) * 768;

  if (tid < 64) {
    int i2 = tid * 2;
    float a0 = 0.f, a1 = 0.f;
    if (i2 < qc) a0 = ldg[((size_t)b * L + t0 + i2) * 8 + h];
    if (i2 + 1 < qc) a1 = ldg[((size_t)b * L + t0 + i2 + 1) * 8 + h];
    float v = a0 + a1;
#pragma unroll
    for (int dlt = 1; dlt < 64; dlt <<= 1) {
      float t = __shfl_up(v, dlt, 64);
      if (tid >= dlt) v += t;
    }
    Lc_s[i2 + 1] = v;
    Lc_s[i2] = v - a1;
  }
  for (int q = tid; q < 2048; q += 256) {
    int row = q >> 4, off = (q & 15) * 8;
    short8v vc = {};
    if (row < qc) vc = *(const short8v*)(xb + (size_t)(t0 + row) * 768 + 640 + off);
    *(short8v*)(Cs + row * 136 + off) = vc;
  }
  {
    const float* hp = sc + (((size_t)b * 8 + h) * 17 + c) * 8192;
    for (int q = tid; q < 8192; q += 256) {
      int p = q >> 7, n = q & 127;
      H0[p * 136 + n] = f2bf(hp[p * 128 + n]);
    }
  }
  __syncthreads();

  const int wm = (w >> 1) * 64, wn = (w & 1) * 32;
  f32x4 acc[4][2] = {};
#pragma unroll
  for (int ks = 0; ks < 4; ++ks) {
    const int koff = ks * 32 + (l >> 4) * 8;
    short8v b0 = *(const short8v*)(H0 + (wn + (l & 15)) * 136 + koff);
    short8v b1 = *(const short8v*)(H0 + (wn + 16 + (l & 15)) * 136 + koff);
#pragma unroll
    for (int mi = 0; mi < 4; ++mi) {
      short8v a = *(const short8v*)(Cs + (wm + mi * 16 + (l & 15)) * 136 + koff);
      acc[mi][0] = __builtin_amdgcn_mfma_f32_16x16x32_bf16(a, b0, acc[mi][0], 0, 0, 0);
      acc[mi][1] = __builtin_amdgcn_mfma_f32_16x16x32_bf16(a, b1, acc[mi][1], 0, 0, 0);
    }
  }
  const float DD = Dh[h];
  float* yb = ybuf + ((size_t)b * L + t0) * 512 + h * 64;
#pragma unroll
  for (int mi = 0; mi < 4; ++mi)
#pragma unroll
    for (int r = 0; r < 4; ++r) {
      int t = wm + mi * 16 + (l >> 4) * 4 + r;
      if (t >= qc) continue;
      float e = __expf(Lc_s[t]);
#pragma unroll
      for (int ni = 0; ni < 2; ++ni) {
        int p = wn + ni * 16 + (l & 15);
        float xs = bf2f(xb[(size_t)(t0 + t) * 768 + h * 64 + p]);
        yb[(size_t)t * 512 + p] += e * acc[mi][ni][r] + DD * xs;
      }
    }
}

// ---------------- y = y*silu(z); RMS-norm over 512; *norm_w ; write bf16
__global__ __launch_bounds__(256) void k_gaterms(const float* __restrict__ y, const float* __restrict__ zx,
                                                 const float* __restrict__ nw, u16* __restrict__ y2,
                                                 int Mc) {
  int row = blockIdx.x * 4 + (threadIdx.x >> 6);
  if (row >= Mc) return;
  int lane = threadIdx.x & 63;
  const float* yr = y + (size_t)row * 512 + lane * 8;
  const float* zr = zx + (size_t)row * 1288 + lane * 8;
  float g[8];
  float ss = 0.f;
#pragma unroll
  for (int j = 0; j < 8; ++j) {
    float yv = yr[j], zv = zr[j];
    float sig = 1.f / (1.f + expf(-zv));
    float gg = yv * zv * sig;
    g[j] = gg;
    ss += gg * gg;
  }
#pragma unroll
  for (int off = 32; off > 0; off >>= 1) ss += __shfl_xor(ss, off);
  float r = rsqrtf(ss * (1.f / 512.f) + EPSF);
#pragma unroll
  for (int j = 0; j < 8; ++j)
    y2[(size_t)row * 512 + lane * 8 + j] = f2bf(g[j] * r * nw[lane * 8 + j]);
}

// ---------------- final LayerNorm over E=256 for rows t=1..2048 (wave per row)
__global__ __launch_bounds__(256) void k_ln(const float* __restrict__ u, const float* __restrict__ g,
                                            const float* __restrict__ bb, float* __restrict__ out) {
  int rid = blockIdx.x * 4 + (threadIdx.x >> 6);
  int lane = threadIdx.x & 63;
  int b = rid >> 11;
  int t = (rid & 2047) + 1;
  const float* ur = u + ((size_t)b * 2049 + t) * 256 + lane * 4;
  float v[4];
  float s1 = 0.f, s2 = 0.f;
#pragma unroll
  for (int j = 0; j < 4; ++j) {
    v[j] = ur[j];
    s1 += v[j];
    s2 += v[j] * v[j];
  }
#pragma unroll
  for (int off = 32; off > 0; off >>= 1) {
    s1 += __shfl_xor(s1, off);
    s2 += __shfl_xor(s2, off);
  }
  float mu = s1 * (1.f / 256.f);
  float var = s2 * (1.f / 256.f) - mu * mu;
  float rs = rsqrtf(var + EPSF);
  float* orow = out + ((size_t)b * 2048 + (t - 1)) * 256 + lane * 4;
#pragma unroll
  for (int j = 0; j < 4; ++j) orow[j] = (v[j] - mu) * rs * g[lane * 4 + j] + bb[lane * 4 + j];
}

// ---------------- masked pool partials
__global__ __launch_bounds__(256) void k_pp(const float* __restrict__ hln, const int* __restrict__ idx,
                                            float* __restrict__ part) {
  int ch = blockIdx.x;
  int b = blockIdx.y;
  int e = threadIdx.x;
  int agg = idx[b] / 6;
  int t0 = ch * 256;
  int tend = agg + 1 - t0;
  if (tend > 256) tend = 256;
  float s = 0.f;
  for (int i = 0; i < tend; ++i) s += hln[((size_t)b * 2048 + t0 + i) * 256 + e];
  part[((size_t)b * 8 + ch) * 256 + e] = s;
}

// ---------------- pooled @ fc_w + fc_b
__global__ __launch_bounds__(256) void k_fc(const float* __restrict__ part, const int* __restrict__ idx,
                                            const float* __restrict__ fw, const float* __restrict__ fb,
                                            float* __restrict__ out) {
  __shared__ float pooled[256];
  int b = blockIdx.x;
  int tid = threadIdx.x;
  float s = 0.f;
#pragma unroll
  for (int ch = 0; ch < 8; ++ch) s += part[((size_t)b * 8 + ch) * 256 + tid];
  pooled[tid] = s;
  __syncthreads();
  if (tid < 100) {
    int agg = idx[b] / 6;
    float inv = 1.f / (float)(agg + 1);
    float acc = 0.f;
    for (int e = 0; e < 256; ++e) acc += pooled[e] * fw[e * 100 + tid];
    out[b * 100 + tid] = acc * inv + fb[tid];
  }
}

extern "C" void kernel_launch(void* const* d_in, const int* in_sizes, int n_in,
                              void* d_out, int out_size, void* d_ws, size_t ws_size,
                              hipStream_t stream) {
  (void)in_sizes; (void)n_in; (void)out_size;
  const float* x        = (const float*)d_in[0];
  const int*   idx      = (const int*)d_in[1];
  const float* patch_w  = (const float*)d_in[2];
  const float* patch_b  = (const float*)d_in[3];
  const float* conv_w   = (const float*)d_in[4];
  const float* conv_b   = (const float*)d_in[5];
  const float* bn_g     = (const float*)d_in[6];
  const float* bn_b     = (const float*)d_in[7];
  const float* cls_tok  = (const float*)d_in[8];
  const float* pos_emb  = (const float*)d_in[9];
  const float* Wi       = (const float*)d_in[10];
  const float* cw       = (const float*)d_in[11];
  const float* cb       = (const float*)d_in[12];
  const float* dt_bias  = (const float*)d_in[13];
  const float* A_log    = (const float*)d_in[14];
  const float* Dh       = (const float*)d_in[15];
  const float* norm_w   = (const float*)d_in[16];
  const float* Wo       = (const float*)d_in[17];
  const float* ln_g     = (const float*)d_in[18];
  const float* ln_b     = (const float*)d_in[19];
  const float* fc_w     = (const float*)d_in[20];
  const float* fc_b     = (const float*)d_in[21];
  float* out = (float*)d_out;
  float* ws = (float*)d_ws;

  // workspace accounting (floats) — identical to round 5 (passed)
  size_t CB = 4;
  {
    auto need = [](size_t cb) {
      size_t per = 2ull * 3145728 + 2ull * 16392 + 1114112 + 262272;
      return (8392704ull + cb * per + 1024 + 1318912 + 524288 + 655360 + 32768) * 4ull;
    };
    if (ws_size < need(4)) CB = 2;
    if (ws_size < need(2)) CB = 1;
  }
  const int NCHUNK = (int)(16 / CB);
  const int Mc = (int)(CB * 2049);

  float* u    = ws;                              // 8392704
  float* bufA = u + 8392704;                     // CB*3145728
  float* bufB = bufA + CB * 3145728;             // CB*3145728
  float* dtb  = bufB + CB * 3145728;             // CB*16392
  float* ldb  = dtb + CB * 16392;                // CB*16392
  float* scb  = ldb + CB * 16392;                // CB*1114112
  float* dtot = scb + CB * 1114112;              // pad 1024
  u16*  u_bf  = (u16*)(dtot + 1024);             // CB*262272 floats
  u16*  WiT   = (u16*)((float*)u_bf + CB * 262272);   // 1318912 floats
  u16*  WoT   = (u16*)((float*)WiT + 1318912);        // 524288 floats
  u16*  wbf   = (u16*)((float*)WoT + 524288);         // 655360 floats
  float* ppar = (float*)wbf + 655360;                 // 32768
  float* hln  = bufA;

  u16* bufA16 = (u16*)bufA;
  u16* bufB16 = (u16*)bufB;

  // ---- weight prep
  k_wconv<<<dim3((4 * 256 * 256 * 5 + 255) / 256), 256, 0, stream>>>(conv_w, wbf);
  k_wti<<<dim3((8 * 1288 * 256 + 255) / 256), 256, 0, stream>>>(Wi, WiT);
  k_wto<<<dim3((8 * 256 * 512 + 255) / 256), 256, 0, stream>>>(Wo, WoT);

  float* zx    = bufA;                               // (CB,2049,1288) f32
  u16*  xBCb   = (u16*)bufB;                         // (CB,2049,768) bf16
  float* ybuf  = bufB + (size_t)CB * 786816;         // (CB,2049,512) f32
  u16*  y2bf   = (u16*)bufB;                         // overwrites xBCb (safe: ssd done)

  const unsigned gy = (unsigned)((Mc + 127) / 128);

  for (int bc = 0; bc < NCHUNK; ++bc) {
    const float* xc = x + (size_t)bc * CB * 8 * 12288;
    float* uc = u + (size_t)bc * CB * 2049 * 256;

    k_patchm<<<dim3(192, (unsigned)CB), 256, 0, stream>>>(xc, patch_w, patch_b, bufA16);
    k_convm<<<dim3(96, 4, (unsigned)CB), 256, 0, stream>>>(bufA16, wbf + 0 * 327680, conv_b + 0, bn_g + 0, bn_b + 0, bufB16, 12288);
    k_convm<<<dim3(96, 4, (unsigned)CB), 256, 0, stream>>>(bufB16, wbf + 1 * 327680, conv_b + 256, bn_g + 256, bn_b + 256, bufA16, 12288);
    {
      size_t tot = CB * 4096 * 256;
      k_mpb<<<dim3((unsigned)((tot + 255) / 256)), 256, 0, stream>>>(bufA16, bufB16, 4096, 3, tot);
    }
    k_convm<<<dim3(32, 4, (unsigned)CB), 256, 0, stream>>>(bufB16, wbf + 2 * 327680, conv_b + 512, bn_g + 512, bn_b + 512, bufA16, 4096);
    k_convm<<<dim3(32, 4, (unsigned)CB), 256, 0, stream>>>(bufA16, wbf + 3 * 327680, conv_b + 768, bn_g + 768, bn_b + 768, bufB16, 4096);
    {
      size_t tot = CB * 2048 * 256;
      k_mpb<<<dim3((unsigned)((tot + 255) / 256)), 256, 0, stream>>>(bufB16, bufA16, 2048, 2, tot);
    }
    k_asmb<<<dim3(2049, (unsigned)CB), 256, 0, stream>>>(bufA16, pos_emb, cls_tok, uc, u_bf);

    for (int l = 0; l < 8; ++l) {
      const u16* WiTl = WiT + (size_t)l * 1288 * 256;
      const u16* WoTl = WoT + (size_t)l * 256 * 512;
      const float* cwl  = cw + (size_t)l * 768 * 4;
      const float* cbl  = cb + (size_t)l * 768;
      const float* dtbl = dt_bias + l * 8;
      const float* all  = A_log + l * 8;
      const float* dhl  = Dh + l * 8;
      const float* nwl  = norm_w + (size_t)l * 512;

      k_gemmm<0><<<dim3(21, gy), 256, 0, stream>>>(u_bf, WiTl, zx, nullptr, Mc, 1288, 256);
      k_dw<<<dim3(4, 33, (unsigned)CB), 256, 0, stream>>>(zx, cwl, cbl, dtbl, all, xBCb, dtb, ldb);
      k_ssd_intra<<<dim3(17, 8, (unsigned)CB), 256, 0, stream>>>(xBCb, dtb, ldb, ybuf, scb, dtot);
      k_ssd_scan<<<dim3((unsigned)(CB * 8 * 32)), 256, 0, stream>>>(scb, dtot, (int)(CB * 8));
      k_ssd_inter<<<dim3(17, 8, (unsigned)CB), 256, 0, stream>>>(xBCb, ldb, scb, dhl, ybuf);
      k_gaterms<<<dim3((unsigned)((Mc + 3) / 4)), 256, 0, stream>>>(ybuf, zx, nwl, y2bf, Mc);
      k_gemmm<1><<<dim3(4, gy), 256, 0, stream>>>(y2bf, WoTl, uc, u_bf, Mc, 256, 512);
    }
  }

  // ---- final LN + masked pool + fc
  k_ln<<<dim3(8192), 256, 0, stream>>>(u, ln_g, ln_b, hln);
  k_pp<<<dim3(8, 16), 256, 0, stream>>>(hln, idx, ppar);
  k_fc<<<dim3(16), 256, 0, stream>>>(ppar, idx, fc_w, fc_b, out);
}

// Round 11
// 5293.829 us; speedup vs baseline: 9.9010x; 1.2677x over previous
//
#include <hip/hip_runtime.h>
#include <cstdint>
#include <cstddef>

#define EPSF 1e-5f

typedef unsigned short u16;
typedef __attribute__((ext_vector_type(8))) short short8v;
typedef __attribute__((ext_vector_type(4))) float f32x4;

static __device__ __forceinline__ u16 f2bf(float f) {
  union { float f; unsigned u; } v; v.f = f;
  unsigned r = v.u + 0x7fffu + ((v.u >> 16) & 1u);
  return (u16)(r >> 16);
}
static __device__ __forceinline__ float bf2f(u16 h) {
  union { unsigned u; float f; } v; v.u = ((unsigned)h) << 16;
  return v.f;
}

// ---------------- weight prep ----------------
__global__ void k_wconv(const float* __restrict__ src, u16* __restrict__ dst) {
  int i = blockIdx.x * 256 + threadIdx.x;
  if (i >= 4 * 256 * 256 * 5) return;
  int k = i % 5, r = i / 5;
  int ci = r & 255; r >>= 8;
  int co = r & 255; int l = r >> 8;
  dst[(((size_t)l * 256 + co) * 5 + k) * 256 + ci] = f2bf(src[i]);
}
__global__ void k_wti(const float* __restrict__ src, u16* __restrict__ dst) {
  int i = blockIdx.x * 256 + threadIdx.x;
  if (i >= 8 * 1288 * 256) return;
  int k = i & 255; int r = i >> 8;
  int n = r % 1288; int l = r / 1288;
  dst[i] = f2bf(src[((size_t)l * 256 + k) * 1288 + n]);
}
__global__ void k_wto(const float* __restrict__ src, u16* __restrict__ dst) {
  int i = blockIdx.x * 256 + threadIdx.x;
  if (i >= 8 * 256 * 512) return;
  int k = i & 511; int r = i >> 9;
  int n = r & 255; int l = r >> 8;
  dst[i] = f2bf(src[((size_t)l * 512 + k) * 256 + n]);
}

// ---------------- patch embed -> [b][L][256] bf16
__global__ __launch_bounds__(256) void k_patchm(const float* __restrict__ x, const float* __restrict__ pw,
                                                const float* __restrict__ pb, u16* __restrict__ outb) {
  __shared__ float xs[8][64];
  const int l0 = blockIdx.x * 64;
  const int b = blockIdx.y;
  const int tid = threadIdx.x;
  const float* xb = x + (size_t)b * 8 * 12288;
  for (int q = tid; q < 512; q += 256) {
    int p = q >> 6, ll = q & 63;
    xs[p][ll] = xb[(size_t)p * 12288 + l0 + ll];
  }
  __syncthreads();
  float pwr[8];
#pragma unroll
  for (int p = 0; p < 8; ++p) pwr[p] = pw[tid * 8 + p];
  const float bias = pb[tid];
  u16* ob = outb + ((size_t)b * 12288 + l0) * 256 + tid;
  for (int ll = 0; ll < 64; ++ll) {
    float acc = bias;
#pragma unroll
    for (int p = 0; p < 8; ++p) acc += xs[p][ll] * pwr[p];
    ob[(size_t)ll * 256] = f2bf(acc);
  }
}

// ---------------- MFMA conv1d (256->256, K=5 causal) + BN + ReLU, [L][C] bf16
__global__ __launch_bounds__(256) void k_convm(const u16* __restrict__ in, const u16* __restrict__ wbf,
                                               const float* __restrict__ cbias, const float* __restrict__ bng,
                                               const float* __restrict__ bnb, u16* __restrict__ outb, int L) {
  __shared__ u16 Xs[132 * 40];
  __shared__ u16 Ws[64 * 168];
  const int l0 = blockIdx.x * 128;
  const int co0 = blockIdx.y * 64;
  const int b = blockIdx.z;
  const int tid = threadIdx.x;
  const int w = tid >> 6, l = tid & 63;
  const int mhalf = (w >> 1) * 64, nhalf = (w & 1) * 32;
  const u16* inb = in + (size_t)b * L * 256;
  u16* outbb = outb + (size_t)b * L * 256;
  f32x4 acc[4][2] = {};
  for (int ci0 = 0; ci0 < 256; ci0 += 32) {
    __syncthreads();
    for (int q = tid; q < 528; q += 256) {
      int row = q >> 2, coff = (q & 3) * 8;
      int gl = l0 - 4 + row;
      short8v v = {};
      if (gl >= 0) v = *(const short8v*)(inb + (size_t)gl * 256 + ci0 + coff);
      *(short8v*)(Xs + row * 40 + coff) = v;
    }
    for (int q = tid; q < 1280; q += 256) {
      int co = q / 20, rem = q % 20, k = rem >> 2, coff = (rem & 3) * 8;
      *(short8v*)(Ws + co * 168 + k * 32 + coff) =
          *(const short8v*)(wbf + ((size_t)(co0 + co) * 5 + k) * 256 + ci0 + coff);
    }
    __syncthreads();
    const int koff = (l >> 4) * 8;
    const int arow = mhalf + (l & 15);
    const int bro0 = (nhalf + (l & 15)) * 168;
    const int bro1 = (nhalf + 16 + (l & 15)) * 168;
#pragma unroll
    for (int k = 0; k < 5; ++k) {
      short8v b0 = *(const short8v*)(Ws + bro0 + k * 32 + koff);
      short8v b1 = *(const short8v*)(Ws + bro1 + k * 32 + koff);
#pragma unroll
      for (int mi = 0; mi < 4; ++mi) {
        short8v a = *(const short8v*)(Xs + (arow + mi * 16 + k) * 40 + koff);
        acc[mi][0] = __builtin_amdgcn_mfma_f32_16x16x32_bf16(a, b0, acc[mi][0], 0, 0, 0);
        acc[mi][1] = __builtin_amdgcn_mfma_f32_16x16x32_bf16(a, b1, acc[mi][1], 0, 0, 0);
      }
    }
  }
  const float scn = rsqrtf(1.f + EPSF);
#pragma unroll
  for (int ni = 0; ni < 2; ++ni) {
    int co = co0 + nhalf + ni * 16 + (l & 15);
    float alpha = bng[co] * scn;
    float beta = cbias[co] * alpha + bnb[co];
#pragma unroll
    for (int mi = 0; mi < 4; ++mi)
#pragma unroll
      for (int r = 0; r < 4; ++r) {
        int row = l0 + mhalf + mi * 16 + (l >> 4) * 4 + r;
        float v = acc[mi][ni][r] * alpha + beta;
        outbb[(size_t)row * 256 + co] = f2bf(fmaxf(v, 0.f));
      }
  }
}

// ---------------- maxpool over L dim, [L][C] bf16
__global__ void k_mpb(const u16* __restrict__ in, u16* __restrict__ out, int Lout, int kp, size_t total) {
  size_t i = (size_t)blockIdx.x * 256 + threadIdx.x;
  if (i >= total) return;
  size_t c = i & 255;
  size_t rest = i >> 8;
  size_t lo = rest % (size_t)Lout;
  size_t b = rest / (size_t)Lout;
  const u16* p = in + (b * (size_t)Lout * kp + lo * kp) * 256 + c;
  float m = bf2f(p[0]);
  for (int j = 1; j < kp; ++j) m = fmaxf(m, bf2f(p[(size_t)j * 256]));
  out[i] = f2bf(m);
}

// ---------------- assemble u rows 0..2048 (f32 + bf16) ; row0 = cls+pos
__global__ __launch_bounds__(256) void k_asmb(const u16* __restrict__ in, const float* __restrict__ pos,
                                              const float* __restrict__ cls, float* __restrict__ uc,
                                              u16* __restrict__ ubc) {
  int t = blockIdx.x;
  int b = blockIdx.y;
  int e = threadIdx.x;
  float v;
  if (t == 0)
    v = cls[e] + pos[e];
  else
    v = bf2f(in[((size_t)b * 2048 + (t - 1)) * 256 + e]) + pos[(size_t)t * 256 + e];
  size_t o = ((size_t)b * 2049 + t) * 256 + e;
  uc[o] = v;
  ubc[o] = f2bf(v);
}

// ---------------- MFMA GEMM: A_bf[M,K] @ BT_bf[N,K]; K%32==0
// MODE 0 (in-proj): n<1280 -> zxb bf16 [M][1280]; n>=1280 -> dtr f32 [M][8]
// MODE 1 (out-proj): C[M,N] += acc (f32) and ubf bf16 copy
template <int MODE>
__global__ __launch_bounds__(256) void k_gemmm(const u16* __restrict__ A, const u16* __restrict__ BT,
                                               u16* __restrict__ OB, float* __restrict__ DT,
                                               float* __restrict__ C, u16* __restrict__ ubf,
                                               int M, int N, int K) {
  __shared__ u16 As[128 * 40];
  __shared__ u16 Bs[64 * 40];
  const int n0 = blockIdx.x * 64;
  const int m0 = blockIdx.y * 128;
  const int tid = threadIdx.x;
  const int w = tid >> 6, l = tid & 63;
  const int mhalf = (w >> 1) * 64, nhalf = (w & 1) * 32;
  f32x4 acc[4][2] = {};
  for (int k0 = 0; k0 < K; k0 += 32) {
    __syncthreads();
    for (int q = tid; q < 512; q += 256) {
      int row = q >> 2, koff = (q & 3) * 8;
      short8v v = {};
      if (m0 + row < M) v = *(const short8v*)(A + (size_t)(m0 + row) * K + k0 + koff);
      *(short8v*)(As + row * 40 + koff) = v;
    }
    {
      int row = tid >> 2, koff = (tid & 3) * 8;
      short8v v = {};
      if (n0 + row < N) v = *(const short8v*)(BT + (size_t)(n0 + row) * K + k0 + koff);
      *(short8v*)(Bs + row * 40 + koff) = v;
    }
    __syncthreads();
    const int koff = (l >> 4) * 8;
    short8v b0 = *(const short8v*)(Bs + (nhalf + (l & 15)) * 40 + koff);
    short8v b1 = *(const short8v*)(Bs + (nhalf + 16 + (l & 15)) * 40 + koff);
#pragma unroll
    for (int mi = 0; mi < 4; ++mi) {
      short8v a = *(const short8v*)(As + (mhalf + mi * 16 + (l & 15)) * 40 + koff);
      acc[mi][0] = __builtin_amdgcn_mfma_f32_16x16x32_bf16(a, b0, acc[mi][0], 0, 0, 0);
      acc[mi][1] = __builtin_amdgcn_mfma_f32_16x16x32_bf16(a, b1, acc[mi][1], 0, 0, 0);
    }
  }
#pragma unroll
  for (int mi = 0; mi < 4; ++mi)
#pragma unroll
    for (int r = 0; r < 4; ++r) {
      int m = m0 + mhalf + mi * 16 + (l >> 4) * 4 + r;
      if (m >= M) continue;
#pragma unroll
      for (int ni = 0; ni < 2; ++ni) {
        int n = n0 + nhalf + ni * 16 + (l & 15);
        if (n >= N) continue;
        float v = acc[mi][ni][r];
        if constexpr (MODE == 0) {
          if (n < 1280) OB[(size_t)m * 1280 + n] = f2bf(v);
          else DT[(size_t)m * 8 + (n - 1280)] = v;
        } else {
          float vv = C[(size_t)m * N + n] + v;
          C[(size_t)m * N + n] = vv;
          ubf[(size_t)m * N + n] = f2bf(vv);
        }
      }
    }
}

// ---------------- depthwise causal conv K=4 + silu (bf16 in/out) ; bx==3: dt/ld from dtr
__global__ __launch_bounds__(256) void k_dw(const u16* __restrict__ zxb, const float* __restrict__ dtr,
                                            const float* __restrict__ cw, const float* __restrict__ cb,
                                            const float* __restrict__ dtbias, const float* __restrict__ al,
                                            u16* __restrict__ xBCb, float* __restrict__ dtb,
                                            float* __restrict__ ldb) {
  const int bx = blockIdx.x;
  const int t0 = blockIdx.y * 64;
  const int b = blockIdx.z;
  if (bx == 3) {
    int h = threadIdx.x & 7, ro = threadIdx.x >> 3;
    float dbv = dtbias[h];
    float av = expf(al[h]);
#pragma unroll
    for (int it = 0; it < 2; ++it) {
      int r = t0 + it * 32 + ro;
      if (r < 2049) {
        float v = dtr[((size_t)b * 2049 + r) * 8 + h] + dbv;
        float d = (v > 20.f) ? v : log1pf(expf(v));
        size_t o = ((size_t)b * 2049 + r) * 8 + h;
        dtb[o] = d;
        ldb[o] = -av * d;
      }
    }
    return;
  }
  int c = bx * 256 + threadIdx.x;
  const u16* col = zxb + ((size_t)b * 2049) * 1280 + 512 + c;
  float cw0 = cw[c * 4 + 0], cw1 = cw[c * 4 + 1], cw2 = cw[c * 4 + 2], cw3 = cw[c * 4 + 3];
  const float bias = cb[c];
  float w0 = 0.f, w1 = 0.f, w2 = 0.f;
  if (t0 - 3 >= 0) w0 = bf2f(col[(size_t)(t0 - 3) * 1280]);
  if (t0 - 2 >= 0) w1 = bf2f(col[(size_t)(t0 - 2) * 1280]);
  if (t0 - 1 >= 0) w2 = bf2f(col[(size_t)(t0 - 1) * 1280]);
  int tend = t0 + 64; if (tend > 2049) tend = 2049;
  u16* ob = xBCb + ((size_t)b * 2049) * 768 + c;
  for (int t = t0; t < tend; ++t) {
    float v = bf2f(col[(size_t)t * 1280]);
    float acc = bias + w0 * cw0 + w1 * cw1 + w2 * cw2 + v * cw3;
    float sig = 1.f / (1.f + expf(-acc));
    ob[(size_t)t * 768] = f2bf(acc * sig);
    w0 = w1; w1 = w2; w2 = v;
  }
}

// ================= MFMA chunked SSD (Q=128, 17 chunks over L=2049) =================
__global__ __launch_bounds__(256) void k_ssd_intra(const u16* __restrict__ xBCb,
                                                   const float* __restrict__ dtg,
                                                   const float* __restrict__ ldg,
                                                   float* __restrict__ ybuf,
                                                   float* __restrict__ sc,
                                                   float* __restrict__ dtot) {
  const int L = 2049;
  const int c = blockIdx.x, h = blockIdx.y, b = blockIdx.z;
  const int tid = threadIdx.x;
  const int w = tid >> 6, l = tid & 63;
  const int t0 = c * 128;
  int qc = L - t0; if (qc > 128) qc = 128;

  __shared__ u16 R1[128 * 136];  // Bs -> BsT
  __shared__ u16 R2[128 * 136];  // Cs -> Ms
  __shared__ u16 R3[128 * 136];  // XT (rows 0..63) | XWT (rows 64..127)
  __shared__ float dt_s[128], Lc_s[128];

  const u16* xb = xBCb + ((size_t)b * L) * 768;

  if (tid < 64) {
    int i2 = tid * 2;
    float a0 = 0.f, a1 = 0.f, d0 = 0.f, d1 = 0.f;
    if (i2 < qc) { size_t r = ((size_t)b * L + t0 + i2) * 8 + h; a0 = ldg[r]; d0 = dtg[r]; }
    if (i2 + 1 < qc) { size_t r = ((size_t)b * L + t0 + i2 + 1) * 8 + h; a1 = ldg[r]; d1 = dtg[r]; }
    dt_s[i2] = d0; dt_s[i2 + 1] = d1;
    float v = a0 + a1;
#pragma unroll
    for (int dlt = 1; dlt < 64; dlt <<= 1) {
      float t = __shfl_up(v, dlt, 64);
      if (tid >= dlt) v += t;
    }
    Lc_s[i2 + 1] = v;
    Lc_s[i2] = v - a1;
  }

  for (int q = tid; q < 2048; q += 256) {
    int row = q >> 4, off = (q & 15) * 8;
    short8v vb = {}, vc = {};
    if (row < qc) {
      const u16* src = xb + (size_t)(t0 + row) * 768;
      vb = *(const short8v*)(src + 512 + off);
      vc = *(const short8v*)(src + 640 + off);
    }
    *(short8v*)(R1 + row * 136 + off) = vb;
    *(short8v*)(R2 + row * 136 + off) = vc;
  }
  for (int q = tid; q < 8192; q += 256) {
    int s = q >> 6, p = q & 63;
    u16 v = 0;
    if (s < qc) v = xb[(size_t)(t0 + s) * 768 + h * 64 + p];
    R3[p * 136 + s] = v;
  }
  __syncthreads();  // B1

  {
    const float Lend = Lc_s[qc - 1];
    for (int q = tid; q < 8192; q += 256) {
      int p = q >> 7, s = q & 127;
      float w2 = __expf(Lend - Lc_s[s]) * dt_s[s];
      float xv = bf2f(R3[p * 136 + s]);
      R3[(64 + p) * 136 + s] = f2bf(xv * w2);
    }
  }

  // G = C·Bᵀ  (128×128, K=128)
  const int wm = (w >> 1) * 64, wn = (w & 1) * 64;
  f32x4 g[4][4] = {};
  const bool skipG = (wm < wn);
  if (!skipG) {
#pragma unroll
    for (int ks = 0; ks < 4; ++ks) {
      const int koff = ks * 32 + (l >> 4) * 8;
      short8v bf[4];
#pragma unroll
      for (int ni = 0; ni < 4; ++ni)
        bf[ni] = *(const short8v*)(R1 + (wn + ni * 16 + (l & 15)) * 136 + koff);
#pragma unroll
      for (int mi = 0; mi < 4; ++mi) {
        short8v a = *(const short8v*)(R2 + (wm + mi * 16 + (l & 15)) * 136 + koff);
#pragma unroll
        for (int ni = 0; ni < 4; ++ni)
          g[mi][ni] = __builtin_amdgcn_mfma_f32_16x16x32_bf16(a, bf[ni], g[mi][ni], 0, 0, 0);
      }
    }
  }
  __syncthreads();  // B2

#pragma unroll
  for (int mi = 0; mi < 4; ++mi)
#pragma unroll
    for (int r = 0; r < 4; ++r) {
      int t = wm + mi * 16 + (l >> 4) * 4 + r;
      float lct = Lc_s[t];
#pragma unroll
      for (int ni = 0; ni < 4; ++ni) {
        int s = wn + ni * 16 + (l & 15);
        float v = 0.f;
        if (s <= t) v = __expf(lct - Lc_s[s]) * dt_s[s] * g[mi][ni][r];
        R2[t * 136 + s] = f2bf(v);
      }
    }
  for (int q = tid; q < 16384; q += 256) {
    int s = q >> 7, n = q & 127;
    u16 v = 0;
    if (s < qc) v = xb[(size_t)(t0 + s) * 768 + 512 + n];
    R1[n * 136 + s] = v;
  }
  if (tid == 0) dtot[((size_t)b * 8 + h) * 17 + c] = __expf(Lc_s[qc - 1]);
  __syncthreads();  // B3

  // Y = Ms @ X
  {
    const int wmy = (w >> 1) * 64, wny = (w & 1) * 32;
    f32x4 ya[4][2] = {};
#pragma unroll
    for (int ks = 0; ks < 4; ++ks) {
      const int koff = ks * 32 + (l >> 4) * 8;
      short8v b0 = *(const short8v*)(R3 + (wny + (l & 15)) * 136 + koff);
      short8v b1 = *(const short8v*)(R3 + (wny + 16 + (l & 15)) * 136 + koff);
#pragma unroll
      for (int mi = 0; mi < 4; ++mi) {
        short8v a = *(const short8v*)(R2 + (wmy + mi * 16 + (l & 15)) * 136 + koff);
        ya[mi][0] = __builtin_amdgcn_mfma_f32_16x16x32_bf16(a, b0, ya[mi][0], 0, 0, 0);
        ya[mi][1] = __builtin_amdgcn_mfma_f32_16x16x32_bf16(a, b1, ya[mi][1], 0, 0, 0);
      }
    }
    float* yb = ybuf + ((size_t)b * L + t0) * 512 + h * 64;
#pragma unroll
    for (int mi = 0; mi < 4; ++mi)
#pragma unroll
      for (int r = 0; r < 4; ++r) {
        int t = wmy + mi * 16 + (l >> 4) * 4 + r;
        if (t >= qc) continue;
#pragma unroll
        for (int ni = 0; ni < 2; ++ni) {
          int p = wny + ni * 16 + (l & 15);
          yb[(size_t)t * 512 + p] = ya[mi][ni][r];
        }
      }
  }

  // Sc
  {
    const int wms = (w & 1) * 32, wns = (w >> 1) * 64;
    f32x4 sa[2][4] = {};
#pragma unroll
    for (int ks = 0; ks < 4; ++ks) {
      const int koff = ks * 32 + (l >> 4) * 8;
      short8v a0 = *(const short8v*)(R3 + (64 + wms + (l & 15)) * 136 + koff);
      short8v a1 = *(const short8v*)(R3 + (64 + wms + 16 + (l & 15)) * 136 + koff);
#pragma unroll
      for (int ni = 0; ni < 4; ++ni) {
        short8v bb = *(const short8v*)(R1 + (wns + ni * 16 + (l & 15)) * 136 + koff);
        sa[0][ni] = __builtin_amdgcn_mfma_f32_16x16x32_bf16(a0, bb, sa[0][ni], 0, 0, 0);
        sa[1][ni] = __builtin_amdgcn_mfma_f32_16x16x32_bf16(a1, bb, sa[1][ni], 0, 0, 0);
      }
    }
    float* scp = sc + (((size_t)b * 8 + h) * 17 + c) * 8192;
#pragma unroll
    for (int mi = 0; mi < 2; ++mi)
#pragma unroll
      for (int r = 0; r < 4; ++r) {
        int p = wms + mi * 16 + (l >> 4) * 4 + r;
#pragma unroll
        for (int ni = 0; ni < 4; ++ni) {
          int n = wns + ni * 16 + (l & 15);
          scp[p * 128 + n] = sa[mi][ni][r];
        }
      }
  }
}

__global__ __launch_bounds__(256) void k_ssd_scan(float* __restrict__ sc, const float* __restrict__ dtot,
                                                  int nbh) {
  int gid = blockIdx.x * 256 + threadIdx.x;
  int bh = gid >> 13;
  if (bh >= nbh) return;
  int elem = gid & 8191;
  float* base = sc + (size_t)bh * 17 * 8192 + elem;
  const float* dtp = dtot + (size_t)bh * 17;
  float hc = 0.f;
#pragma unroll
  for (int cc = 0; cc < 17; ++cc) {
    float D = dtp[cc];
    float v = base[(size_t)cc * 8192];
    base[(size_t)cc * 8192] = hc;
    hc = hc * D + v;
  }
}

__global__ __launch_bounds__(256) void k_ssd_inter(const u16* __restrict__ xBCb,
                                                   const float* __restrict__ ldg,
                                                   const float* __restrict__ sc,
                                                   const float* __restrict__ Dh,
                                                   float* __restrict__ ybuf) {
  const int L = 2049;
  const int c = blockIdx.x, h = blockIdx.y, b = blockIdx.z;
  const int tid = threadIdx.x;
  const int w = tid >> 6, l = tid & 63;
  const int t0 = c * 128;
  int qc = L - t0; if (qc > 128) qc = 128;

  __shared__ u16 Cs[128 * 136];
  __shared__ u16 H0[64 * 136];
  __shared__ float Lc_s[128];

  const u16* xb = xBCb + ((size_t)b * L) * 768;

  if (tid < 64) {
    int i2 = tid * 2;
    float a0 = 0.f, a1 = 0.f;
    if (i2 < qc) a0 = ldg[((size_t)b * L + t0 + i2) * 8 + h];
    if (i2 + 1 < qc) a1 = ldg[((size_t)b * L + t0 + i2 + 1) * 8 + h];
    float v = a0 + a1;
#pragma unroll
    for (int dlt = 1; dlt < 64; dlt <<= 1) {
      float t = __shfl_up(v, dlt, 64);
      if (tid >= dlt) v += t;
    }
    Lc_s[i2 + 1] = v;
    Lc_s[i2] = v - a1;
  }
  for (int q = tid; q < 2048; q += 256) {
    int row = q >> 4, off = (q & 15) * 8;
    short8v vc = {};
    if (row < qc) vc = *(const short8v*)(xb + (size_t)(t0 + row) * 768 + 640 + off);
    *(short8v*)(Cs + row * 136 + off) = vc;
  }
  {
    const float* hp = sc + (((size_t)b * 8 + h) * 17 + c) * 8192;
    for (int q = tid; q < 8192; q += 256) {
      int p = q >> 7, n = q & 127;
      H0[p * 136 + n] = f2bf(hp[p * 128 + n]);
    }
  }
  __syncthreads();

  const int wm = (w >> 1) * 64, wn = (w & 1) * 32;
  f32x4 acc[4][2] = {};
#pragma unroll
  for (int ks = 0; ks < 4; ++ks) {
    const int koff = ks * 32 + (l >> 4) * 8;
    short8v b0 = *(const short8v*)(H0 + (wn + (l & 15)) * 136 + koff);
    short8v b1 = *(const short8v*)(H0 + (wn + 16 + (l & 15)) * 136 + koff);
#pragma unroll
    for (int mi = 0; mi < 4; ++mi) {
      short8v a = *(const short8v*)(Cs + (wm + mi * 16 + (l & 15)) * 136 + koff);
      acc[mi][0] = __builtin_amdgcn_mfma_f32_16x16x32_bf16(a, b0, acc[mi][0], 0, 0, 0);
      acc[mi][1] = __builtin_amdgcn_mfma_f32_16x16x32_bf16(a, b1, acc[mi][1], 0, 0, 0);
    }
  }
  const float DD = Dh[h];
  float* yb = ybuf + ((size_t)b * L + t0) * 512 + h * 64;
#pragma unroll
  for (int mi = 0; mi < 4; ++mi)
#pragma unroll
    for (int r = 0; r < 4; ++r) {
      int t = wm + mi * 16 + (l >> 4) * 4 + r;
      if (t >= qc) continue;
      float e = __expf(Lc_s[t]);
#pragma unroll
      for (int ni = 0; ni < 2; ++ni) {
        int p = wn + ni * 16 + (l & 15);
        float xs = bf2f(xb[(size_t)(t0 + t) * 768 + h * 64 + p]);
        yb[(size_t)t * 512 + p] += e * acc[mi][ni][r] + DD * xs;
      }
    }
}

// ---------------- y = y*silu(z); RMS-norm over 512; *norm_w ; write bf16 (z from bf16 zxb)
__global__ __launch_bounds__(256) void k_gaterms(const float* __restrict__ y, const u16* __restrict__ zxb,
                                                 const float* __restrict__ nw, u16* __restrict__ y2,
                                                 int Mc) {
  int row = blockIdx.x * 4 + (threadIdx.x >> 6);
  if (row >= Mc) return;
  int lane = threadIdx.x & 63;
  const float* yr = y + (size_t)row * 512 + lane * 8;
  const u16* zr = zxb + (size_t)row * 1280 + lane * 8;
  short8v zv8 = *(const short8v*)zr;
  float g[8];
  float ss = 0.f;
#pragma unroll
  for (int j = 0; j < 8; ++j) {
    float yv = yr[j];
    float zv = bf2f((u16)zv8[j]);
    float sig = 1.f / (1.f + expf(-zv));
    float gg = yv * zv * sig;
    g[j] = gg;
    ss += gg * gg;
  }
#pragma unroll
  for (int off = 32; off > 0; off >>= 1) ss += __shfl_xor(ss, off);
  float r = rsqrtf(ss * (1.f / 512.f) + EPSF);
#pragma unroll
  for (int j = 0; j < 8; ++j)
    y2[(size_t)row * 512 + lane * 8 + j] = f2bf(g[j] * r * nw[lane * 8 + j]);
}

// ---------------- final LayerNorm over E=256 for rows t=1..2048 (wave per row)
__global__ __launch_bounds__(256) void k_ln(const float* __restrict__ u, const float* __restrict__ g,
                                            const float* __restrict__ bb, float* __restrict__ out) {
  int rid = blockIdx.x * 4 + (threadIdx.x >> 6);
  int lane = threadIdx.x & 63;
  int b = rid >> 11;
  int t = (rid & 2047) + 1;
  const float* ur = u + ((size_t)b * 2049 + t) * 256 + lane * 4;
  float v[4];
  float s1 = 0.f, s2 = 0.f;
#pragma unroll
  for (int j = 0; j < 4; ++j) {
    v[j] = ur[j];
    s1 += v[j];
    s2 += v[j] * v[j];
  }
#pragma unroll
  for (int off = 32; off > 0; off >>= 1) {
    s1 += __shfl_xor(s1, off);
    s2 += __shfl_xor(s2, off);
  }
  float mu = s1 * (1.f / 256.f);
  float var = s2 * (1.f / 256.f) - mu * mu;
  float rs = rsqrtf(var + EPSF);
  float* orow = out + ((size_t)b * 2048 + (t - 1)) * 256 + lane * 4;
#pragma unroll
  for (int j = 0; j < 4; ++j) orow[j] = (v[j] - mu) * rs * g[lane * 4 + j] + bb[lane * 4 + j];
}

// ---------------- masked pool partials
__global__ __launch_bounds__(256) void k_pp(const float* __restrict__ hln, const int* __restrict__ idx,
                                            float* __restrict__ part) {
  int ch = blockIdx.x;
  int b = blockIdx.y;
  int e = threadIdx.x;
  int agg = idx[b] / 6;
  int t0 = ch * 256;
  int tend = agg + 1 - t0;
  if (tend > 256) tend = 256;
  float s = 0.f;
  for (int i = 0; i < tend; ++i) s += hln[((size_t)b * 2048 + t0 + i) * 256 + e];
  part[((size_t)b * 8 + ch) * 256 + e] = s;
}

// ---------------- pooled @ fc_w + fc_b
__global__ __launch_bounds__(256) void k_fc(const float* __restrict__ part, const int* __restrict__ idx,
                                            const float* __restrict__ fw, const float* __restrict__ fb,
                                            float* __restrict__ out) {
  __shared__ float pooled[256];
  int b = blockIdx.x;
  int tid = threadIdx.x;
  float s = 0.f;
#pragma unroll
  for (int ch = 0; ch < 8; ++ch) s += part[((size_t)b * 8 + ch) * 256 + tid];
  pooled[tid] = s;
  __syncthreads();
  if (tid < 100) {
    int agg = idx[b] / 6;
    float inv = 1.f / (float)(agg + 1);
    float acc = 0.f;
    for (int e = 0; e < 256; ++e) acc += pooled[e] * fw[e * 100 + tid];
    out[b * 100 + tid] = acc * inv + fb[tid];
  }
}

extern "C" void kernel_launch(void* const* d_in, const int* in_sizes, int n_in,
                              void* d_out, int out_size, void* d_ws, size_t ws_size,
                              hipStream_t stream) {
  (void)in_sizes; (void)n_in; (void)out_size;
  const float* x        = (const float*)d_in[0];
  const int*   idx      = (const int*)d_in[1];
  const float* patch_w  = (const float*)d_in[2];
  const float* patch_b  = (const float*)d_in[3];
  const float* conv_w   = (const float*)d_in[4];
  const float* conv_b   = (const float*)d_in[5];
  const float* bn_g     = (const float*)d_in[6];
  const float* bn_b     = (const float*)d_in[7];
  const float* cls_tok  = (const float*)d_in[8];
  const float* pos_emb  = (const float*)d_in[9];
  const float* Wi       = (const float*)d_in[10];
  const float* cw       = (const float*)d_in[11];
  const float* cb       = (const float*)d_in[12];
  const float* dt_bias  = (const float*)d_in[13];
  const float* A_log    = (const float*)d_in[14];
  const float* Dh       = (const float*)d_in[15];
  const float* norm_w   = (const float*)d_in[16];
  const float* Wo       = (const float*)d_in[17];
  const float* ln_g     = (const float*)d_in[18];
  const float* ln_b     = (const float*)d_in[19];
  const float* fc_w     = (const float*)d_in[20];
  const float* fc_b     = (const float*)d_in[21];
  float* out = (float*)d_out;
  float* ws = (float*)d_ws;

  // workspace accounting (floats). Per-chunk-batch mamba overlay footprint:
  //   zxb 1,311,360 + dtr/dtb/ldb 3*16,392 + xBCb 786,816 + ybuf 1,049,088
  //   + y2bf 524,544 + scb 1,114,112 = 4,835,096 floats per batch.
  // dtot: CB*8*17 entries -> alloc 4096 (covers CB=16's 2176).  [r9 bug: was 1024]
  auto need = [](size_t cb) {
    size_t Rsz = cb * 4835096ull;
    if (Rsz < 8388608ull) Rsz = 8388608ull;
    return (8392704ull + Rsz + 4096 + 1318912 + 524288 + 655360 + 32768 + cb * 262272ull) * 4ull;
  };
  size_t CB = 16;
  while (CB > 1 && ws_size < need(CB)) CB >>= 1;
  const int NCHUNK = (int)(16 / CB);
  const int Mc = (int)(CB * 2049);

  size_t Rsz = CB * 4835096ull;
  if (Rsz < 8388608ull) Rsz = 8388608ull;

  float* u   = ws;                 // 8,392,704
  float* R   = u + 8392704;        // Rsz
  // mamba overlay in R
  u16*  zxb  = (u16*)R;                          // CB*1,311,360 floats
  float* dtr = R + CB * 1311360;                 // CB*16392
  float* dtb = dtr + CB * 16392;                 // CB*16392
  float* ldb = dtb + CB * 16392;                 // CB*16392
  float* afterldb = ldb + CB * 16392;
  u16*  xBCb = (u16*)afterldb;                   // CB*786,816 floats (Mc*768 u16)
  float* ybuf = afterldb + CB * 786816;          // CB*1,049,088
  u16*  y2bf = (u16*)(ybuf + CB * 1049088);      // CB*524,544 floats
  float* scb = ybuf + CB * 1049088 + CB * 524544;  // CB*1,114,112
  // frontend overlay in R
  u16* fA = (u16*)R;                             // CB*1,572,864 floats
  u16* fB = (u16*)(R + CB * 1572864);            // CB*1,572,864 floats
  // final overlay
  float* hln = R;                                // 8,388,608
  // after R
  float* dtot = R + Rsz;                         // 4096 (CB*8*17 <= 2176 entries)
  u16*  WiT  = (u16*)(dtot + 4096);              // 1,318,912 floats
  u16*  WoT  = (u16*)((float*)WiT + 1318912);    // 524,288 floats
  u16*  wbf  = (u16*)((float*)WoT + 524288);     // 655,360 floats
  float* ppar = (float*)wbf + 655360;            // 32,768
  u16*  u_bf = (u16*)(ppar + 32768);             // CB*262,272 floats

  // ---- weight prep
  k_wconv<<<dim3((4 * 256 * 256 * 5 + 255) / 256), 256, 0, stream>>>(conv_w, wbf);
  k_wti<<<dim3((8 * 1288 * 256 + 255) / 256), 256, 0, stream>>>(Wi, WiT);
  k_wto<<<dim3((8 * 256 * 512 + 255) / 256), 256, 0, stream>>>(Wo, WoT);

  const unsigned gy = (unsigned)((Mc + 127) / 128);

  for (int bc = 0; bc < NCHUNK; ++bc) {
    const float* xc = x + (size_t)bc * CB * 8 * 12288;
    float* uc = u + (size_t)bc * CB * 2049 * 256;

    k_patchm<<<dim3(192, (unsigned)CB), 256, 0, stream>>>(xc, patch_w, patch_b, fA);
    k_convm<<<dim3(96, 4, (unsigned)CB), 256, 0, stream>>>(fA, wbf + 0 * 327680, conv_b + 0, bn_g + 0, bn_b + 0, fB, 12288);
    k_convm<<<dim3(96, 4, (unsigned)CB), 256, 0, stream>>>(fB, wbf + 1 * 327680, conv_b + 256, bn_g + 256, bn_b + 256, fA, 12288);
    {
      size_t tot = CB * 4096 * 256;
      k_mpb<<<dim3((unsigned)((tot + 255) / 256)), 256, 0, stream>>>(fA, fB, 4096, 3, tot);
    }
    k_convm<<<dim3(32, 4, (unsigned)CB), 256, 0, stream>>>(fB, wbf + 2 * 327680, conv_b + 512, bn_g + 512, bn_b + 512, fA, 4096);
    k_convm<<<dim3(32, 4, (unsigned)CB), 256, 0, stream>>>(fA, wbf + 3 * 327680, conv_b + 768, bn_g + 768, bn_b + 768, fB, 4096);
    {
      size_t tot = CB * 2048 * 256;
      k_mpb<<<dim3((unsigned)((tot + 255) / 256)), 256, 0, stream>>>(fB, fA, 2048, 2, tot);
    }
    k_asmb<<<dim3(2049, (unsigned)CB), 256, 0, stream>>>(fA, pos_emb, cls_tok, uc, u_bf);

    for (int l = 0; l < 8; ++l) {
      const u16* WiTl = WiT + (size_t)l * 1288 * 256;
      const u16* WoTl = WoT + (size_t)l * 256 * 512;
      const float* cwl  = cw + (size_t)l * 768 * 4;
      const float* cbl  = cb + (size_t)l * 768;
      const float* dtbl = dt_bias + l * 8;
      const float* all  = A_log + l * 8;
      const float* dhl  = Dh + l * 8;
      const float* nwl  = norm_w + (size_t)l * 512;

      k_gemmm<0><<<dim3(21, gy), 256, 0, stream>>>(u_bf, WiTl, zxb, dtr, nullptr, nullptr, Mc, 1288, 256);
      k_dw<<<dim3(4, 33, (unsigned)CB), 256, 0, stream>>>(zxb, dtr, cwl, cbl, dtbl, all, xBCb, dtb, ldb);
      k_ssd_intra<<<dim3(17, 8, (unsigned)CB), 256, 0, stream>>>(xBCb, dtb, ldb, ybuf, scb, dtot);
      k_ssd_scan<<<dim3((unsigned)(CB * 8 * 32)), 256, 0, stream>>>(scb, dtot, (int)(CB * 8));
      k_ssd_inter<<<dim3(17, 8, (unsigned)CB), 256, 0, stream>>>(xBCb, ldb, scb, dhl, ybuf);
      k_gaterms<<<dim3((unsigned)((Mc + 3) / 4)), 256, 0, stream>>>(ybuf, zxb, nwl, y2bf, Mc);
      k_gemmm<1><<<dim3(4, gy), 256, 0, stream>>>(y2bf, WoTl, nullptr, nullptr, uc, u_bf, Mc, 256, 512);
    }
  }

  // ---- final LN + masked pool + fc
  k_ln<<<dim3(8192), 256, 0, stream>>>(u, ln_g, ln_b, hln);
  k_pp<<<dim3(8, 16), 256, 0, stream>>>(hln, idx, ppar);
  k_fc<<<dim3(16), 256, 0, stream>>>(ppar, idx, fc_w, fc_b, out);
}

// Round 13
// 4145.730 us; speedup vs baseline: 12.6430x; 1.2769x over previous
//
#include <hip/hip_runtime.h>
#include <cstdint>
#include <cstddef>

#define EPSF 1e-5f

typedef unsigned short u16;
typedef __attribute__((ext_vector_type(8))) short short8v;
typedef __attribute__((ext_vector_type(4))) float f32x4;

static __device__ __forceinline__ u16 f2bf(float f) {
  union { float f; unsigned u; } v; v.f = f;
  unsigned r = v.u + 0x7fffu + ((v.u >> 16) & 1u);
  return (u16)(r >> 16);
}
static __device__ __forceinline__ float bf2f(u16 h) {
  union { unsigned u; float f; } v; v.u = ((unsigned)h) << 16;
  return v.f;
}

// ---------------- weight prep ----------------
__global__ void k_wconv(const float* __restrict__ src, u16* __restrict__ dst) {
  int i = blockIdx.x * 256 + threadIdx.x;
  if (i >= 4 * 256 * 256 * 5) return;
  int k = i % 5, r = i / 5;
  int ci = r & 255; r >>= 8;
  int co = r & 255; int l = r >> 8;
  dst[(((size_t)l * 256 + co) * 5 + k) * 256 + ci] = f2bf(src[i]);
}
__global__ void k_wti(const float* __restrict__ src, u16* __restrict__ dst) {
  int i = blockIdx.x * 256 + threadIdx.x;
  if (i >= 8 * 1288 * 256) return;
  int k = i & 255; int r = i >> 8;
  int n = r % 1288; int l = r / 1288;
  dst[i] = f2bf(src[((size_t)l * 256 + k) * 1288 + n]);
}
__global__ void k_wto(const float* __restrict__ src, u16* __restrict__ dst) {
  int i = blockIdx.x * 256 + threadIdx.x;
  if (i >= 8 * 256 * 512) return;
  int k = i & 511; int r = i >> 9;
  int n = r & 255; int l = r >> 8;
  dst[i] = f2bf(src[((size_t)l * 512 + k) * 256 + n]);
}

// ---------------- patch embed -> [b][L][256] bf16
__global__ __launch_bounds__(256) void k_patchm(const float* __restrict__ x, const float* __restrict__ pw,
                                                const float* __restrict__ pb, u16* __restrict__ outb) {
  __shared__ float xs[8][64];
  const int l0 = blockIdx.x * 64;
  const int b = blockIdx.y;
  const int tid = threadIdx.x;
  const float* xb = x + (size_t)b * 8 * 12288;
  for (int q = tid; q < 512; q += 256) {
    int p = q >> 6, ll = q & 63;
    xs[p][ll] = xb[(size_t)p * 12288 + l0 + ll];
  }
  __syncthreads();
  float pwr[8];
#pragma unroll
  for (int p = 0; p < 8; ++p) pwr[p] = pw[tid * 8 + p];
  const float bias = pb[tid];
  u16* ob = outb + ((size_t)b * 12288 + l0) * 256 + tid;
  for (int ll = 0; ll < 64; ++ll) {
    float acc = bias;
#pragma unroll
    for (int p = 0; p < 8; ++p) acc += xs[p][ll] * pwr[p];
    ob[(size_t)ll * 256] = f2bf(acc);
  }
}

// ---------------- MFMA conv1d (256->256, K=5 causal) + BN + ReLU, [L][C] bf16
__global__ __launch_bounds__(256) void k_convm(const u16* __restrict__ in, const u16* __restrict__ wbf,
                                               const float* __restrict__ cbias, const float* __restrict__ bng,
                                               const float* __restrict__ bnb, u16* __restrict__ outb, int L) {
  __shared__ u16 Xs[132 * 40];
  __shared__ u16 Ws[64 * 168];
  const int l0 = blockIdx.x * 128;
  const int co0 = blockIdx.y * 64;
  const int b = blockIdx.z;
  const int tid = threadIdx.x;
  const int w = tid >> 6, l = tid & 63;
  const int mhalf = (w >> 1) * 64, nhalf = (w & 1) * 32;
  const u16* inb = in + (size_t)b * L * 256;
  u16* outbb = outb + (size_t)b * L * 256;
  f32x4 acc[4][2] = {};
  for (int ci0 = 0; ci0 < 256; ci0 += 32) {
    __syncthreads();
    for (int q = tid; q < 528; q += 256) {
      int row = q >> 2, coff = (q & 3) * 8;
      int gl = l0 - 4 + row;
      short8v v = {};
      if (gl >= 0) v = *(const short8v*)(inb + (size_t)gl * 256 + ci0 + coff);
      *(short8v*)(Xs + row * 40 + coff) = v;
    }
    for (int q = tid; q < 1280; q += 256) {
      int co = q / 20, rem = q % 20, k = rem >> 2, coff = (rem & 3) * 8;
      *(short8v*)(Ws + co * 168 + k * 32 + coff) =
          *(const short8v*)(wbf + ((size_t)(co0 + co) * 5 + k) * 256 + ci0 + coff);
    }
    __syncthreads();
    const int koff = (l >> 4) * 8;
    const int arow = mhalf + (l & 15);
    const int bro0 = (nhalf + (l & 15)) * 168;
    const int bro1 = (nhalf + 16 + (l & 15)) * 168;
#pragma unroll
    for (int k = 0; k < 5; ++k) {
      short8v b0 = *(const short8v*)(Ws + bro0 + k * 32 + koff);
      short8v b1 = *(const short8v*)(Ws + bro1 + k * 32 + koff);
#pragma unroll
      for (int mi = 0; mi < 4; ++mi) {
        short8v a = *(const short8v*)(Xs + (arow + mi * 16 + k) * 40 + koff);
        acc[mi][0] = __builtin_amdgcn_mfma_f32_16x16x32_bf16(a, b0, acc[mi][0], 0, 0, 0);
        acc[mi][1] = __builtin_amdgcn_mfma_f32_16x16x32_bf16(a, b1, acc[mi][1], 0, 0, 0);
      }
    }
  }
  const float scn = rsqrtf(1.f + EPSF);
#pragma unroll
  for (int ni = 0; ni < 2; ++ni) {
    int co = co0 + nhalf + ni * 16 + (l & 15);
    float alpha = bng[co] * scn;
    float beta = cbias[co] * alpha + bnb[co];
#pragma unroll
    for (int mi = 0; mi < 4; ++mi)
#pragma unroll
      for (int r = 0; r < 4; ++r) {
        int row = l0 + mhalf + mi * 16 + (l >> 4) * 4 + r;
        float v = acc[mi][ni][r] * alpha + beta;
        outbb[(size_t)row * 256 + co] = f2bf(fmaxf(v, 0.f));
      }
  }
}

// ---------------- maxpool over L dim, [L][C] bf16
__global__ void k_mpb(const u16* __restrict__ in, u16* __restrict__ out, int Lout, int kp, size_t total) {
  size_t i = (size_t)blockIdx.x * 256 + threadIdx.x;
  if (i >= total) return;
  size_t c = i & 255;
  size_t rest = i >> 8;
  size_t lo = rest % (size_t)Lout;
  size_t b = rest / (size_t)Lout;
  const u16* p = in + (b * (size_t)Lout * kp + lo * kp) * 256 + c;
  float m = bf2f(p[0]);
  for (int j = 1; j < kp; ++j) m = fmaxf(m, bf2f(p[(size_t)j * 256]));
  out[i] = f2bf(m);
}

// ---------------- assemble u rows 0..2048 (f32 + bf16) ; row0 = cls+pos
__global__ __launch_bounds__(256) void k_asmb(const u16* __restrict__ in, const float* __restrict__ pos,
                                              const float* __restrict__ cls, float* __restrict__ uc,
                                              u16* __restrict__ ubc) {
  int t = blockIdx.x;
  int b = blockIdx.y;
  int e = threadIdx.x;
  float v;
  if (t == 0)
    v = cls[e] + pos[e];
  else
    v = bf2f(in[((size_t)b * 2048 + (t - 1)) * 256 + e]) + pos[(size_t)t * 256 + e];
  size_t o = ((size_t)b * 2049 + t) * 256 + e;
  uc[o] = v;
  ubc[o] = f2bf(v);
}

// ---------------- MFMA GEMM: A_bf[M,K] @ BT_bf[N,K]; K%32==0
// MODE 0 (in-proj): n<1280 -> zxb bf16 [M][1280]; n>=1280 -> dtr f32 [M][8]
// MODE 1 (out-proj): C[M,N] += acc (f32) and ubf bf16 copy
template <int MODE>
__global__ __launch_bounds__(256) void k_gemmm(const u16* __restrict__ A, const u16* __restrict__ BT,
                                               u16* __restrict__ OB, float* __restrict__ DT,
                                               float* __restrict__ C, u16* __restrict__ ubf,
                                               int M, int N, int K) {
  __shared__ u16 As[128 * 40];
  __shared__ u16 Bs[64 * 40];
  const int n0 = blockIdx.x * 64;
  const int m0 = blockIdx.y * 128;
  const int tid = threadIdx.x;
  const int w = tid >> 6, l = tid & 63;
  const int mhalf = (w >> 1) * 64, nhalf = (w & 1) * 32;
  f32x4 acc[4][2] = {};
  for (int k0 = 0; k0 < K; k0 += 32) {
    __syncthreads();
    for (int q = tid; q < 512; q += 256) {
      int row = q >> 2, koff = (q & 3) * 8;
      short8v v = {};
      if (m0 + row < M) v = *(const short8v*)(A + (size_t)(m0 + row) * K + k0 + koff);
      *(short8v*)(As + row * 40 + koff) = v;
    }
    {
      int row = tid >> 2, koff = (tid & 3) * 8;
      short8v v = {};
      if (n0 + row < N) v = *(const short8v*)(BT + (size_t)(n0 + row) * K + k0 + koff);
      *(short8v*)(Bs + row * 40 + koff) = v;
    }
    __syncthreads();
    const int koff = (l >> 4) * 8;
    short8v b0 = *(const short8v*)(Bs + (nhalf + (l & 15)) * 40 + koff);
    short8v b1 = *(const short8v*)(Bs + (nhalf + 16 + (l & 15)) * 40 + koff);
#pragma unroll
    for (int mi = 0; mi < 4; ++mi) {
      short8v a = *(const short8v*)(As + (mhalf + mi * 16 + (l & 15)) * 40 + koff);
      acc[mi][0] = __builtin_amdgcn_mfma_f32_16x16x32_bf16(a, b0, acc[mi][0], 0, 0, 0);
      acc[mi][1] = __builtin_amdgcn_mfma_f32_16x16x32_bf16(a, b1, acc[mi][1], 0, 0, 0);
    }
  }
#pragma unroll
  for (int mi = 0; mi < 4; ++mi)
#pragma unroll
    for (int r = 0; r < 4; ++r) {
      int m = m0 + mhalf + mi * 16 + (l >> 4) * 4 + r;
      if (m >= M) continue;
#pragma unroll
      for (int ni = 0; ni < 2; ++ni) {
        int n = n0 + nhalf + ni * 16 + (l & 15);
        if (n >= N) continue;
        float v = acc[mi][ni][r];
        if constexpr (MODE == 0) {
          if (n < 1280) OB[(size_t)m * 1280 + n] = f2bf(v);
          else DT[(size_t)m * 8 + (n - 1280)] = v;
        } else {
          float vv = C[(size_t)m * N + n] + v;
          C[(size_t)m * N + n] = vv;
          ubf[(size_t)m * N + n] = f2bf(vv);
        }
      }
    }
}

// ---------------- depthwise causal conv K=4 + silu (bf16 in/out) ; bx==3: dt/ld from dtr
__global__ __launch_bounds__(256) void k_dw(const u16* __restrict__ zxb, const float* __restrict__ dtr,
                                            const float* __restrict__ cw, const float* __restrict__ cb,
                                            const float* __restrict__ dtbias, const float* __restrict__ al,
                                            u16* __restrict__ xBCb, float* __restrict__ dtb,
                                            float* __restrict__ ldb) {
  const int bx = blockIdx.x;
  const int t0 = blockIdx.y * 64;
  const int b = blockIdx.z;
  if (bx == 3) {
    int h = threadIdx.x & 7, ro = threadIdx.x >> 3;
    float dbv = dtbias[h];
    float av = expf(al[h]);
#pragma unroll
    for (int it = 0; it < 2; ++it) {
      int r = t0 + it * 32 + ro;
      if (r < 2049) {
        float v = dtr[((size_t)b * 2049 + r) * 8 + h] + dbv;
        float d = (v > 20.f) ? v : log1pf(expf(v));
        size_t o = ((size_t)b * 2049 + r) * 8 + h;
        dtb[o] = d;
        ldb[o] = -av * d;
      }
    }
    return;
  }
  int c = bx * 256 + threadIdx.x;
  const u16* col = zxb + ((size_t)b * 2049) * 1280 + 512 + c;
  float cw0 = cw[c * 4 + 0], cw1 = cw[c * 4 + 1], cw2 = cw[c * 4 + 2], cw3 = cw[c * 4 + 3];
  const float bias = cb[c];
  float w0 = 0.f, w1 = 0.f, w2 = 0.f;
  if (t0 - 3 >= 0) w0 = bf2f(col[(size_t)(t0 - 3) * 1280]);
  if (t0 - 2 >= 0) w1 = bf2f(col[(size_t)(t0 - 2) * 1280]);
  if (t0 - 1 >= 0) w2 = bf2f(col[(size_t)(t0 - 1) * 1280]);
  int tend = t0 + 64; if (tend > 2049) tend = 2049;
  u16* ob = xBCb + ((size_t)b * 2049) * 768 + c;
  for (int t = t0; t < tend; ++t) {
    float v = bf2f(col[(size_t)t * 1280]);
    float acc = bias + w0 * cw0 + w1 * cw1 + w2 * cw2 + v * cw3;
    float sig = 1.f / (1.f + expf(-acc));
    ob[(size_t)t * 768] = f2bf(acc * sig);
    w0 = w1; w1 = w2; w2 = v;
  }
}

// ================= MFMA chunked SSD (Q=128, 17 chunks over L=2049) =================
// intra: G=C·Bᵀ -> Ms -> Y=Ms@X ; 2-region LDS (70KB), vectorized staging
__global__ __launch_bounds__(256) void k_ssd_intra(const u16* __restrict__ xBCb,
                                                   const float* __restrict__ dtg,
                                                   const float* __restrict__ ldg,
                                                   float* __restrict__ ybuf,
                                                   float* __restrict__ dtot) {
  const int L = 2049;
  const int c = blockIdx.x, h = blockIdx.y, b = blockIdx.z;
  const int tid = threadIdx.x;
  const int w = tid >> 6, l = tid & 63;
  const int t0 = c * 128;
  int qc = L - t0; if (qc > 128) qc = 128;

  __shared__ u16 R1[128 * 136];  // Bs -> XT
  __shared__ u16 R2[128 * 136];  // Cs -> Ms
  __shared__ float dt_s[128], Lc_s[128];

  const u16* xb = xBCb + ((size_t)b * L) * 768;

  // wave0: load dt/ld + inclusive scan of ld -> Lc
  if (tid < 64) {
    int i2 = tid * 2;
    float a0 = 0.f, a1 = 0.f, d0 = 0.f, d1 = 0.f;
    if (i2 < qc) { size_t r = ((size_t)b * L + t0 + i2) * 8 + h; a0 = ldg[r]; d0 = dtg[r]; }
    if (i2 + 1 < qc) { size_t r = ((size_t)b * L + t0 + i2 + 1) * 8 + h; a1 = ldg[r]; d1 = dtg[r]; }
    dt_s[i2] = d0; dt_s[i2 + 1] = d1;
    float v = a0 + a1;
#pragma unroll
    for (int dlt = 1; dlt < 64; dlt <<= 1) {
      float t = __shfl_up(v, dlt, 64);
      if (tid >= dlt) v += t;
    }
    Lc_s[i2 + 1] = v;
    Lc_s[i2] = v - a1;
  }

  // stage Bs (R1), Cs (R2) vectorized
  for (int q = tid; q < 2048; q += 256) {
    int row = q >> 4, off = (q & 15) * 8;
    short8v vb = {}, vc = {};
    if (row < qc) {
      const u16* src = xb + (size_t)(t0 + row) * 768;
      vb = *(const short8v*)(src + 512 + off);
      vc = *(const short8v*)(src + 640 + off);
    }
    *(short8v*)(R1 + row * 136 + off) = vb;
    *(short8v*)(R2 + row * 136 + off) = vc;
  }
  __syncthreads();  // B1

  // G = C·Bᵀ  (128×128, K=128)
  const int wm = (w >> 1) * 64, wn = (w & 1) * 64;
  f32x4 g[4][4] = {};
  const bool skipG = (wm < wn);
  if (!skipG) {
#pragma unroll
    for (int ks = 0; ks < 4; ++ks) {
      const int koff = ks * 32 + (l >> 4) * 8;
      short8v bf[4];
#pragma unroll
      for (int ni = 0; ni < 4; ++ni)
        bf[ni] = *(const short8v*)(R1 + (wn + ni * 16 + (l & 15)) * 136 + koff);
#pragma unroll
      for (int mi = 0; mi < 4; ++mi) {
        short8v a = *(const short8v*)(R2 + (wm + mi * 16 + (l & 15)) * 136 + koff);
#pragma unroll
        for (int ni = 0; ni < 4; ++ni)
          g[mi][ni] = __builtin_amdgcn_mfma_f32_16x16x32_bf16(a, bf[ni], g[mi][ni], 0, 0, 0);
      }
    }
  }
  __syncthreads();  // B2 (G reads done)

  // Ms -> R2 ; XT -> R1 rows 0..63 (vectorized load + LDS scatter) ; dtot
#pragma unroll
  for (int mi = 0; mi < 4; ++mi)
#pragma unroll
    for (int r = 0; r < 4; ++r) {
      int t = wm + mi * 16 + (l >> 4) * 4 + r;
      float lct = Lc_s[t];
#pragma unroll
      for (int ni = 0; ni < 4; ++ni) {
        int s = wn + ni * 16 + (l & 15);
        float v = 0.f;
        if (s <= t) v = __expf(lct - Lc_s[s]) * dt_s[s] * g[mi][ni][r];
        R2[t * 136 + s] = f2bf(v);
      }
    }
  for (int q = tid; q < 1024; q += 256) {
    int s = q >> 3, pv = (q & 7) * 8;
    short8v v = {};
    if (s < qc) v = *(const short8v*)(xb + (size_t)(t0 + s) * 768 + h * 64 + pv);
#pragma unroll
    for (int j = 0; j < 8; ++j) R1[(pv + j) * 136 + s] = (u16)v[j];
  }
  if (tid == 0) dtot[((size_t)b * 8 + h) * 17 + c] = __expf(Lc_s[qc - 1]);
  __syncthreads();  // B3

  // Y = Ms(R2) @ XT(R1)  (128×64, K=128)
  {
    const int wmy = (w >> 1) * 64, wny = (w & 1) * 32;
    f32x4 ya[4][2] = {};
#pragma unroll
    for (int ks = 0; ks < 4; ++ks) {
      const int koff = ks * 32 + (l >> 4) * 8;
      short8v b0 = *(const short8v*)(R1 + (wny + (l & 15)) * 136 + koff);
      short8v b1 = *(const short8v*)(R1 + (wny + 16 + (l & 15)) * 136 + koff);
#pragma unroll
      for (int mi = 0; mi < 4; ++mi) {
        short8v a = *(const short8v*)(R2 + (wmy + mi * 16 + (l & 15)) * 136 + koff);
        ya[mi][0] = __builtin_amdgcn_mfma_f32_16x16x32_bf16(a, b0, ya[mi][0], 0, 0, 0);
        ya[mi][1] = __builtin_amdgcn_mfma_f32_16x16x32_bf16(a, b1, ya[mi][1], 0, 0, 0);
      }
    }
    float* yb = ybuf + ((size_t)b * L + t0) * 512 + h * 64;
#pragma unroll
    for (int mi = 0; mi < 4; ++mi)
#pragma unroll
      for (int r = 0; r < 4; ++r) {
        int t = wmy + mi * 16 + (l >> 4) * 4 + r;
        if (t >= qc) continue;
#pragma unroll
        for (int ni = 0; ni < 2; ++ni) {
          int p = wny + ni * 16 + (l & 15);
          yb[(size_t)t * 512 + p] = ya[mi][ni][r];
        }
      }
  }
}

// state: Sc[p][n] = sum_s exp(Lend-Lc[s])*dt[s]*X[s,p]*B[s,n]  (64×128, K=128)
__global__ __launch_bounds__(256) void k_ssd_state(const u16* __restrict__ xBCb,
                                                   const float* __restrict__ dtg,
                                                   const float* __restrict__ ldg,
                                                   float* __restrict__ sc) {
  const int L = 2049;
  const int c = blockIdx.x, h = blockIdx.y, b = blockIdx.z;
  const int tid = threadIdx.x;
  const int w = tid >> 6, l = tid & 63;
  const int t0 = c * 128;
  int qc = L - t0; if (qc > 128) qc = 128;

  __shared__ u16 XW[64 * 136];
  __shared__ u16 BT[128 * 136];
  __shared__ float dt_s[128], Lc_s[128];

  const u16* xb = xBCb + ((size_t)b * L) * 768;

  if (tid < 64) {
    int i2 = tid * 2;
    float a0 = 0.f, a1 = 0.f, d0 = 0.f, d1 = 0.f;
    if (i2 < qc) { size_t r = ((size_t)b * L + t0 + i2) * 8 + h; a0 = ldg[r]; d0 = dtg[r]; }
    if (i2 + 1 < qc) { size_t r = ((size_t)b * L + t0 + i2 + 1) * 8 + h; a1 = ldg[r]; d1 = dtg[r]; }
    dt_s[i2] = d0; dt_s[i2 + 1] = d1;
    float v = a0 + a1;
#pragma unroll
    for (int dlt = 1; dlt < 64; dlt <<= 1) {
      float t = __shfl_up(v, dlt, 64);
      if (tid >= dlt) v += t;
    }
    Lc_s[i2 + 1] = v;
    Lc_s[i2] = v - a1;
  }
  __syncthreads();  // scan ready

  const float Lend = Lc_s[qc - 1];
  // XW[p][s] = X[s,p]*w2[s] (vectorized load + scatter)
  for (int q = tid; q < 1024; q += 256) {
    int s = q >> 3, pv = (q & 7) * 8;
    float w2 = __expf(Lend - Lc_s[s]) * dt_s[s];
    short8v v = {};
    if (s < qc) v = *(const short8v*)(xb + (size_t)(t0 + s) * 768 + h * 64 + pv);
#pragma unroll
    for (int j = 0; j < 8; ++j) XW[(pv + j) * 136 + s] = f2bf(bf2f((u16)v[j]) * w2);
  }
  // BT[n][s] = B[s,n]
  for (int q = tid; q < 2048; q += 256) {
    int s = q >> 4, nv = (q & 15) * 8;
    short8v v = {};
    if (s < qc) v = *(const short8v*)(xb + (size_t)(t0 + s) * 768 + 512 + nv);
#pragma unroll
    for (int j = 0; j < 8; ++j) BT[(nv + j) * 136 + s] = (u16)v[j];
  }
  __syncthreads();

  const int wms = (w & 1) * 32, wns = (w >> 1) * 64;
  f32x4 sa[2][4] = {};
#pragma unroll
  for (int ks = 0; ks < 4; ++ks) {
    const int koff = ks * 32 + (l >> 4) * 8;
    short8v a0 = *(const short8v*)(XW + (wms + (l & 15)) * 136 + koff);
    short8v a1 = *(const short8v*)(XW + (wms + 16 + (l & 15)) * 136 + koff);
#pragma unroll
    for (int ni = 0; ni < 4; ++ni) {
      short8v bb = *(const short8v*)(BT + (wns + ni * 16 + (l & 15)) * 136 + koff);
      sa[0][ni] = __builtin_amdgcn_mfma_f32_16x16x32_bf16(a0, bb, sa[0][ni], 0, 0, 0);
      sa[1][ni] = __builtin_amdgcn_mfma_f32_16x16x32_bf16(a1, bb, sa[1][ni], 0, 0, 0);
    }
  }
  float* scp = sc + (((size_t)b * 8 + h) * 17 + c) * 8192;
#pragma unroll
  for (int mi = 0; mi < 2; ++mi)
#pragma unroll
    for (int r = 0; r < 4; ++r) {
      int p = wms + mi * 16 + (l >> 4) * 4 + r;
#pragma unroll
      for (int ni = 0; ni < 4; ++ni) {
        int n = wns + ni * 16 + (l & 15);
        scp[p * 128 + n] = sa[mi][ni][r];
      }
    }
}

__global__ __launch_bounds__(256) void k_ssd_scan(float* __restrict__ sc, const float* __restrict__ dtot,
                                                  int nbh) {
  int gid = blockIdx.x * 256 + threadIdx.x;
  int bh = gid >> 13;
  if (bh >= nbh) return;
  int elem = gid & 8191;
  float* base = sc + (size_t)bh * 17 * 8192 + elem;
  const float* dtp = dtot + (size_t)bh * 17;
  float hc = 0.f;
#pragma unroll
  for (int cc = 0; cc < 17; ++cc) {
    float D = dtp[cc];
    float v = base[(size_t)cc * 8192];
    base[(size_t)cc * 8192] = hc;
    hc = hc * D + v;
  }
}

__global__ __launch_bounds__(256) void k_ssd_inter(const u16* __restrict__ xBCb,
                                                   const float* __restrict__ ldg,
                                                   const float* __restrict__ sc,
                                                   const float* __restrict__ Dh,
                                                   float* __restrict__ ybuf) {
  const int L = 2049;
  const int c = blockIdx.x, h = blockIdx.y, b = blockIdx.z;
  const int tid = threadIdx.x;
  const int w = tid >> 6, l = tid & 63;
  const int t0 = c * 128;
  int qc = L - t0; if (qc > 128) qc = 128;

  __shared__ u16 Cs[128 * 136];
  __shared__ u16 H0[64 * 136];
  __shared__ float Lc_s[128];

  const u16* xb = xBCb + ((size_t)b * L) * 768;

  if (tid < 64) {
    int i2 = tid * 2;
    float a0 = 0.f, a1 = 0.f;
    if (i2 < qc) a0 = ldg[((size_t)b * L + t0 + i2) * 8 + h];
    if (i2 + 1 < qc) a1 = ldg[((size_t)b * L + t0 + i2 + 1) * 8 + h];
    float v = a0 + a1;
#pragma unroll
    for (int dlt = 1; dlt < 64; dlt <<= 1) {
      float t = __shfl_up(v, dlt, 64);
      if (tid >= dlt) v += t;
    }
    Lc_s[i2 + 1] = v;
    Lc_s[i2] = v - a1;
  }
  for (int q = tid; q < 2048; q += 256) {
    int row = q >> 4, off = (q & 15) * 8;
    short8v vc = {};
    if (row < qc) vc = *(const short8v*)(xb + (size_t)(t0 + row) * 768 + 640 + off);
    *(short8v*)(Cs + row * 136 + off) = vc;
  }
  {
    const float* hp = sc + (((size_t)b * 8 + h) * 17 + c) * 8192;
    for (int q = tid; q < 8192; q += 256) {
      int p = q >> 7, n = q & 127;
      H0[p * 136 + n] = f2bf(hp[p * 128 + n]);
    }
  }
  __syncthreads();

  const int wm = (w >> 1) * 64, wn = (w & 1) * 32;
  f32x4 acc[4][2] = {};
#pragma unroll
  for (int ks = 0; ks < 4; ++ks) {
    const int koff = ks * 32 + (l >> 4) * 8;
    short8v b0 = *(const short8v*)(H0 + (wn + (l & 15)) * 136 + koff);
    short8v b1 = *(const short8v*)(H0 + (wn + 16 + (l & 15)) * 136 + koff);
#pragma unroll
    for (int mi = 0; mi < 4; ++mi) {
      short8v a = *(const short8v*)(Cs + (wm + mi * 16 + (l & 15)) * 136 + koff);
      acc[mi][0] = __builtin_amdgcn_mfma_f32_16x16x32_bf16(a, b0, acc[mi][0], 0, 0, 0);
      acc[mi][1] = __builtin_amdgcn_mfma_f32_16x16x32_bf16(a, b1, acc[mi][1], 0, 0, 0);
    }
  }
  const float DD = Dh[h];
  float* yb = ybuf + ((size_t)b * L + t0) * 512 + h * 64;
#pragma unroll
  for (int mi = 0; mi < 4; ++mi)
#pragma unroll
    for (int r = 0; r < 4; ++r) {
      int t = wm + mi * 16 + (l >> 4) * 4 + r;
      if (t >= qc) continue;
      float e = __expf(Lc_s[t]);
#pragma unroll
      for (int ni = 0; ni < 2; ++ni) {
        int p = wn + ni * 16 + (l & 15);
        float xs = bf2f(xb[(size_t)(t0 + t) * 768 + h * 64 + p]);
        yb[(size_t)t * 512 + p] += e * acc[mi][ni][r] + DD * xs;
      }
    }
}

// ---------------- y = y*silu(z); RMS-norm over 512; *norm_w ; write bf16 (z from bf16 zxb)
__global__ __launch_bounds__(256) void k_gaterms(const float* __restrict__ y, const u16* __restrict__ zxb,
                                                 const float* __restrict__ nw, u16* __restrict__ y2,
                                                 int Mc) {
  int row = blockIdx.x * 4 + (threadIdx.x >> 6);
  if (row >= Mc) return;
  int lane = threadIdx.x & 63;
  const float* yr = y + (size_t)row * 512 + lane * 8;
  const u16* zr = zxb + (size_t)row * 1280 + lane * 8;
  short8v zv8 = *(const short8v*)zr;
  float g[8];
  float ss = 0.f;
#pragma unroll
  for (int j = 0; j < 8; ++j) {
    float yv = yr[j];
    float zv = bf2f((u16)zv8[j]);
    float sig = 1.f / (1.f + expf(-zv));
    float gg = yv * zv * sig;
    g[j] = gg;
    ss += gg * gg;
  }
#pragma unroll
  for (int off = 32; off > 0; off >>= 1) ss += __shfl_xor(ss, off);
  float r = rsqrtf(ss * (1.f / 512.f) + EPSF);
#pragma unroll
  for (int j = 0; j < 8; ++j)
    y2[(size_t)row * 512 + lane * 8 + j] = f2bf(g[j] * r * nw[lane * 8 + j]);
}

// ---------------- final LayerNorm over E=256 for rows t=1..2048 (wave per row)
__global__ __launch_bounds__(256) void k_ln(const float* __restrict__ u, const float* __restrict__ g,
                                            const float* __restrict__ bb, float* __restrict__ out) {
  int rid = blockIdx.x * 4 + (threadIdx.x >> 6);
  int lane = threadIdx.x & 63;
  int b = rid >> 11;
  int t = (rid & 2047) + 1;
  const float* ur = u + ((size_t)b * 2049 + t) * 256 + lane * 4;
  float v[4];
  float s1 = 0.f, s2 = 0.f;
#pragma unroll
  for (int j = 0; j < 4; ++j) {
    v[j] = ur[j];
    s1 += v[j];
    s2 += v[j] * v[j];
  }
#pragma unroll
  for (int off = 32; off > 0; off >>= 1) {
    s1 += __shfl_xor(s1, off);
    s2 += __shfl_xor(s2, off);
  }
  float mu = s1 * (1.f / 256.f);
  float var = s2 * (1.f / 256.f) - mu * mu;
  float rs = rsqrtf(var + EPSF);
  float* orow = out + ((size_t)b * 2048 + (t - 1)) * 256 + lane * 4;
#pragma unroll
  for (int j = 0; j < 4; ++j) orow[j] = (v[j] - mu) * rs * g[lane * 4 + j] + bb[lane * 4 + j];
}

// ---------------- masked pool partials
__global__ __launch_bounds__(256) void k_pp(const float* __restrict__ hln, const int* __restrict__ idx,
                                            float* __restrict__ part) {
  int ch = blockIdx.x;
  int b = blockIdx.y;
  int e = threadIdx.x;
  int agg = idx[b] / 6;
  int t0 = ch * 256;
  int tend = agg + 1 - t0;
  if (tend > 256) tend = 256;
  float s = 0.f;
  for (int i = 0; i < tend; ++i) s += hln[((size_t)b * 2048 + t0 + i) * 256 + e];
  part[((size_t)b * 8 + ch) * 256 + e] = s;
}

// ---------------- pooled @ fc_w + fc_b
__global__ __launch_bounds__(256) void k_fc(const float* __restrict__ part, const int* __restrict__ idx,
                                            const float* __restrict__ fw, const float* __restrict__ fb,
                                            float* __restrict__ out) {
  __shared__ float pooled[256];
  int b = blockIdx.x;
  int tid = threadIdx.x;
  float s = 0.f;
#pragma unroll
  for (int ch = 0; ch < 8; ++ch) s += part[((size_t)b * 8 + ch) * 256 + tid];
  pooled[tid] = s;
  __syncthreads();
  if (tid < 100) {
    int agg = idx[b] / 6;
    float inv = 1.f / (float)(agg + 1);
    float acc = 0.f;
    for (int e = 0; e < 256; ++e) acc += pooled[e] * fw[e * 100 + tid];
    out[b * 100 + tid] = acc * inv + fb[tid];
  }
}

extern "C" void kernel_launch(void* const* d_in, const int* in_sizes, int n_in,
                              void* d_out, int out_size, void* d_ws, size_t ws_size,
                              hipStream_t stream) {
  (void)in_sizes; (void)n_in; (void)out_size;
  const float* x        = (const float*)d_in[0];
  const int*   idx      = (const int*)d_in[1];
  const float* patch_w  = (const float*)d_in[2];
  const float* patch_b  = (const float*)d_in[3];
  const float* conv_w   = (const float*)d_in[4];
  const float* conv_b   = (const float*)d_in[5];
  const float* bn_g     = (const float*)d_in[6];
  const float* bn_b     = (const float*)d_in[7];
  const float* cls_tok  = (const float*)d_in[8];
  const float* pos_emb  = (const float*)d_in[9];
  const float* Wi       = (const float*)d_in[10];
  const float* cw       = (const float*)d_in[11];
  const float* cb       = (const float*)d_in[12];
  const float* dt_bias  = (const float*)d_in[13];
  const float* A_log    = (const float*)d_in[14];
  const float* Dh       = (const float*)d_in[15];
  const float* norm_w   = (const float*)d_in[16];
  const float* Wo       = (const float*)d_in[17];
  const float* ln_g     = (const float*)d_in[18];
  const float* ln_b     = (const float*)d_in[19];
  const float* fc_w     = (const float*)d_in[20];
  const float* fc_b     = (const float*)d_in[21];
  float* out = (float*)d_out;
  float* ws = (float*)d_ws;

  // workspace accounting (floats). Per-chunk-batch mamba overlay footprint:
  //   zxb 1,311,360 + dtr/dtb/ldb 3*16,392 + xBCb 786,816 + ybuf 1,049,088
  //   + y2bf 524,544 + scb 1,114,112 = 4,835,096 floats per batch.
  // dtot: CB*8*17 entries -> alloc 4096 (covers CB=16's 2176).
  auto need = [](size_t cb) {
    size_t Rsz = cb * 4835096ull;
    if (Rsz < 8388608ull) Rsz = 8388608ull;
    return (8392704ull + Rsz + 4096 + 1318912 + 524288 + 655360 + 32768 + cb * 262272ull) * 4ull;
  };
  size_t CB = 16;
  while (CB > 1 && ws_size < need(CB)) CB >>= 1;
  const int NCHUNK = (int)(16 / CB);
  const int Mc = (int)(CB * 2049);

  size_t Rsz = CB * 4835096ull;
  if (Rsz < 8388608ull) Rsz = 8388608ull;

  float* u   = ws;                 // 8,392,704
  float* R   = u + 8392704;        // Rsz
  // mamba overlay in R
  u16*  zxb  = (u16*)R;                          // CB*1,311,360 floats
  float* dtr = R + CB * 1311360;                 // CB*16392
  float* dtb = dtr + CB * 16392;                 // CB*16392
  float* ldb = dtb + CB * 16392;                 // CB*16392
  float* afterldb = ldb + CB * 16392;
  u16*  xBCb = (u16*)afterldb;                   // CB*786,816 floats (Mc*768 u16)
  float* ybuf = afterldb + CB * 786816;          // CB*1,049,088
  u16*  y2bf = (u16*)(ybuf + CB * 1049088);      // CB*524,544 floats
  float* scb = ybuf + CB * 1049088 + CB * 524544;  // CB*1,114,112
  // frontend overlay in R
  u16* fA = (u16*)R;                             // CB*1,572,864 floats
  u16* fB = (u16*)(R + CB * 1572864);            // CB*1,572,864 floats
  // final overlay
  float* hln = R;                                // 8,388,608
  // after R
  float* dtot = R + Rsz;                         // 4096 (CB*8*17 <= 2176 entries)
  u16*  WiT  = (u16*)(dtot + 4096);              // 1,318,912 floats
  u16*  WoT  = (u16*)((float*)WiT + 1318912);    // 524,288 floats
  u16*  wbf  = (u16*)((float*)WoT + 524288);     // 655,360 floats
  float* ppar = (float*)wbf + 655360;            // 32,768
  u16*  u_bf = (u16*)(ppar + 32768);             // CB*262,272 floats

  // ---- weight prep
  k_wconv<<<dim3((4 * 256 * 256 * 5 + 255) / 256), 256, 0, stream>>>(conv_w, wbf);
  k_wti<<<dim3((8 * 1288 * 256 + 255) / 256), 256, 0, stream>>>(Wi, WiT);
  k_wto<<<dim3((8 * 256 * 512 + 255) / 256), 256, 0, stream>>>(Wo, WoT);

  const unsigned gy = (unsigned)((Mc + 127) / 128);

  for (int bc = 0; bc < NCHUNK; ++bc) {
    const float* xc = x + (size_t)bc * CB * 8 * 12288;
    float* uc = u + (size_t)bc * CB * 2049 * 256;

    k_patchm<<<dim3(192, (unsigned)CB), 256, 0, stream>>>(xc, patch_w, patch_b, fA);
    k_convm<<<dim3(96, 4, (unsigned)CB), 256, 0, stream>>>(fA, wbf + 0 * 327680, conv_b + 0, bn_g + 0, bn_b + 0, fB, 12288);
    k_convm<<<dim3(96, 4, (unsigned)CB), 256, 0, stream>>>(fB, wbf + 1 * 327680, conv_b + 256, bn_g + 256, bn_b + 256, fA, 12288);
    {
      size_t tot = CB * 4096 * 256;
      k_mpb<<<dim3((unsigned)((tot + 255) / 256)), 256, 0, stream>>>(fA, fB, 4096, 3, tot);
    }
    k_convm<<<dim3(32, 4, (unsigned)CB), 256, 0, stream>>>(fB, wbf + 2 * 327680, conv_b + 512, bn_g + 512, bn_b + 512, fA, 4096);
    k_convm<<<dim3(32, 4, (unsigned)CB), 256, 0, stream>>>(fA, wbf + 3 * 327680, conv_b + 768, bn_g + 768, bn_b + 768, fB, 4096);
    {
      size_t tot = CB * 2048 * 256;
      k_mpb<<<dim3((unsigned)((tot + 255) / 256)), 256, 0, stream>>>(fB, fA, 2048, 2, tot);
    }
    k_asmb<<<dim3(2049, (unsigned)CB), 256, 0, stream>>>(fA, pos_emb, cls_tok, uc, u_bf);

    for (int l = 0; l < 8; ++l) {
      const u16* WiTl = WiT + (size_t)l * 1288 * 256;
      const u16* WoTl = WoT + (size_t)l * 256 * 512;
      const float* cwl  = cw + (size_t)l * 768 * 4;
      const float* cbl  = cb + (size_t)l * 768;
      const float* dtbl = dt_bias + l * 8;
      const float* all  = A_log + l * 8;
      const float* dhl  = Dh + l * 8;
      const float* nwl  = norm_w + (size_t)l * 512;

      k_gemmm<0><<<dim3(21, gy), 256, 0, stream>>>(u_bf, WiTl, zxb, dtr, nullptr, nullptr, Mc, 1288, 256);
      k_dw<<<dim3(4, 33, (unsigned)CB), 256, 0, stream>>>(zxb, dtr, cwl, cbl, dtbl, all, xBCb, dtb, ldb);
      k_ssd_intra<<<dim3(17, 8, (unsigned)CB), 256, 0, stream>>>(xBCb, dtb, ldb, ybuf, dtot);
      k_ssd_state<<<dim3(17, 8, (unsigned)CB), 256, 0, stream>>>(xBCb, dtb, ldb, scb);
      k_ssd_scan<<<dim3((unsigned)(CB * 8 * 32)), 256, 0, stream>>>(scb, dtot, (int)(CB * 8));
      k_ssd_inter<<<dim3(17, 8, (unsigned)CB), 256, 0, stream>>>(xBCb, ldb, scb, dhl, ybuf);
      k_gaterms<<<dim3((unsigned)((Mc + 3) / 4)), 256, 0, stream>>>(ybuf, zxb, nwl, y2bf, Mc);
      k_gemmm<1><<<dim3(4, gy), 256, 0, stream>>>(y2bf, WoTl, nullptr, nullptr, uc, u_bf, Mc, 256, 512);
    }
  }

  // ---- final LN + masked pool + fc
  k_ln<<<dim3(8192), 256, 0, stream>>>(u, ln_g, ln_b, hln);
  k_pp<<<dim3(8, 16), 256, 0, stream>>>(hln, idx, ppar);
  k_fc<<<dim3(16), 256, 0, stream>>>(ppar, idx, fc_w, fc_b, out);
}